// Round 1
// baseline (2818.503 us; speedup 1.0000x reference)
//
#include <hip/hip_runtime.h>
#include <hip/hip_bf16.h>

// ---------------------------------------------------------------------------
// mGCN: 3-view GCN + cross-view attention, 2 layers, edge scoring. fp32 baseline.
// Dims: N=50000, D=H=128, V=3, E=800000/view, Eev=100000.
// ---------------------------------------------------------------------------

#define THREADS 256

__device__ __forceinline__ float eluf(float x) {
    return x > 0.f ? x : expm1f(x);
}

// ---------------------- degree / dinv ----------------------
__global__ __launch_bounds__(THREADS) void deg_init_kernel(float* deg, int VN) {
    int i = blockIdx.x * THREADS + threadIdx.x;
    if (i < VN) deg[i] = 1.f;  // self loop
}

__global__ __launch_bounds__(THREADS) void deg_scatter_kernel(
    const int* __restrict__ ei, float* __restrict__ deg, int N, int E, int V) {
    int t = blockIdx.x * THREADS + threadIdx.x;
    if (t >= V * E) return;
    int v = t / E, e = t - v * E;
    int col = ei[(size_t)v * 2 * E + E + e];
    atomicAdd(&deg[v * N + col], 1.f);
}

__global__ __launch_bounds__(THREADS) void deg_rsqrt_kernel(float* deg, int VN) {
    int i = blockIdx.x * THREADS + threadIdx.x;
    if (i < VN) deg[i] = rsqrtf(deg[i]);
}

// ---------------------- GEMM: C[M,Nn] = A[M,K] @ B[Nn,K]^T, batched over z ----------------------
__global__ __launch_bounds__(THREADS) void gemm_nt_kernel(
    const float* __restrict__ A, const float* __restrict__ B,
    float* __restrict__ C, int M, int Nn, int K) {
    int v = blockIdx.z;
    const float* Bv = B + (size_t)v * Nn * K;
    float* Cv = C + (size_t)v * M * Nn;
    __shared__ float As[16][68];
    __shared__ float Bs[16][68];
    int tid = threadIdx.x;
    int tx = tid & 15, ty = tid >> 4;
    int m0 = blockIdx.x * 64, n0 = blockIdx.y * 64;
    float acc[4][4] = {};
    for (int k0 = 0; k0 < K; k0 += 16) {
        int k = tid & 15, m = tid >> 4;
#pragma unroll
        for (int i = 0; i < 4; i++) {
            int mm = m + 16 * i;
            int gm = m0 + mm;
            As[k][mm] = (gm < M) ? A[(size_t)gm * K + k0 + k] : 0.f;
        }
#pragma unroll
        for (int i = 0; i < 4; i++) {
            int nn = m + 16 * i;
            int gn = n0 + nn;
            Bs[k][nn] = (gn < Nn) ? Bv[(size_t)gn * K + k0 + k] : 0.f;
        }
        __syncthreads();
#pragma unroll
        for (int kk = 0; kk < 16; kk++) {
            float a[4], b[4];
#pragma unroll
            for (int i = 0; i < 4; i++) a[i] = As[kk][ty * 4 + i];
#pragma unroll
            for (int j = 0; j < 4; j++) b[j] = Bs[kk][tx * 4 + j];
#pragma unroll
            for (int i = 0; i < 4; i++)
#pragma unroll
                for (int j = 0; j < 4; j++) acc[i][j] += a[i] * b[j];
        }
        __syncthreads();
    }
#pragma unroll
    for (int i = 0; i < 4; i++) {
        int gm = m0 + ty * 4 + i;
        if (gm >= M) continue;
#pragma unroll
        for (int j = 0; j < 4; j++) {
            int gn = n0 + tx * 4 + j;
            if (gn < Nn) Cv[(size_t)gm * Nn + gn] = acc[i][j];
        }
    }
}

// ---------------------- combine GEMM: xc = elu(emb @ Wc^T + bc) ----------------------
// emb[n, j] = xr1[(j>>7)*N*H + n*H + (j&127)], K=V*H=384, Nn=H=128
__global__ __launch_bounds__(THREADS) void gemm_emb_kernel(
    const float* __restrict__ XR, const float* __restrict__ B,
    const float* __restrict__ bias, float* __restrict__ C, int M, int Nn, int K, int N) {
    __shared__ float As[16][68];
    __shared__ float Bs[16][68];
    int tid = threadIdx.x;
    int tx = tid & 15, ty = tid >> 4;
    int m0 = blockIdx.x * 64, n0 = blockIdx.y * 64;
    float acc[4][4] = {};
    for (int k0 = 0; k0 < K; k0 += 16) {
        int k = tid & 15, m = tid >> 4;
        // A: gathered from XR [V,N,H]; (k0+k) stays within one 128-block
        size_t vbase = (size_t)(k0 >> 7) * N * 128;
        int col = (k0 & 127) + k;
#pragma unroll
        for (int i = 0; i < 4; i++) {
            int mm = m + 16 * i;
            int gm = m0 + mm;
            As[k][mm] = (gm < M) ? XR[vbase + (size_t)gm * 128 + col] : 0.f;
        }
#pragma unroll
        for (int i = 0; i < 4; i++) {
            int nn = m + 16 * i;
            int gn = n0 + nn;
            Bs[k][nn] = (gn < Nn) ? B[(size_t)gn * K + k0 + k] : 0.f;
        }
        __syncthreads();
#pragma unroll
        for (int kk = 0; kk < 16; kk++) {
            float a[4], b[4];
#pragma unroll
            for (int i = 0; i < 4; i++) a[i] = As[kk][ty * 4 + i];
#pragma unroll
            for (int j = 0; j < 4; j++) b[j] = Bs[kk][tx * 4 + j];
#pragma unroll
            for (int i = 0; i < 4; i++)
#pragma unroll
                for (int j = 0; j < 4; j++) acc[i][j] += a[i] * b[j];
        }
        __syncthreads();
    }
#pragma unroll
    for (int i = 0; i < 4; i++) {
        int gm = m0 + ty * 4 + i;
        if (gm >= M) continue;
#pragma unroll
        for (int j = 0; j < 4; j++) {
            int gn = n0 + tx * 4 + j;
            if (gn < Nn) C[(size_t)gm * Nn + gn] = eluf(acc[i][j] + bias[gn]);
        }
    }
}

// ---------------------- attention ----------------------
// T[v,k,b] = sum_a W[v,k,a] * A[a,b]    (all dims 128, V=3)
__global__ __launch_bounds__(THREADS) void small_mm_nn_kernel(
    const float* __restrict__ W, const float* __restrict__ A, float* __restrict__ T) {
    int idx = blockIdx.x * THREADS + threadIdx.x;
    if (idx >= 3 * 128 * 128) return;
    int b = idx & 127;
    int vk = idx >> 7;
    const float* w = W + (size_t)vk * 128;
    float s = 0.f;
#pragma unroll 8
    for (int a = 0; a < 128; a++) s += w[a] * A[a * 128 + b];
    T[idx] = s;
}

// Mraw[v*3+w] = sum_i T[v][i]*W[w][i] + 128*bA
__global__ __launch_bounds__(THREADS) void att_reduce_kernel(
    const float* __restrict__ T, const float* __restrict__ W,
    const float* __restrict__ bA, float* __restrict__ Mraw) {
    int v = blockIdx.x / 3, w = blockIdx.x % 3;
    const float* tp = T + (size_t)v * 16384;
    const float* wp = W + (size_t)w * 16384;
    float s = 0.f;
    for (int i = threadIdx.x; i < 16384; i += THREADS) s += tp[i] * wp[i];
    __shared__ float red[THREADS];
    red[threadIdx.x] = s;
    __syncthreads();
    for (int st = THREADS / 2; st; st >>= 1) {
        if (threadIdx.x < st) red[threadIdx.x] += red[threadIdx.x + st];
        __syncthreads();
    }
    if (threadIdx.x == 0) Mraw[blockIdx.x] = red[0] + 128.f * bA[0];
}

__global__ void att_softmax_kernel(const float* __restrict__ Mraw, float* __restrict__ att) {
    int v = threadIdx.x;
    if (v >= 3) return;
    float m0 = Mraw[v * 3 + 0], m1 = Mraw[v * 3 + 1], m2 = Mraw[v * 3 + 2];
    float mx = fmaxf(m0, fmaxf(m1, m2));
    float e0 = expf(m0 - mx), e1 = expf(m1 - mx), e2 = expf(m2 - mx);
    float s = e0 + e1 + e2;
    att[v * 3 + 0] = e0 / s;
    att[v * 3 + 1] = e1 / s;
    att[v * 3 + 2] = e2 / s;
}

// ---------------------- GCN aggregation ----------------------
// agg[v,n,h] = dinv[v,n]^2 * xlin[v,n,h]   (self-loop term, also zero-init)
__global__ __launch_bounds__(THREADS) void self_init_kernel(
    const float* __restrict__ xlin, const float* __restrict__ dinv,
    float* __restrict__ agg, int total) {
    int idx = blockIdx.x * THREADS + threadIdx.x;
    if (idx >= total) return;
    float d = dinv[idx >> 7];  // [v*N+n]
    agg[idx] = d * d * xlin[idx];
}

// per-edge scatter: agg[v,col,f] += dinv[row]*dinv[col]*xlin[v,row,f]
__global__ __launch_bounds__(THREADS) void edge_scatter_kernel(
    const int* __restrict__ ei, const float* __restrict__ dinv,
    const float* __restrict__ xlin, float* __restrict__ agg, int N, int E, int V) {
    int t = blockIdx.x * THREADS + threadIdx.x;
    int eg = t >> 7, f = t & 127;
    if (eg >= V * E) return;
    int v = eg / E, e = eg - v * E;
    const int* eiv = ei + (size_t)v * 2 * E;
    int row = eiv[e], col = eiv[E + e];
    float norm = dinv[v * N + row] * dinv[v * N + col];
    atomicAdd(&agg[((size_t)v * N + col) * 128 + f],
              norm * xlin[((size_t)v * N + row) * 128 + f]);
}

// ---------------------- cross representation (in-place on agg) ----------------------
// xr = (1-alpha) + inner + elu(alpha * sum_w att[v,w]*xlin[w,n,h])
// inner = elu_inner ? elu(agg+bias) : agg+bias
__global__ __launch_bounds__(THREADS) void cross_rep_kernel(
    float* __restrict__ agg, const float* __restrict__ xlin,
    const float* __restrict__ att, const float* __restrict__ bias,
    int N, int elu_inner) {
    int idx = blockIdx.x * THREADS + threadIdx.x;
    int NH = N * 128;
    if (idx >= 3 * NH) return;
    int v = idx / NH;
    int nh = idx - v * NH;
    int h = idx & 127;
    float a = agg[idx] + bias[v * 128 + h];
    if (elu_inner) a = eluf(a);
    float cr = att[v * 3 + 0] * xlin[nh] + att[v * 3 + 1] * xlin[NH + nh] +
               att[v * 3 + 2] * xlin[2 * NH + nh];
    cr *= 0.5f;  // alpha
    agg[idx] = 0.5f + a + eluf(cr);
}

// ---------------------- edge scoring ----------------------
__global__ __launch_bounds__(THREADS) void edge_score_kernel(
    const float* __restrict__ xr2, const int* __restrict__ edges,
    const int* __restrict__ edges_neg, float* __restrict__ out, int N, int Eev, int V) {
    int wave = (blockIdx.x * THREADS + threadIdx.x) >> 6;
    int lane = threadIdx.x & 63;
    int total = V * 2 * Eev;
    if (wave >= total) return;
    int v = wave / (2 * Eev);
    int r = wave - v * (2 * Eev);
    const int* ep;
    if (r < Eev)
        ep = edges + ((size_t)v * Eev + r) * 2;
    else
        ep = edges_neg + ((size_t)v * Eev + (r - Eev)) * 2;
    int a = ep[0], b = ep[1];
    const float* pa = xr2 + ((size_t)v * N + a) * 128;
    const float* pb = xr2 + ((size_t)v * N + b) * 128;
    float s = pa[lane] * pb[lane] + pa[lane + 64] * pb[lane + 64];
#pragma unroll
    for (int off = 32; off; off >>= 1) s += __shfl_down(s, off);
    if (lane == 0) out[wave] = s;
}

// ---------------------------------------------------------------------------
extern "C" void kernel_launch(void* const* d_in, const int* in_sizes, int n_in,
                              void* d_out, int out_size, void* d_ws, size_t ws_size,
                              hipStream_t stream) {
    const float* x   = (const float*)d_in[0];
    const float* W1  = (const float*)d_in[1];
    const float* b1  = (const float*)d_in[2];
    const float* W2  = (const float*)d_in[3];
    const float* b2  = (const float*)d_in[4];
    const float* A1  = (const float*)d_in[5];
    const float* bA1 = (const float*)d_in[6];
    const float* A2  = (const float*)d_in[7];
    const float* bA2 = (const float*)d_in[8];
    const float* Wc1 = (const float*)d_in[9];
    const float* bc1 = (const float*)d_in[10];
    // Wc2 (11), bc2 (12) unused by the reference
    const int* ei        = (const int*)d_in[13];
    const int* edges     = (const int*)d_in[14];
    const int* edges_neg = (const int*)d_in[15];
    float* out = (float*)d_out;

    const int H = 128, V = 3;
    const int N = in_sizes[0] / H;          // 50000
    const int E = in_sizes[13] / (V * 2);   // 800000
    const int Eev = in_sizes[14] / (V * 2); // 100000
    const int VNH = V * N * H;              // 19.2M
    const int VN = V * N;

    // workspace partition (floats)
    float* ws = (float*)d_ws;
    float* xlin = ws;                 // V*N*H
    float* agg  = xlin + VNH;         // V*N*H
    float* xc   = agg + VNH;          // N*H
    float* dinv = xc + (size_t)N * H; // V*N
    float* T    = dinv + VN;          // V*128*128
    float* Mraw = T + V * H * H;      // 9
    float* att  = Mraw + 16;          // 9
    (void)ws_size; (void)n_in; (void)out_size;

    dim3 blk(THREADS);
    int gVN = (VN + THREADS - 1) / THREADS;
    int gVE = (V * E + THREADS - 1) / THREADS;
    int gVNH = (VNH + THREADS - 1) / THREADS;
    int gScatter = (int)(((size_t)V * E * 128 + THREADS - 1) / THREADS);
    dim3 gemmGrid((N + 63) / 64, (H + 63) / 64, V);
    dim3 gemmGrid1((N + 63) / 64, (H + 63) / 64, 1);
    int gScore = (int)(((size_t)V * 2 * Eev * 64 + THREADS - 1) / THREADS);

    // --- degrees (same for both layers) ---
    deg_init_kernel<<<gVN, blk, 0, stream>>>(dinv, VN);
    deg_scatter_kernel<<<gVE, blk, 0, stream>>>(ei, dinv, N, E, V);
    deg_rsqrt_kernel<<<gVN, blk, 0, stream>>>(dinv, VN);

    // --- layer 1 ---
    gemm_nt_kernel<<<gemmGrid, blk, 0, stream>>>(x, W1, xlin, N, H, 128);
    small_mm_nn_kernel<<<(3 * 128 * 128 + THREADS - 1) / THREADS, blk, 0, stream>>>(W1, A1, T);
    att_reduce_kernel<<<9, blk, 0, stream>>>(T, W1, bA1, Mraw);
    att_softmax_kernel<<<1, 64, 0, stream>>>(Mraw, att);
    self_init_kernel<<<gVNH, blk, 0, stream>>>(xlin, dinv, agg, VNH);
    edge_scatter_kernel<<<gScatter, blk, 0, stream>>>(ei, dinv, xlin, agg, N, E, V);
    cross_rep_kernel<<<gVNH, blk, 0, stream>>>(agg, xlin, att, b1, N, 1);

    // --- combine ---
    gemm_emb_kernel<<<gemmGrid1, blk, 0, stream>>>(agg, Wc1, bc1, xc, N, H, V * H, N);

    // --- layer 2 ---
    gemm_nt_kernel<<<gemmGrid, blk, 0, stream>>>(xc, W2, xlin, N, H, 128);
    small_mm_nn_kernel<<<(3 * 128 * 128 + THREADS - 1) / THREADS, blk, 0, stream>>>(W2, A2, T);
    att_reduce_kernel<<<9, blk, 0, stream>>>(T, W2, bA2, Mraw);
    att_softmax_kernel<<<1, 64, 0, stream>>>(Mraw, att);
    self_init_kernel<<<gVNH, blk, 0, stream>>>(xlin, dinv, agg, VNH);
    edge_scatter_kernel<<<gScatter, blk, 0, stream>>>(ei, dinv, xlin, agg, N, E, V);
    cross_rep_kernel<<<gVNH, blk, 0, stream>>>(agg, xlin, att, b2, N, 0);

    // --- scoring ---
    edge_score_kernel<<<gScore, blk, 0, stream>>>(agg, edges, edges_neg, out, N, Eev, V);
}

// Round 2
// 1481.762 us; speedup vs baseline: 1.9021x; 1.9021x over previous
//
#include <hip/hip_runtime.h>
#include <hip/hip_bf16.h>

// ---------------------------------------------------------------------------
// mGCN: 3-view GCN + cross-view attention, 2 layers, edge scoring.
// R2: CSR-gather aggregation (no float atomics) + fused cross_rep epilogue.
// Dims: N=50000, D=H=128, V=3, E=800000/view, Eev=100000.
// ---------------------------------------------------------------------------

#define THREADS 256

__device__ __forceinline__ float eluf(float x) {
    return x > 0.f ? x : expm1f(x);
}

// ---------------------- CSR build ----------------------
__global__ __launch_bounds__(THREADS) void init_int_kernel(int* p, int n) {
    int i = blockIdx.x * THREADS + threadIdx.x;
    if (i < n) p[i] = 0;
}

__global__ __launch_bounds__(THREADS) void hist_kernel(
    const int* __restrict__ ei, int* __restrict__ cnt, int N, int E, int V) {
    int t = blockIdx.x * THREADS + threadIdx.x;
    if (t >= V * E) return;
    int v = t / E, e = t - v * E;
    int col = ei[(size_t)v * 2 * E + E + e];
    atomicAdd(&cnt[v * N + col], 1);
}

__global__ __launch_bounds__(THREADS) void dinv_kernel(
    const int* __restrict__ cnt, float* __restrict__ dinv, int VN) {
    int i = blockIdx.x * THREADS + threadIdx.x;
    if (i < VN) dinv[i] = rsqrtf((float)(cnt[i] + 1));  // +1 self loop
}

// single-workgroup exclusive scan: ptr[i] = sum_{j<i} cnt[j]
#define SCAN_T 1024
__global__ __launch_bounds__(SCAN_T) void scan_kernel(
    const int* __restrict__ cnt, int* __restrict__ ptr, int n) {
    __shared__ int sums[SCAN_T];
    int t = threadIdx.x;
    int per = (n + SCAN_T - 1) / SCAN_T;
    int beg = t * per, end = min(beg + per, n);
    int s = 0;
    for (int i = beg; i < end; i++) s += cnt[i];
    sums[t] = s;
    __syncthreads();
    for (int off = 1; off < SCAN_T; off <<= 1) {
        int val = (t >= off) ? sums[t - off] : 0;
        __syncthreads();
        sums[t] += val;
        __syncthreads();
    }
    int run = (t == 0) ? 0 : sums[t - 1];
    for (int i = beg; i < end; i++) { ptr[i] = run; run += cnt[i]; }
}

// fill: pos = atomicAdd(ptr[g]); idx[pos] = row.  After this, ptr[g] = end(g),
// and start(g) = (g==0 ? 0 : ptr[g-1]).
__global__ __launch_bounds__(THREADS) void fill_kernel(
    const int* __restrict__ ei, int* __restrict__ ptr, int* __restrict__ idx,
    int N, int E, int V) {
    int t = blockIdx.x * THREADS + threadIdx.x;
    if (t >= V * E) return;
    int v = t / E, e = t - v * E;
    const int* eiv = ei + (size_t)v * 2 * E;
    int row = eiv[e], col = eiv[E + e];
    int pos = atomicAdd(&ptr[v * N + col], 1);
    idx[pos] = row;
}

// ---------------------- GEMM: C[M,Nn] = A[M,K] @ B[Nn,K]^T, batched over z ----------------------
__global__ __launch_bounds__(THREADS) void gemm_nt_kernel(
    const float* __restrict__ A, const float* __restrict__ B,
    float* __restrict__ C, int M, int Nn, int K) {
    int v = blockIdx.z;
    const float* Bv = B + (size_t)v * Nn * K;
    float* Cv = C + (size_t)v * M * Nn;
    __shared__ float As[16][68];
    __shared__ float Bs[16][68];
    int tid = threadIdx.x;
    int tx = tid & 15, ty = tid >> 4;
    int m0 = blockIdx.x * 64, n0 = blockIdx.y * 64;
    float acc[4][4] = {};
    for (int k0 = 0; k0 < K; k0 += 16) {
        int k = tid & 15, m = tid >> 4;
#pragma unroll
        for (int i = 0; i < 4; i++) {
            int mm = m + 16 * i;
            int gm = m0 + mm;
            As[k][mm] = (gm < M) ? A[(size_t)gm * K + k0 + k] : 0.f;
        }
#pragma unroll
        for (int i = 0; i < 4; i++) {
            int nn = m + 16 * i;
            int gn = n0 + nn;
            Bs[k][nn] = (gn < Nn) ? Bv[(size_t)gn * K + k0 + k] : 0.f;
        }
        __syncthreads();
#pragma unroll
        for (int kk = 0; kk < 16; kk++) {
            float a[4], b[4];
#pragma unroll
            for (int i = 0; i < 4; i++) a[i] = As[kk][ty * 4 + i];
#pragma unroll
            for (int j = 0; j < 4; j++) b[j] = Bs[kk][tx * 4 + j];
#pragma unroll
            for (int i = 0; i < 4; i++)
#pragma unroll
                for (int j = 0; j < 4; j++) acc[i][j] += a[i] * b[j];
        }
        __syncthreads();
    }
#pragma unroll
    for (int i = 0; i < 4; i++) {
        int gm = m0 + ty * 4 + i;
        if (gm >= M) continue;
#pragma unroll
        for (int j = 0; j < 4; j++) {
            int gn = n0 + tx * 4 + j;
            if (gn < Nn) Cv[(size_t)gm * Nn + gn] = acc[i][j];
        }
    }
}

// ---------------------- combine GEMM: xc = elu(emb @ Wc^T + bc) ----------------------
// emb[n, j] = xr1[(j>>7)*N*H + n*H + (j&127)], K=V*H=384, Nn=H=128
__global__ __launch_bounds__(THREADS) void gemm_emb_kernel(
    const float* __restrict__ XR, const float* __restrict__ B,
    const float* __restrict__ bias, float* __restrict__ C, int M, int Nn, int K, int N) {
    __shared__ float As[16][68];
    __shared__ float Bs[16][68];
    int tid = threadIdx.x;
    int tx = tid & 15, ty = tid >> 4;
    int m0 = blockIdx.x * 64, n0 = blockIdx.y * 64;
    float acc[4][4] = {};
    for (int k0 = 0; k0 < K; k0 += 16) {
        int k = tid & 15, m = tid >> 4;
        size_t vbase = (size_t)(k0 >> 7) * N * 128;
        int col = (k0 & 127) + k;
#pragma unroll
        for (int i = 0; i < 4; i++) {
            int mm = m + 16 * i;
            int gm = m0 + mm;
            As[k][mm] = (gm < M) ? XR[vbase + (size_t)gm * 128 + col] : 0.f;
        }
#pragma unroll
        for (int i = 0; i < 4; i++) {
            int nn = m + 16 * i;
            int gn = n0 + nn;
            Bs[k][nn] = (gn < Nn) ? B[(size_t)gn * K + k0 + k] : 0.f;
        }
        __syncthreads();
#pragma unroll
        for (int kk = 0; kk < 16; kk++) {
            float a[4], b[4];
#pragma unroll
            for (int i = 0; i < 4; i++) a[i] = As[kk][ty * 4 + i];
#pragma unroll
            for (int j = 0; j < 4; j++) b[j] = Bs[kk][tx * 4 + j];
#pragma unroll
            for (int i = 0; i < 4; i++)
#pragma unroll
                for (int j = 0; j < 4; j++) acc[i][j] += a[i] * b[j];
        }
        __syncthreads();
    }
#pragma unroll
    for (int i = 0; i < 4; i++) {
        int gm = m0 + ty * 4 + i;
        if (gm >= M) continue;
#pragma unroll
        for (int j = 0; j < 4; j++) {
            int gn = n0 + tx * 4 + j;
            if (gn < Nn) C[(size_t)gm * Nn + gn] = eluf(acc[i][j] + bias[gn]);
        }
    }
}

// ---------------------- attention ----------------------
__global__ __launch_bounds__(THREADS) void small_mm_nn_kernel(
    const float* __restrict__ W, const float* __restrict__ A, float* __restrict__ T) {
    int idx = blockIdx.x * THREADS + threadIdx.x;
    if (idx >= 3 * 128 * 128) return;
    int b = idx & 127;
    int vk = idx >> 7;
    const float* w = W + (size_t)vk * 128;
    float s = 0.f;
#pragma unroll 8
    for (int a = 0; a < 128; a++) s += w[a] * A[a * 128 + b];
    T[idx] = s;
}

__global__ __launch_bounds__(THREADS) void att_reduce_kernel(
    const float* __restrict__ T, const float* __restrict__ W,
    const float* __restrict__ bA, float* __restrict__ Mraw) {
    int v = blockIdx.x / 3, w = blockIdx.x % 3;
    const float* tp = T + (size_t)v * 16384;
    const float* wp = W + (size_t)w * 16384;
    float s = 0.f;
    for (int i = threadIdx.x; i < 16384; i += THREADS) s += tp[i] * wp[i];
    __shared__ float red[THREADS];
    red[threadIdx.x] = s;
    __syncthreads();
    for (int st = THREADS / 2; st; st >>= 1) {
        if (threadIdx.x < st) red[threadIdx.x] += red[threadIdx.x + st];
        __syncthreads();
    }
    if (threadIdx.x == 0) Mraw[blockIdx.x] = red[0] + 128.f * bA[0];
}

__global__ void att_softmax_kernel(const float* __restrict__ Mraw, float* __restrict__ att) {
    int v = threadIdx.x;
    if (v >= 3) return;
    float m0 = Mraw[v * 3 + 0], m1 = Mraw[v * 3 + 1], m2 = Mraw[v * 3 + 2];
    float mx = fmaxf(m0, fmaxf(m1, m2));
    float e0 = expf(m0 - mx), e1 = expf(m1 - mx), e2 = expf(m2 - mx);
    float s = e0 + e1 + e2;
    att[v * 3 + 0] = e0 / s;
    att[v * 3 + 1] = e1 / s;
    att[v * 3 + 2] = e2 / s;
}

// ---------------------- fused GCN gather + cross_rep ----------------------
// One wave per (v,n). Lane owns features {lane, lane+64}.
// agg = dinv[g]^2*xlin[g] + sum_{in-edges} dinv[g]*dinv[row]*xlin[row]
// xr  = (1-alpha) + inner(agg+bias) + elu(alpha * sum_w att[v,w]*xlin[w,n,:])
__global__ __launch_bounds__(THREADS) void gather_cross_kernel(
    const float* __restrict__ xlin, const float* __restrict__ dinv,
    const int* __restrict__ ptr, const int* __restrict__ idx,
    const float* __restrict__ att, const float* __restrict__ bias,
    float* __restrict__ xr, int N, int elu_inner) {
    int wv = (blockIdx.x * THREADS + threadIdx.x) >> 6;
    int lane = threadIdx.x & 63;
    int VN = 3 * N;
    if (wv >= VN) return;
    int v = wv / N;
    int n = wv - v * N;
    int vN = v * N;
    size_t base = (size_t)wv * 128;

    float dc = dinv[wv];
    float a0 = dc * dc * xlin[base + lane];
    float a1 = dc * dc * xlin[base + 64 + lane];

    int s = (wv == 0) ? 0 : ptr[wv - 1];
    int e = ptr[wv];
    for (int j = s; j < e; j++) {
        int r = idx[j];
        float nrm = dc * dinv[vN + r];
        size_t rb = ((size_t)(vN + r)) * 128;
        a0 += nrm * xlin[rb + lane];
        a1 += nrm * xlin[rb + 64 + lane];
    }

    a0 += bias[v * 128 + lane];
    a1 += bias[v * 128 + 64 + lane];
    if (elu_inner) { a0 = eluf(a0); a1 = eluf(a1); }

    size_t nb = (size_t)n * 128;
    size_t NH = (size_t)N * 128;
    float w0 = att[v * 3 + 0], w1 = att[v * 3 + 1], w2 = att[v * 3 + 2];
    float c0 = w0 * xlin[nb + lane] + w1 * xlin[NH + nb + lane] + w2 * xlin[2 * NH + nb + lane];
    float c1 = w0 * xlin[nb + 64 + lane] + w1 * xlin[NH + nb + 64 + lane] + w2 * xlin[2 * NH + nb + 64 + lane];

    xr[base + lane]      = 0.5f + a0 + eluf(0.5f * c0);
    xr[base + 64 + lane] = 0.5f + a1 + eluf(0.5f * c1);
}

// ---------------------- edge scoring ----------------------
__global__ __launch_bounds__(THREADS) void edge_score_kernel(
    const float* __restrict__ xr2, const int* __restrict__ edges,
    const int* __restrict__ edges_neg, float* __restrict__ out, int N, int Eev, int V) {
    int wave = (blockIdx.x * THREADS + threadIdx.x) >> 6;
    int lane = threadIdx.x & 63;
    int total = V * 2 * Eev;
    if (wave >= total) return;
    int v = wave / (2 * Eev);
    int r = wave - v * (2 * Eev);
    const int* ep;
    if (r < Eev)
        ep = edges + ((size_t)v * Eev + r) * 2;
    else
        ep = edges_neg + ((size_t)v * Eev + (r - Eev)) * 2;
    int a = ep[0], b = ep[1];
    const float* pa = xr2 + ((size_t)v * N + a) * 128;
    const float* pb = xr2 + ((size_t)v * N + b) * 128;
    float s = pa[lane] * pb[lane] + pa[lane + 64] * pb[lane + 64];
#pragma unroll
    for (int off = 32; off; off >>= 1) s += __shfl_down(s, off);
    if (lane == 0) out[wave] = s;
}

// ---------------------------------------------------------------------------
extern "C" void kernel_launch(void* const* d_in, const int* in_sizes, int n_in,
                              void* d_out, int out_size, void* d_ws, size_t ws_size,
                              hipStream_t stream) {
    const float* x   = (const float*)d_in[0];
    const float* W1  = (const float*)d_in[1];
    const float* b1  = (const float*)d_in[2];
    const float* W2  = (const float*)d_in[3];
    const float* b2  = (const float*)d_in[4];
    const float* A1  = (const float*)d_in[5];
    const float* bA1 = (const float*)d_in[6];
    const float* A2  = (const float*)d_in[7];
    const float* bA2 = (const float*)d_in[8];
    const float* Wc1 = (const float*)d_in[9];
    const float* bc1 = (const float*)d_in[10];
    const int* ei        = (const int*)d_in[13];
    const int* edges     = (const int*)d_in[14];
    const int* edges_neg = (const int*)d_in[15];
    float* out = (float*)d_out;

    const int H = 128, V = 3;
    const int N = in_sizes[0] / H;          // 50000
    const int E = in_sizes[13] / (V * 2);   // 800000
    const int Eev = in_sizes[14] / (V * 2); // 100000
    const int VNH = V * N * H;
    const int VN = V * N;
    const int VE = V * E;

    // workspace partition
    float* ws   = (float*)d_ws;
    float* xlin = ws;                  // VNH
    float* agg  = xlin + VNH;          // VNH (holds xr1 then xr2)
    float* xc   = agg + VNH;           // N*H
    float* dinv = xc + (size_t)N * H;  // VN
    float* T    = dinv + VN;           // 3*128*128
    float* Mraw = T + 3 * 128 * 128;   // 16
    float* att  = Mraw + 16;           // 16
    int* cnt = (int*)(att + 16);       // VN
    int* ptr = cnt + VN;               // VN
    int* idx = ptr + VN;               // VE
    (void)ws_size; (void)n_in; (void)out_size;

    dim3 blk(THREADS);
    int gVN = (VN + THREADS - 1) / THREADS;
    int gVE = (VE + THREADS - 1) / THREADS;
    int gGather = (int)(((size_t)VN * 64 + THREADS - 1) / THREADS);
    dim3 gemmGrid((N + 63) / 64, (H + 63) / 64, V);
    dim3 gemmGrid1((N + 63) / 64, (H + 63) / 64, 1);
    int gScore = (int)(((size_t)V * 2 * Eev * 64 + THREADS - 1) / THREADS);

    // --- CSR build (shared by both layers) ---
    init_int_kernel<<<gVN, blk, 0, stream>>>(cnt, VN);
    hist_kernel<<<gVE, blk, 0, stream>>>(ei, cnt, N, E, V);
    dinv_kernel<<<gVN, blk, 0, stream>>>(cnt, dinv, VN);
    scan_kernel<<<1, SCAN_T, 0, stream>>>(cnt, ptr, VN);
    fill_kernel<<<gVE, blk, 0, stream>>>(ei, ptr, idx, N, E, V);

    // --- layer 1 ---
    gemm_nt_kernel<<<gemmGrid, blk, 0, stream>>>(x, W1, xlin, N, H, 128);
    small_mm_nn_kernel<<<(3 * 128 * 128 + THREADS - 1) / THREADS, blk, 0, stream>>>(W1, A1, T);
    att_reduce_kernel<<<9, blk, 0, stream>>>(T, W1, bA1, Mraw);
    att_softmax_kernel<<<1, 64, 0, stream>>>(Mraw, att);
    gather_cross_kernel<<<gGather, blk, 0, stream>>>(xlin, dinv, ptr, idx, att, b1, agg, N, 1);

    // --- combine ---
    gemm_emb_kernel<<<gemmGrid1, blk, 0, stream>>>(agg, Wc1, bc1, xc, N, H, V * H, N);

    // --- layer 2 ---
    gemm_nt_kernel<<<gemmGrid, blk, 0, stream>>>(xc, W2, xlin, N, H, 128);
    small_mm_nn_kernel<<<(3 * 128 * 128 + THREADS - 1) / THREADS, blk, 0, stream>>>(W2, A2, T);
    att_reduce_kernel<<<9, blk, 0, stream>>>(T, W2, bA2, Mraw);
    att_softmax_kernel<<<1, 64, 0, stream>>>(Mraw, att);
    gather_cross_kernel<<<gGather, blk, 0, stream>>>(xlin, dinv, ptr, idx, att, b2, agg, N, 0);

    // --- scoring ---
    edge_score_kernel<<<gScore, blk, 0, stream>>>(agg, edges, edges_neg, out, N, Eev, V);
}

// Round 3
// 1216.088 us; speedup vs baseline: 2.3177x; 1.2185x over previous
//
#include <hip/hip_runtime.h>
#include <hip/hip_bf16.h>

// ---------------------------------------------------------------------------
// mGCN: 3-view GCN + cross-view attention, 2 layers, edge scoring.
// R3: split-bf16 (bfx3) MFMA GEMMs + float2-vectorized CSR gather.
// Dims: N=50000, D=H=128, V=3, E=800000/view, Eev=100000.
// ---------------------------------------------------------------------------

#define THREADS 256

typedef __bf16 bf16x8 __attribute__((ext_vector_type(8)));
typedef float f32x4 __attribute__((ext_vector_type(4)));
typedef unsigned short us8 __attribute__((ext_vector_type(8)));

__device__ __forceinline__ float eluf(float x) {
    return x > 0.f ? x : expm1f(x);
}

// fp32 -> bf16 bits, round-to-nearest-even
__device__ __forceinline__ unsigned short f2bf(float f) {
    unsigned u = __builtin_bit_cast(unsigned, f);
    u += 0x7FFF + ((u >> 16) & 1);
    return (unsigned short)(u >> 16);
}
__device__ __forceinline__ float bf2f(unsigned short s) {
    unsigned u = ((unsigned)s) << 16;
    return __builtin_bit_cast(float, u);
}

// ---------------------- CSR build ----------------------
__global__ __launch_bounds__(THREADS) void init_int_kernel(int* p, int n) {
    int i = blockIdx.x * THREADS + threadIdx.x;
    if (i < n) p[i] = 0;
}

__global__ __launch_bounds__(THREADS) void hist_kernel(
    const int* __restrict__ ei, int* __restrict__ cnt, int N, int E, int V) {
    int t = blockIdx.x * THREADS + threadIdx.x;
    if (t >= V * E) return;
    int v = t / E, e = t - v * E;
    int col = ei[(size_t)v * 2 * E + E + e];
    atomicAdd(&cnt[v * N + col], 1);
}

__global__ __launch_bounds__(THREADS) void dinv_kernel(
    const int* __restrict__ cnt, float* __restrict__ dinv, int VN) {
    int i = blockIdx.x * THREADS + threadIdx.x;
    if (i < VN) dinv[i] = rsqrtf((float)(cnt[i] + 1));  // +1 self loop
}

#define SCAN_T 1024
__global__ __launch_bounds__(SCAN_T) void scan_kernel(
    const int* __restrict__ cnt, int* __restrict__ ptr, int n) {
    __shared__ int sums[SCAN_T];
    int t = threadIdx.x;
    int per = (n + SCAN_T - 1) / SCAN_T;
    int beg = t * per, end = min(beg + per, n);
    int s = 0;
    for (int i = beg; i < end; i++) s += cnt[i];
    sums[t] = s;
    __syncthreads();
    for (int off = 1; off < SCAN_T; off <<= 1) {
        int val = (t >= off) ? sums[t - off] : 0;
        __syncthreads();
        sums[t] += val;
        __syncthreads();
    }
    int run = (t == 0) ? 0 : sums[t - 1];
    for (int i = beg; i < end; i++) { ptr[i] = run; run += cnt[i]; }
}

__global__ __launch_bounds__(THREADS) void fill_kernel(
    const int* __restrict__ ei, int* __restrict__ ptr, int* __restrict__ idx,
    int N, int E, int V) {
    int t = blockIdx.x * THREADS + threadIdx.x;
    if (t >= V * E) return;
    int v = t / E, e = t - v * E;
    const int* eiv = ei + (size_t)v * 2 * E;
    int row = eiv[e], col = eiv[E + e];
    int pos = atomicAdd(&ptr[v * N + col], 1);
    idx[pos] = row;
}

// ---------------------- bfx3 MFMA GEMM ----------------------
// C[M,128] = A[M,K] @ B[128,K]^T computed in split-bf16 (hi+lo), fp32 acc.
// Tile: BM=128, BN=128(=Nn), BK=64. 4 waves of 64x64 (4x4 frags of 16x16x32).
// A addressing: element (m, k0+c) at A[(k0>>7)*AV + (k0&127) + m*128 + c]
//   (AV=0 for plain [M,128] A; AV=N*128 for the [V,N,H] gathered emb A).
// B addressing: element (n, k0+c) at B[z*Bz + n*Kb + k0 + c].
// Epilogue: bias!=null -> elu(acc+bias[col]).
__global__ __launch_bounds__(256) void gemm_bfx3_kernel(
    const float* __restrict__ A, const float* __restrict__ B,
    const float* __restrict__ bias, float* __restrict__ C,
    int M, int Kb, size_t AV, size_t Bz, size_t Cz) {
    __shared__ unsigned short Ahi[128 * 64];
    __shared__ unsigned short Alo[128 * 64];
    __shared__ unsigned short Bhi[128 * 64];
    __shared__ unsigned short Blo[128 * 64];
    int tid = threadIdx.x;
    int z = blockIdx.z;
    int m0 = blockIdx.x * 128;
    const float* Bp = B + (size_t)z * Bz;
    int lane = tid & 63, wid = tid >> 6;
    int wr = wid >> 1, wc = wid & 1;
    int lr = lane & 15, lg = lane >> 4;
    f32x4 acc[4][4] = {};

    for (int k0 = 0; k0 < Kb; k0 += 64) {
        size_t Abase = (size_t)(k0 >> 7) * AV + (k0 & 127);
        // stage: 128 rows x 64 cols, hi/lo bf16, XOR-swizzled (elem ^= (row&7)<<3)
        for (int i = 0; i < 4; ++i) {
            int ch = tid + i * 256;          // 0..1023
            int row = ch >> 3, c8 = (ch & 7) << 3;
            int e = (row * 64 + c8) ^ ((row & 7) << 3);
            // A tile
            float va[8];
            int gm = m0 + row;
            if (gm < M) {
                const float* p = A + Abase + (size_t)gm * 128 + c8;
                *(float4*)(va)     = *(const float4*)(p);
                *(float4*)(va + 4) = *(const float4*)(p + 4);
            } else {
#pragma unroll
                for (int j = 0; j < 8; j++) va[j] = 0.f;
            }
            us8 h8, l8;
#pragma unroll
            for (int j = 0; j < 8; j++) {
                unsigned short h = f2bf(va[j]);
                h8[j] = h;
                l8[j] = f2bf(va[j] - bf2f(h));
            }
            *(us8*)&Ahi[e] = h8;
            *(us8*)&Alo[e] = l8;
            // B tile (rows of B = output cols, always 128 = full)
            float vb[8];
            const float* q = Bp + (size_t)row * Kb + k0 + c8;
            *(float4*)(vb)     = *(const float4*)(q);
            *(float4*)(vb + 4) = *(const float4*)(q + 4);
#pragma unroll
            for (int j = 0; j < 8; j++) {
                unsigned short h = f2bf(vb[j]);
                h8[j] = h;
                l8[j] = f2bf(vb[j] - bf2f(h));
            }
            *(us8*)&Bhi[e] = h8;
            *(us8*)&Blo[e] = l8;
        }
        __syncthreads();
#pragma unroll
        for (int ks = 0; ks < 2; ++ks) {
            bf16x8 ah[4], al[4], bh[4], bl[4];
#pragma unroll
            for (int m = 0; m < 4; m++) {
                int row = wr * 64 + m * 16 + lr;
                int e = (row * 64 + ks * 32 + lg * 8) ^ ((row & 7) << 3);
                ah[m] = *(const bf16x8*)&Ahi[e];
                al[m] = *(const bf16x8*)&Alo[e];
            }
#pragma unroll
            for (int n = 0; n < 4; n++) {
                int col = wc * 64 + n * 16 + lr;
                int e = (col * 64 + ks * 32 + lg * 8) ^ ((col & 7) << 3);
                bh[n] = *(const bf16x8*)&Bhi[e];
                bl[n] = *(const bf16x8*)&Blo[e];
            }
#pragma unroll
            for (int m = 0; m < 4; m++)
#pragma unroll
                for (int n = 0; n < 4; n++) {
                    acc[m][n] = __builtin_amdgcn_mfma_f32_16x16x32_bf16(ah[m], bh[n], acc[m][n], 0, 0, 0);
                    acc[m][n] = __builtin_amdgcn_mfma_f32_16x16x32_bf16(ah[m], bl[n], acc[m][n], 0, 0, 0);
                    acc[m][n] = __builtin_amdgcn_mfma_f32_16x16x32_bf16(al[m], bh[n], acc[m][n], 0, 0, 0);
                }
        }
        __syncthreads();
    }

    float* Cp = C + (size_t)z * Cz;
#pragma unroll
    for (int m = 0; m < 4; m++) {
        int rbase = m0 + wr * 64 + m * 16 + lg * 4;
#pragma unroll
        for (int n = 0; n < 4; n++) {
            int col = wc * 64 + n * 16 + lr;
#pragma unroll
            for (int j = 0; j < 4; j++) {
                int row = rbase + j;
                if (row < M) {
                    float vv = acc[m][n][j];
                    if (bias) vv = eluf(vv + bias[col]);
                    Cp[(size_t)row * 128 + col] = vv;
                }
            }
        }
    }
}

// ---------------------- attention ----------------------
__global__ __launch_bounds__(THREADS) void small_mm_nn_kernel(
    const float* __restrict__ W, const float* __restrict__ A, float* __restrict__ T) {
    int idx = blockIdx.x * THREADS + threadIdx.x;
    if (idx >= 3 * 128 * 128) return;
    int b = idx & 127;
    int vk = idx >> 7;
    const float* w = W + (size_t)vk * 128;
    float s = 0.f;
#pragma unroll 8
    for (int a = 0; a < 128; a++) s += w[a] * A[a * 128 + b];
    T[idx] = s;
}

__global__ __launch_bounds__(THREADS) void att_reduce_kernel(
    const float* __restrict__ T, const float* __restrict__ W,
    const float* __restrict__ bA, float* __restrict__ Mraw) {
    int v = blockIdx.x / 3, w = blockIdx.x % 3;
    const float* tp = T + (size_t)v * 16384;
    const float* wp = W + (size_t)w * 16384;
    float s = 0.f;
    for (int i = threadIdx.x; i < 16384; i += THREADS) s += tp[i] * wp[i];
    __shared__ float red[THREADS];
    red[threadIdx.x] = s;
    __syncthreads();
    for (int st = THREADS / 2; st; st >>= 1) {
        if (threadIdx.x < st) red[threadIdx.x] += red[threadIdx.x + st];
        __syncthreads();
    }
    if (threadIdx.x == 0) Mraw[blockIdx.x] = red[0] + 128.f * bA[0];
}

__global__ void att_softmax_kernel(const float* __restrict__ Mraw, float* __restrict__ att) {
    int v = threadIdx.x;
    if (v >= 3) return;
    float m0 = Mraw[v * 3 + 0], m1 = Mraw[v * 3 + 1], m2 = Mraw[v * 3 + 2];
    float mx = fmaxf(m0, fmaxf(m1, m2));
    float e0 = expf(m0 - mx), e1 = expf(m1 - mx), e2 = expf(m2 - mx);
    float s = e0 + e1 + e2;
    att[v * 3 + 0] = e0 / s;
    att[v * 3 + 1] = e1 / s;
    att[v * 3 + 2] = e2 / s;
}

// ---------------------- fused GCN gather + cross_rep ----------------------
// One wave per (v,n). Lane owns float2 (features 2*lane, 2*lane+1).
__global__ __launch_bounds__(THREADS) void gather_cross_kernel(
    const float* __restrict__ xlin, const float* __restrict__ dinv,
    const int* __restrict__ ptr, const int* __restrict__ idx,
    const float* __restrict__ att, const float* __restrict__ bias,
    float* __restrict__ xr, int N, int elu_inner) {
    int wv = (blockIdx.x * THREADS + threadIdx.x) >> 6;
    int lane = threadIdx.x & 63;
    int VN = 3 * N;
    if (wv >= VN) return;
    int v = wv / N;
    int n = wv - v * N;
    int vN = v * N;
    const float2* xl2 = (const float2*)xlin;

    float dc = dinv[wv];
    float2 t = xl2[(size_t)wv * 64 + lane];
    float a0 = dc * dc * t.x, a1 = dc * dc * t.y;

    int s = (wv == 0) ? 0 : ptr[wv - 1];
    int e = ptr[wv];
    int j = s;
    for (; j + 1 < e; j += 2) {
        int r0 = idx[j], r1 = idx[j + 1];
        float w0 = dc * dinv[vN + r0], w1 = dc * dinv[vN + r1];
        float2 u0 = xl2[(size_t)(vN + r0) * 64 + lane];
        float2 u1 = xl2[(size_t)(vN + r1) * 64 + lane];
        a0 += w0 * u0.x + w1 * u1.x;
        a1 += w0 * u0.y + w1 * u1.y;
    }
    if (j < e) {
        int r0 = idx[j];
        float w0 = dc * dinv[vN + r0];
        float2 u0 = xl2[(size_t)(vN + r0) * 64 + lane];
        a0 += w0 * u0.x;
        a1 += w0 * u0.y;
    }

    const float2* b2 = (const float2*)bias;
    float2 bb = b2[v * 64 + lane];
    a0 += bb.x;
    a1 += bb.y;
    if (elu_inner) { a0 = eluf(a0); a1 = eluf(a1); }

    float w0 = att[v * 3 + 0], w1 = att[v * 3 + 1], w2 = att[v * 3 + 2];
    size_t nb = (size_t)n * 64 + lane, NH2 = (size_t)N * 64;
    float2 c0 = xl2[nb], c1 = xl2[NH2 + nb], c2 = xl2[2 * NH2 + nb];
    float cx = w0 * c0.x + w1 * c1.x + w2 * c2.x;
    float cy = w0 * c0.y + w1 * c1.y + w2 * c2.y;

    float2 o;
    o.x = 0.5f + a0 + eluf(0.5f * cx);
    o.y = 0.5f + a1 + eluf(0.5f * cy);
    ((float2*)xr)[(size_t)wv * 64 + lane] = o;
}

// ---------------------- edge scoring ----------------------
__global__ __launch_bounds__(THREADS) void edge_score_kernel(
    const float* __restrict__ xr2, const int* __restrict__ edges,
    const int* __restrict__ edges_neg, float* __restrict__ out, int N, int Eev, int V) {
    int wave = (blockIdx.x * THREADS + threadIdx.x) >> 6;
    int lane = threadIdx.x & 63;
    int total = V * 2 * Eev;
    if (wave >= total) return;
    int v = wave / (2 * Eev);
    int r = wave - v * (2 * Eev);
    const int* ep;
    if (r < Eev)
        ep = edges + ((size_t)v * Eev + r) * 2;
    else
        ep = edges_neg + ((size_t)v * Eev + (r - Eev)) * 2;
    int a = ep[0], b = ep[1];
    const float2* pa = (const float2*)xr2 + ((size_t)v * N + a) * 64;
    const float2* pb = (const float2*)xr2 + ((size_t)v * N + b) * 64;
    float2 ua = pa[lane], ub = pb[lane];
    float s = ua.x * ub.x + ua.y * ub.y;
#pragma unroll
    for (int off = 32; off; off >>= 1) s += __shfl_down(s, off);
    if (lane == 0) out[wave] = s;
}

// ---------------------------------------------------------------------------
extern "C" void kernel_launch(void* const* d_in, const int* in_sizes, int n_in,
                              void* d_out, int out_size, void* d_ws, size_t ws_size,
                              hipStream_t stream) {
    const float* x   = (const float*)d_in[0];
    const float* W1  = (const float*)d_in[1];
    const float* b1  = (const float*)d_in[2];
    const float* W2  = (const float*)d_in[3];
    const float* b2  = (const float*)d_in[4];
    const float* A1  = (const float*)d_in[5];
    const float* bA1 = (const float*)d_in[6];
    const float* A2  = (const float*)d_in[7];
    const float* bA2 = (const float*)d_in[8];
    const float* Wc1 = (const float*)d_in[9];
    const float* bc1 = (const float*)d_in[10];
    const int* ei        = (const int*)d_in[13];
    const int* edges     = (const int*)d_in[14];
    const int* edges_neg = (const int*)d_in[15];
    float* out = (float*)d_out;

    const int H = 128, V = 3;
    const int N = in_sizes[0] / H;          // 50000
    const int E = in_sizes[13] / (V * 2);   // 800000
    const int Eev = in_sizes[14] / (V * 2); // 100000
    const int VNH = V * N * H;
    const int VN = V * N;
    const int VE = V * E;

    // workspace partition
    float* ws   = (float*)d_ws;
    float* xlin = ws;                  // VNH
    float* agg  = xlin + VNH;          // VNH (xr1 then xr2)
    float* xc   = agg + VNH;           // N*H
    float* dinv = xc + (size_t)N * H;  // VN
    float* T    = dinv + VN;           // 3*128*128
    float* Mraw = T + 3 * 128 * 128;   // 16
    float* att  = Mraw + 16;           // 16
    int* cnt = (int*)(att + 16);       // VN
    int* ptr = cnt + VN;               // VN
    int* idx = ptr + VN;               // VE
    (void)ws_size; (void)n_in; (void)out_size;

    dim3 blk(THREADS);
    int gVN = (VN + THREADS - 1) / THREADS;
    int gVE = (VE + THREADS - 1) / THREADS;
    int gGather = (int)(((size_t)VN * 64 + THREADS - 1) / THREADS);
    dim3 gemmGrid((N + 127) / 128, 1, V);
    dim3 gemmGrid1((N + 127) / 128, 1, 1);
    int gScore = (int)(((size_t)V * 2 * Eev * 64 + THREADS - 1) / THREADS);

    // --- CSR build (shared by both layers) ---
    init_int_kernel<<<gVN, blk, 0, stream>>>(cnt, VN);
    hist_kernel<<<gVE, blk, 0, stream>>>(ei, cnt, N, E, V);
    dinv_kernel<<<gVN, blk, 0, stream>>>(cnt, dinv, VN);
    scan_kernel<<<1, SCAN_T, 0, stream>>>(cnt, ptr, VN);
    fill_kernel<<<gVE, blk, 0, stream>>>(ei, ptr, idx, N, E, V);

    // --- layer 1 ---
    gemm_bfx3_kernel<<<gemmGrid, blk, 0, stream>>>(
        x, W1, nullptr, xlin, N, 128, (size_t)0, (size_t)128 * 128, (size_t)N * 128);
    small_mm_nn_kernel<<<(3 * 128 * 128 + THREADS - 1) / THREADS, blk, 0, stream>>>(W1, A1, T);
    att_reduce_kernel<<<9, blk, 0, stream>>>(T, W1, bA1, Mraw);
    att_softmax_kernel<<<1, 64, 0, stream>>>(Mraw, att);
    gather_cross_kernel<<<gGather, blk, 0, stream>>>(xlin, dinv, ptr, idx, att, b1, agg, N, 1);

    // --- combine: xc = elu(emb @ Wc1^T + bc1), emb gathered from agg ---
    gemm_bfx3_kernel<<<gemmGrid1, blk, 0, stream>>>(
        agg, Wc1, bc1, xc, N, 384, (size_t)N * 128, (size_t)0, (size_t)0);

    // --- layer 2 ---
    gemm_bfx3_kernel<<<gemmGrid, blk, 0, stream>>>(
        xc, W2, nullptr, xlin, N, 128, (size_t)0, (size_t)128 * 128, (size_t)N * 128);
    small_mm_nn_kernel<<<(3 * 128 * 128 + THREADS - 1) / THREADS, blk, 0, stream>>>(W2, A2, T);
    att_reduce_kernel<<<9, blk, 0, stream>>>(T, W2, bA2, Mraw);
    att_softmax_kernel<<<1, 64, 0, stream>>>(Mraw, att);
    gather_cross_kernel<<<gGather, blk, 0, stream>>>(xlin, dinv, ptr, idx, att, b2, agg, N, 0);

    // --- scoring ---
    edge_score_kernel<<<gScore, blk, 0, stream>>>(agg, edges, edges_neg, out, N, Eev, V);
}

// Round 4
// 1004.518 us; speedup vs baseline: 2.8058x; 1.2106x over previous
//
#include <hip/hip_runtime.h>
#include <hip/hip_bf16.h>

// ---------------------------------------------------------------------------
// mGCN: 3-view GCN + cross-view attention, 2 layers, edge scoring.
// R4: hierarchical scan; bf16 xlin (GEMM bf16 epilogue + 256B/edge gather,
//     2 edges in flight per wave); bfx3 MFMA GEMMs; fp32 everywhere else.
// Dims: N=50000, D=H=128, V=3, E=800000/view, Eev=100000.
// ---------------------------------------------------------------------------

#define THREADS 256

typedef __bf16 bf16x8 __attribute__((ext_vector_type(8)));
typedef float f32x4 __attribute__((ext_vector_type(4)));
typedef unsigned short us8 __attribute__((ext_vector_type(8)));
typedef unsigned short us4 __attribute__((ext_vector_type(4)));

__device__ __forceinline__ float eluf(float x) {
    return x > 0.f ? x : expm1f(x);
}

// fp32 -> bf16 bits, round-to-nearest-even
__device__ __forceinline__ unsigned short f2bf(float f) {
    unsigned u = __builtin_bit_cast(unsigned, f);
    u += 0x7FFF + ((u >> 16) & 1);
    return (unsigned short)(u >> 16);
}
__device__ __forceinline__ float bf2f(unsigned short s) {
    unsigned u = ((unsigned)s) << 16;
    return __builtin_bit_cast(float, u);
}

// ---------------------- CSR build ----------------------
__global__ __launch_bounds__(THREADS) void init_int_kernel(int* p, int n) {
    int i = blockIdx.x * THREADS + threadIdx.x;
    if (i < n) p[i] = 0;
}

__global__ __launch_bounds__(THREADS) void hist_kernel(
    const int* __restrict__ ei, int* __restrict__ cnt, int N, int E, int V) {
    int t = blockIdx.x * THREADS + threadIdx.x;
    if (t >= V * E) return;
    int v = t / E, e = t - v * E;
    int col = ei[(size_t)v * 2 * E + E + e];
    atomicAdd(&cnt[v * N + col], 1);
}

__global__ __launch_bounds__(THREADS) void dinv_kernel(
    const int* __restrict__ cnt, float* __restrict__ dinv, int VN) {
    int i = blockIdx.x * THREADS + threadIdx.x;
    if (i < VN) dinv[i] = rsqrtf((float)(cnt[i] + 1));  // +1 self loop
}

// ---- hierarchical exclusive scan: ptr[i] = sum_{j<i} cnt[j] ----
#define SC_T 256
#define SC_CHUNK 1024  // SC_T * 4

__global__ __launch_bounds__(SC_T) void scan_sum_kernel(
    const int* __restrict__ cnt, int* __restrict__ bsum, int n) {
    __shared__ int red[SC_T];
    int base = blockIdx.x * SC_CHUNK + threadIdx.x * 4;
    int s = 0;
#pragma unroll
    for (int k = 0; k < 4; k++) {
        int i = base + k;
        if (i < n) s += cnt[i];
    }
    red[threadIdx.x] = s;
    __syncthreads();
    for (int st = SC_T / 2; st; st >>= 1) {
        if (threadIdx.x < st) red[threadIdx.x] += red[threadIdx.x + st];
        __syncthreads();
    }
    if (threadIdx.x == 0) bsum[blockIdx.x] = red[0];
}

// single block: exclusive scan of bsum[0..nb), nb <= 256
__global__ __launch_bounds__(SC_T) void scan_top_kernel(int* bsum, int nb) {
    __shared__ int sh[SC_T];
    int t = threadIdx.x;
    int v = (t < nb) ? bsum[t] : 0;
    sh[t] = v;
    __syncthreads();
    for (int off = 1; off < SC_T; off <<= 1) {
        int u = (t >= off) ? sh[t - off] : 0;
        __syncthreads();
        sh[t] += u;
        __syncthreads();
    }
    if (t < nb) bsum[t] = sh[t] - v;  // exclusive
}

__global__ __launch_bounds__(SC_T) void scan_apply_kernel(
    const int* __restrict__ cnt, const int* __restrict__ bsum,
    int* __restrict__ ptr, int n) {
    __shared__ int sh[SC_T];
    int base = blockIdx.x * SC_CHUNK + threadIdx.x * 4;
    int v[4];
    int s = 0;
#pragma unroll
    for (int k = 0; k < 4; k++) {
        int i = base + k;
        v[k] = (i < n) ? cnt[i] : 0;
        s += v[k];
    }
    int tin = s;
    sh[threadIdx.x] = s;
    __syncthreads();
    for (int off = 1; off < SC_T; off <<= 1) {
        int u = (threadIdx.x >= off) ? sh[threadIdx.x - off] : 0;
        __syncthreads();
        sh[threadIdx.x] += u;
        __syncthreads();
    }
    int run = bsum[blockIdx.x] + sh[threadIdx.x] - tin;
#pragma unroll
    for (int k = 0; k < 4; k++) {
        int i = base + k;
        if (i < n) {
            ptr[i] = run;
            run += v[k];
        }
    }
}

__global__ __launch_bounds__(THREADS) void fill_kernel(
    const int* __restrict__ ei, int* __restrict__ ptr, int* __restrict__ idx,
    int N, int E, int V) {
    int t = blockIdx.x * THREADS + threadIdx.x;
    if (t >= V * E) return;
    int v = t / E, e = t - v * E;
    const int* eiv = ei + (size_t)v * 2 * E;
    int row = eiv[e], col = eiv[E + e];
    int pos = atomicAdd(&ptr[v * N + col], 1);
    idx[pos] = row;
}

// ---------------------- bfx3 MFMA GEMM ----------------------
// C[M,128] = A[M,K] @ B[128,K]^T in split-bf16 (hi+lo), fp32 acc.
// Tile: BM=128, BN=128, BK=64; 4 waves of 64x64 (4x4 frags of 16x16x32).
// A elem (m, k0+c) at A[(k0>>7)*AV + (k0&127) + m*128 + c].
// Output: Cbf!=null -> bf16 store (no bias); else fp32 with elu(acc+bias).
__global__ __launch_bounds__(256) void gemm_bfx3_kernel(
    const float* __restrict__ A, const float* __restrict__ B,
    const float* __restrict__ bias, float* __restrict__ Cf,
    unsigned short* __restrict__ Cbf,
    int M, int Kb, size_t AV, size_t Bz, size_t Cz) {
    __shared__ unsigned short Ahi[128 * 64];
    __shared__ unsigned short Alo[128 * 64];
    __shared__ unsigned short Bhi[128 * 64];
    __shared__ unsigned short Blo[128 * 64];
    int tid = threadIdx.x;
    int z = blockIdx.z;
    int m0 = blockIdx.x * 128;
    const float* Bp = B + (size_t)z * Bz;
    int lane = tid & 63, wid = tid >> 6;
    int wr = wid >> 1, wc = wid & 1;
    int lr = lane & 15, lg = lane >> 4;
    f32x4 acc[4][4] = {};

    for (int k0 = 0; k0 < Kb; k0 += 64) {
        size_t Abase = (size_t)(k0 >> 7) * AV + (k0 & 127);
        for (int i = 0; i < 4; ++i) {
            int ch = tid + i * 256;  // 0..1023
            int row = ch >> 3, c8 = (ch & 7) << 3;
            int e = (row * 64 + c8) ^ ((row & 7) << 3);
            float va[8];
            int gm = m0 + row;
            if (gm < M) {
                const float* p = A + Abase + (size_t)gm * 128 + c8;
                *(float4*)(va)     = *(const float4*)(p);
                *(float4*)(va + 4) = *(const float4*)(p + 4);
            } else {
#pragma unroll
                for (int j = 0; j < 8; j++) va[j] = 0.f;
            }
            us8 h8, l8;
#pragma unroll
            for (int j = 0; j < 8; j++) {
                unsigned short h = f2bf(va[j]);
                h8[j] = h;
                l8[j] = f2bf(va[j] - bf2f(h));
            }
            *(us8*)&Ahi[e] = h8;
            *(us8*)&Alo[e] = l8;
            float vb[8];
            const float* q = Bp + (size_t)row * Kb + k0 + c8;
            *(float4*)(vb)     = *(const float4*)(q);
            *(float4*)(vb + 4) = *(const float4*)(q + 4);
#pragma unroll
            for (int j = 0; j < 8; j++) {
                unsigned short h = f2bf(vb[j]);
                h8[j] = h;
                l8[j] = f2bf(vb[j] - bf2f(h));
            }
            *(us8*)&Bhi[e] = h8;
            *(us8*)&Blo[e] = l8;
        }
        __syncthreads();
#pragma unroll
        for (int ks = 0; ks < 2; ++ks) {
            bf16x8 ah[4], al[4], bh[4], bl[4];
#pragma unroll
            for (int m = 0; m < 4; m++) {
                int row = wr * 64 + m * 16 + lr;
                int e = (row * 64 + ks * 32 + lg * 8) ^ ((row & 7) << 3);
                ah[m] = *(const bf16x8*)&Ahi[e];
                al[m] = *(const bf16x8*)&Alo[e];
            }
#pragma unroll
            for (int n = 0; n < 4; n++) {
                int col = wc * 64 + n * 16 + lr;
                int e = (col * 64 + ks * 32 + lg * 8) ^ ((col & 7) << 3);
                bh[n] = *(const bf16x8*)&Bhi[e];
                bl[n] = *(const bf16x8*)&Blo[e];
            }
#pragma unroll
            for (int m = 0; m < 4; m++)
#pragma unroll
                for (int n = 0; n < 4; n++) {
                    acc[m][n] = __builtin_amdgcn_mfma_f32_16x16x32_bf16(ah[m], bh[n], acc[m][n], 0, 0, 0);
                    acc[m][n] = __builtin_amdgcn_mfma_f32_16x16x32_bf16(ah[m], bl[n], acc[m][n], 0, 0, 0);
                    acc[m][n] = __builtin_amdgcn_mfma_f32_16x16x32_bf16(al[m], bh[n], acc[m][n], 0, 0, 0);
                }
        }
        __syncthreads();
    }

#pragma unroll
    for (int m = 0; m < 4; m++) {
        int rbase = m0 + wr * 64 + m * 16 + lg * 4;
#pragma unroll
        for (int n = 0; n < 4; n++) {
            int col = wc * 64 + n * 16 + lr;
#pragma unroll
            for (int j = 0; j < 4; j++) {
                int row = rbase + j;
                if (row < M) {
                    float vv = acc[m][n][j];
                    if (Cbf) {
                        Cbf[(size_t)z * Cz + (size_t)row * 128 + col] = f2bf(vv);
                    } else {
                        Cf[(size_t)z * Cz + (size_t)row * 128 + col] = eluf(vv + bias[col]);
                    }
                }
            }
        }
    }
}

// ---------------------- attention ----------------------
__global__ __launch_bounds__(THREADS) void small_mm_nn_kernel(
    const float* __restrict__ W, const float* __restrict__ A, float* __restrict__ T) {
    int idx = blockIdx.x * THREADS + threadIdx.x;
    if (idx >= 3 * 128 * 128) return;
    int b = idx & 127;
    int vk = idx >> 7;
    const float* w = W + (size_t)vk * 128;
    float s = 0.f;
#pragma unroll 8
    for (int a = 0; a < 128; a++) s += w[a] * A[a * 128 + b];
    T[idx] = s;
}

__global__ __launch_bounds__(THREADS) void att_reduce_kernel(
    const float* __restrict__ T, const float* __restrict__ W,
    const float* __restrict__ bA, float* __restrict__ Mraw) {
    int v = blockIdx.x / 3, w = blockIdx.x % 3;
    const float* tp = T + (size_t)v * 16384;
    const float* wp = W + (size_t)w * 16384;
    float s = 0.f;
    for (int i = threadIdx.x; i < 16384; i += THREADS) s += tp[i] * wp[i];
    __shared__ float red[THREADS];
    red[threadIdx.x] = s;
    __syncthreads();
    for (int st = THREADS / 2; st; st >>= 1) {
        if (threadIdx.x < st) red[threadIdx.x] += red[threadIdx.x + st];
        __syncthreads();
    }
    if (threadIdx.x == 0) Mraw[blockIdx.x] = red[0] + 128.f * bA[0];
}

__global__ void att_softmax_kernel(const float* __restrict__ Mraw, float* __restrict__ att) {
    int v = threadIdx.x;
    if (v >= 3) return;
    float m0 = Mraw[v * 3 + 0], m1 = Mraw[v * 3 + 1], m2 = Mraw[v * 3 + 2];
    float mx = fmaxf(m0, fmaxf(m1, m2));
    float e0 = expf(m0 - mx), e1 = expf(m1 - mx), e2 = expf(m2 - mx);
    float s = e0 + e1 + e2;
    att[v * 3 + 0] = e0 / s;
    att[v * 3 + 1] = e1 / s;
    att[v * 3 + 2] = e2 / s;
}

// ---------------------- fused GCN gather + cross_rep ----------------------
// One wave per (v,n). Two 32-lane halves process alternate edges; l32 owns
// 4 features (ushort4 bf16 loads). Halves merged via shfl_xor(32).
__global__ __launch_bounds__(THREADS) void gather_cross_kernel(
    const unsigned short* __restrict__ xlin, const float* __restrict__ dinv,
    const int* __restrict__ ptr, const int* __restrict__ idx,
    const float* __restrict__ att, const float* __restrict__ bias,
    float* __restrict__ xr, int N, int elu_inner) {
    int wv = (blockIdx.x * THREADS + threadIdx.x) >> 6;
    int lane = threadIdx.x & 63;
    int VN = 3 * N;
    if (wv >= VN) return;
    int v = wv / N;
    int n = wv - v * N;
    int vN = v * N;
    int sub = lane >> 5, l32 = lane & 31;
    int f0 = l32 * 4;

    float dc = dinv[wv];
    float a0 = 0.f, a1 = 0.f, a2 = 0.f, a3 = 0.f;

    int s = (wv == 0) ? 0 : ptr[wv - 1];
    int e = ptr[wv];
    for (int j = s + sub; j < e; j += 2) {
        int r = idx[j];
        float w = dc * dinv[vN + r];
        us4 u = *(const us4*)(xlin + (((size_t)(vN + r)) << 7) + f0);
        a0 += w * bf2f(u[0]);
        a1 += w * bf2f(u[1]);
        a2 += w * bf2f(u[2]);
        a3 += w * bf2f(u[3]);
    }
    a0 += __shfl_xor(a0, 32);
    a1 += __shfl_xor(a1, 32);
    a2 += __shfl_xor(a2, 32);
    a3 += __shfl_xor(a3, 32);

    // self term + bias
    us4 su = *(const us4*)(xlin + (((size_t)wv) << 7) + f0);
    float dc2 = dc * dc;
    a0 += dc2 * bf2f(su[0]);
    a1 += dc2 * bf2f(su[1]);
    a2 += dc2 * bf2f(su[2]);
    a3 += dc2 * bf2f(su[3]);
    float4 bb = *(const float4*)(bias + v * 128 + f0);
    a0 += bb.x; a1 += bb.y; a2 += bb.z; a3 += bb.w;
    if (elu_inner) {
        a0 = eluf(a0); a1 = eluf(a1); a2 = eluf(a2); a3 = eluf(a3);
    }

    // cross term
    float w0 = att[v * 3 + 0], w1 = att[v * 3 + 1], w2 = att[v * 3 + 2];
    size_t nb = (((size_t)n) << 7) + f0;
    size_t NH = ((size_t)N) << 7;
    us4 c0 = *(const us4*)(xlin + nb);
    us4 c1 = *(const us4*)(xlin + NH + nb);
    us4 c2 = *(const us4*)(xlin + 2 * NH + nb);
    float4 o;
    o.x = 0.5f + a0 + eluf(0.5f * (w0 * bf2f(c0[0]) + w1 * bf2f(c1[0]) + w2 * bf2f(c2[0])));
    o.y = 0.5f + a1 + eluf(0.5f * (w0 * bf2f(c0[1]) + w1 * bf2f(c1[1]) + w2 * bf2f(c2[1])));
    o.z = 0.5f + a2 + eluf(0.5f * (w0 * bf2f(c0[2]) + w1 * bf2f(c1[2]) + w2 * bf2f(c2[2])));
    o.w = 0.5f + a3 + eluf(0.5f * (w0 * bf2f(c0[3]) + w1 * bf2f(c1[3]) + w2 * bf2f(c2[3])));

    if (sub == 0) *(float4*)(xr + (((size_t)wv) << 7) + f0) = o;
}

// ---------------------- edge scoring ----------------------
__global__ __launch_bounds__(THREADS) void edge_score_kernel(
    const float* __restrict__ xr2, const int* __restrict__ edges,
    const int* __restrict__ edges_neg, float* __restrict__ out, int N, int Eev, int V) {
    int wave = (blockIdx.x * THREADS + threadIdx.x) >> 6;
    int lane = threadIdx.x & 63;
    int total = V * 2 * Eev;
    if (wave >= total) return;
    int v = wave / (2 * Eev);
    int r = wave - v * (2 * Eev);
    const int* ep;
    if (r < Eev)
        ep = edges + ((size_t)v * Eev + r) * 2;
    else
        ep = edges_neg + ((size_t)v * Eev + (r - Eev)) * 2;
    int a = ep[0], b = ep[1];
    const float2* pa = (const float2*)xr2 + ((size_t)v * N + a) * 64;
    const float2* pb = (const float2*)xr2 + ((size_t)v * N + b) * 64;
    float2 ua = pa[lane], ub = pb[lane];
    float s = ua.x * ub.x + ua.y * ub.y;
#pragma unroll
    for (int off = 32; off; off >>= 1) s += __shfl_down(s, off);
    if (lane == 0) out[wave] = s;
}

// ---------------------------------------------------------------------------
extern "C" void kernel_launch(void* const* d_in, const int* in_sizes, int n_in,
                              void* d_out, int out_size, void* d_ws, size_t ws_size,
                              hipStream_t stream) {
    const float* x   = (const float*)d_in[0];
    const float* W1  = (const float*)d_in[1];
    const float* b1  = (const float*)d_in[2];
    const float* W2  = (const float*)d_in[3];
    const float* b2  = (const float*)d_in[4];
    const float* A1  = (const float*)d_in[5];
    const float* bA1 = (const float*)d_in[6];
    const float* A2  = (const float*)d_in[7];
    const float* bA2 = (const float*)d_in[8];
    const float* Wc1 = (const float*)d_in[9];
    const float* bc1 = (const float*)d_in[10];
    const int* ei        = (const int*)d_in[13];
    const int* edges     = (const int*)d_in[14];
    const int* edges_neg = (const int*)d_in[15];
    float* out = (float*)d_out;

    const int H = 128, V = 3;
    const int N = in_sizes[0] / H;          // 50000
    const int E = in_sizes[13] / (V * 2);   // 800000
    const int Eev = in_sizes[14] / (V * 2); // 100000
    const int VNH = V * N * H;
    const int VN = V * N;
    const int VE = V * E;

    // workspace partition
    float* ws   = (float*)d_ws;
    float* agg  = ws;                  // VNH (xr1 then xr2)
    float* xc   = agg + VNH;           // N*H
    float* dinv = xc + (size_t)N * H;  // VN
    float* T    = dinv + VN;           // 3*128*128
    float* Mraw = T + 3 * 128 * 128;   // 16
    float* att  = Mraw + 16;           // 16
    int* cnt  = (int*)(att + 16);      // VN
    int* ptr  = cnt + VN;              // VN
    int* bsum = ptr + VN;              // 256
    int* idx  = bsum + 256;            // VE
    unsigned short* xlin = (unsigned short*)(idx + VE);  // VNH bf16
    (void)ws_size; (void)n_in; (void)out_size;

    dim3 blk(THREADS);
    int gVN = (VN + THREADS - 1) / THREADS;
    int gVE = (VE + THREADS - 1) / THREADS;
    int gGather = (int)(((size_t)VN * 64 + THREADS - 1) / THREADS);
    int nScanB = (VN + SC_CHUNK - 1) / SC_CHUNK;  // 147 <= 256
    dim3 gemmGrid((N + 127) / 128, 1, V);
    dim3 gemmGrid1((N + 127) / 128, 1, 1);
    int gScore = (int)(((size_t)V * 2 * Eev * 64 + THREADS - 1) / THREADS);

    // --- CSR build (shared by both layers) ---
    init_int_kernel<<<gVN, blk, 0, stream>>>(cnt, VN);
    hist_kernel<<<gVE, blk, 0, stream>>>(ei, cnt, N, E, V);
    dinv_kernel<<<gVN, blk, 0, stream>>>(cnt, dinv, VN);
    scan_sum_kernel<<<nScanB, SC_T, 0, stream>>>(cnt, bsum, VN);
    scan_top_kernel<<<1, SC_T, 0, stream>>>(bsum, nScanB);
    scan_apply_kernel<<<nScanB, SC_T, 0, stream>>>(cnt, bsum, ptr, VN);
    fill_kernel<<<gVE, blk, 0, stream>>>(ei, ptr, idx, N, E, V);

    // --- layer 1 ---
    gemm_bfx3_kernel<<<gemmGrid, blk, 0, stream>>>(
        x, W1, nullptr, nullptr, xlin, N, 128, (size_t)0, (size_t)128 * 128, (size_t)N * 128);
    small_mm_nn_kernel<<<(3 * 128 * 128 + THREADS - 1) / THREADS, blk, 0, stream>>>(W1, A1, T);
    att_reduce_kernel<<<9, blk, 0, stream>>>(T, W1, bA1, Mraw);
    att_softmax_kernel<<<1, 64, 0, stream>>>(Mraw, att);
    gather_cross_kernel<<<gGather, blk, 0, stream>>>(xlin, dinv, ptr, idx, att, b1, agg, N, 1);

    // --- combine: xc = elu(emb @ Wc1^T + bc1), emb gathered from agg ---
    gemm_bfx3_kernel<<<gemmGrid1, blk, 0, stream>>>(
        agg, Wc1, bc1, xc, nullptr, N, 384, (size_t)N * 128, (size_t)0, (size_t)0);

    // --- layer 2 ---
    gemm_bfx3_kernel<<<gemmGrid, blk, 0, stream>>>(
        xc, W2, nullptr, nullptr, xlin, N, 128, (size_t)0, (size_t)128 * 128, (size_t)N * 128);
    small_mm_nn_kernel<<<(3 * 128 * 128 + THREADS - 1) / THREADS, blk, 0, stream>>>(W2, A2, T);
    att_reduce_kernel<<<9, blk, 0, stream>>>(T, W2, bA2, Mraw);
    att_softmax_kernel<<<1, 64, 0, stream>>>(Mraw, att);
    gather_cross_kernel<<<gGather, blk, 0, stream>>>(xlin, dinv, ptr, idx, att, b2, agg, N, 0);

    // --- scoring ---
    edge_score_kernel<<<gScore, blk, 0, stream>>>(agg, edges, edges_neg, out, N, Eev, V);
}

// Round 5
// 873.815 us; speedup vs baseline: 3.2255x; 1.1496x over previous
//
#include <hip/hip_runtime.h>
#include <hip/hip_bf16.h>

// ---------------------------------------------------------------------------
// mGCN: 3-view GCN + cross-view attention, 2 layers, edge scoring.
// R5: dinv-prescaled bf16 xlin (gather = pure sum), 4x16-lane gather groups
//     (4 edges in flight, us8 loads), 2-edge-per-wave scoring.
// Dims: N=50000, D=H=128, V=3, E=800000/view, Eev=100000.
// ---------------------------------------------------------------------------

#define THREADS 256

typedef __bf16 bf16x8 __attribute__((ext_vector_type(8)));
typedef float f32x4 __attribute__((ext_vector_type(4)));
typedef unsigned short us8 __attribute__((ext_vector_type(8)));

__device__ __forceinline__ float eluf(float x) {
    return x > 0.f ? x : expm1f(x);
}

// fp32 -> bf16 bits, round-to-nearest-even
__device__ __forceinline__ unsigned short f2bf(float f) {
    unsigned u = __builtin_bit_cast(unsigned, f);
    u += 0x7FFF + ((u >> 16) & 1);
    return (unsigned short)(u >> 16);
}
__device__ __forceinline__ float bf2f(unsigned short s) {
    unsigned u = ((unsigned)s) << 16;
    return __builtin_bit_cast(float, u);
}

// ---------------------- CSR build ----------------------
__global__ __launch_bounds__(THREADS) void init_int_kernel(int* p, int n) {
    int i = blockIdx.x * THREADS + threadIdx.x;
    if (i < n) p[i] = 0;
}

__global__ __launch_bounds__(THREADS) void hist_kernel(
    const int* __restrict__ ei, int* __restrict__ cnt, int N, int E, int V) {
    int t = blockIdx.x * THREADS + threadIdx.x;
    if (t >= V * E) return;
    int v = t / E, e = t - v * E;
    int col = ei[(size_t)v * 2 * E + E + e];
    atomicAdd(&cnt[v * N + col], 1);
}

__global__ __launch_bounds__(THREADS) void dinv_kernel(
    const int* __restrict__ cnt, float* __restrict__ dinv, int VN) {
    int i = blockIdx.x * THREADS + threadIdx.x;
    if (i < VN) dinv[i] = rsqrtf((float)(cnt[i] + 1));  // +1 self loop
}

// ---- hierarchical exclusive scan ----
#define SC_T 256
#define SC_CHUNK 1024  // SC_T * 4

__global__ __launch_bounds__(SC_T) void scan_sum_kernel(
    const int* __restrict__ cnt, int* __restrict__ bsum, int n) {
    __shared__ int red[SC_T];
    int base = blockIdx.x * SC_CHUNK + threadIdx.x * 4;
    int s = 0;
#pragma unroll
    for (int k = 0; k < 4; k++) {
        int i = base + k;
        if (i < n) s += cnt[i];
    }
    red[threadIdx.x] = s;
    __syncthreads();
    for (int st = SC_T / 2; st; st >>= 1) {
        if (threadIdx.x < st) red[threadIdx.x] += red[threadIdx.x + st];
        __syncthreads();
    }
    if (threadIdx.x == 0) bsum[blockIdx.x] = red[0];
}

__global__ __launch_bounds__(SC_T) void scan_top_kernel(int* bsum, int nb) {
    __shared__ int sh[SC_T];
    int t = threadIdx.x;
    int v = (t < nb) ? bsum[t] : 0;
    sh[t] = v;
    __syncthreads();
    for (int off = 1; off < SC_T; off <<= 1) {
        int u = (t >= off) ? sh[t - off] : 0;
        __syncthreads();
        sh[t] += u;
        __syncthreads();
    }
    if (t < nb) bsum[t] = sh[t] - v;  // exclusive
}

__global__ __launch_bounds__(SC_T) void scan_apply_kernel(
    const int* __restrict__ cnt, const int* __restrict__ bsum,
    int* __restrict__ ptr, int n) {
    __shared__ int sh[SC_T];
    int base = blockIdx.x * SC_CHUNK + threadIdx.x * 4;
    int v[4];
    int s = 0;
#pragma unroll
    for (int k = 0; k < 4; k++) {
        int i = base + k;
        v[k] = (i < n) ? cnt[i] : 0;
        s += v[k];
    }
    int tin = s;
    sh[threadIdx.x] = s;
    __syncthreads();
    for (int off = 1; off < SC_T; off <<= 1) {
        int u = (threadIdx.x >= off) ? sh[threadIdx.x - off] : 0;
        __syncthreads();
        sh[threadIdx.x] += u;
        __syncthreads();
    }
    int run = bsum[blockIdx.x] + sh[threadIdx.x] - tin;
#pragma unroll
    for (int k = 0; k < 4; k++) {
        int i = base + k;
        if (i < n) {
            ptr[i] = run;
            run += v[k];
        }
    }
}

__global__ __launch_bounds__(THREADS) void fill_kernel(
    const int* __restrict__ ei, int* __restrict__ ptr, int* __restrict__ idx,
    int N, int E, int V) {
    int t = blockIdx.x * THREADS + threadIdx.x;
    if (t >= V * E) return;
    int v = t / E, e = t - v * E;
    const int* eiv = ei + (size_t)v * 2 * E;
    int row = eiv[e], col = eiv[E + e];
    int pos = atomicAdd(&ptr[v * N + col], 1);
    idx[pos] = row;
}

// ---------------------- bfx3 MFMA GEMM ----------------------
// C[M,128] = A[M,K] @ B[128,K]^T in split-bf16 (hi+lo), fp32 acc.
// Output: Cbf!=null -> bf16 store of (acc * dscale[z*M+row]); else fp32 elu(acc+bias).
__global__ __launch_bounds__(256) void gemm_bfx3_kernel(
    const float* __restrict__ A, const float* __restrict__ B,
    const float* __restrict__ bias, float* __restrict__ Cf,
    unsigned short* __restrict__ Cbf, const float* __restrict__ dscale,
    int M, int Kb, size_t AV, size_t Bz, size_t Cz) {
    __shared__ unsigned short Ahi[128 * 64];
    __shared__ unsigned short Alo[128 * 64];
    __shared__ unsigned short Bhi[128 * 64];
    __shared__ unsigned short Blo[128 * 64];
    int tid = threadIdx.x;
    int z = blockIdx.z;
    int m0 = blockIdx.x * 128;
    const float* Bp = B + (size_t)z * Bz;
    int lane = tid & 63, wid = tid >> 6;
    int wr = wid >> 1, wc = wid & 1;
    int lr = lane & 15, lg = lane >> 4;
    f32x4 acc[4][4] = {};

    for (int k0 = 0; k0 < Kb; k0 += 64) {
        size_t Abase = (size_t)(k0 >> 7) * AV + (k0 & 127);
        for (int i = 0; i < 4; ++i) {
            int ch = tid + i * 256;  // 0..1023
            int row = ch >> 3, c8 = (ch & 7) << 3;
            int e = (row * 64 + c8) ^ ((row & 7) << 3);
            float va[8];
            int gm = m0 + row;
            if (gm < M) {
                const float* p = A + Abase + (size_t)gm * 128 + c8;
                *(float4*)(va)     = *(const float4*)(p);
                *(float4*)(va + 4) = *(const float4*)(p + 4);
            } else {
#pragma unroll
                for (int j = 0; j < 8; j++) va[j] = 0.f;
            }
            us8 h8, l8;
#pragma unroll
            for (int j = 0; j < 8; j++) {
                unsigned short h = f2bf(va[j]);
                h8[j] = h;
                l8[j] = f2bf(va[j] - bf2f(h));
            }
            *(us8*)&Ahi[e] = h8;
            *(us8*)&Alo[e] = l8;
            float vb[8];
            const float* q = Bp + (size_t)row * Kb + k0 + c8;
            *(float4*)(vb)     = *(const float4*)(q);
            *(float4*)(vb + 4) = *(const float4*)(q + 4);
#pragma unroll
            for (int j = 0; j < 8; j++) {
                unsigned short h = f2bf(vb[j]);
                h8[j] = h;
                l8[j] = f2bf(vb[j] - bf2f(h));
            }
            *(us8*)&Bhi[e] = h8;
            *(us8*)&Blo[e] = l8;
        }
        __syncthreads();
#pragma unroll
        for (int ks = 0; ks < 2; ++ks) {
            bf16x8 ah[4], al[4], bh[4], bl[4];
#pragma unroll
            for (int m = 0; m < 4; m++) {
                int row = wr * 64 + m * 16 + lr;
                int e = (row * 64 + ks * 32 + lg * 8) ^ ((row & 7) << 3);
                ah[m] = *(const bf16x8*)&Ahi[e];
                al[m] = *(const bf16x8*)&Alo[e];
            }
#pragma unroll
            for (int n = 0; n < 4; n++) {
                int col = wc * 64 + n * 16 + lr;
                int e = (col * 64 + ks * 32 + lg * 8) ^ ((col & 7) << 3);
                bh[n] = *(const bf16x8*)&Bhi[e];
                bl[n] = *(const bf16x8*)&Blo[e];
            }
#pragma unroll
            for (int m = 0; m < 4; m++)
#pragma unroll
                for (int n = 0; n < 4; n++) {
                    acc[m][n] = __builtin_amdgcn_mfma_f32_16x16x32_bf16(ah[m], bh[n], acc[m][n], 0, 0, 0);
                    acc[m][n] = __builtin_amdgcn_mfma_f32_16x16x32_bf16(ah[m], bl[n], acc[m][n], 0, 0, 0);
                    acc[m][n] = __builtin_amdgcn_mfma_f32_16x16x32_bf16(al[m], bh[n], acc[m][n], 0, 0, 0);
                }
        }
        __syncthreads();
    }

#pragma unroll
    for (int m = 0; m < 4; m++) {
        int rbase = m0 + wr * 64 + m * 16 + lg * 4;
#pragma unroll
        for (int n = 0; n < 4; n++) {
            int col = wc * 64 + n * 16 + lr;
#pragma unroll
            for (int j = 0; j < 4; j++) {
                int row = rbase + j;
                if (row < M) {
                    float vv = acc[m][n][j];
                    if (Cbf) {
                        float sc = dscale[(size_t)z * M + row];
                        Cbf[(size_t)z * Cz + (size_t)row * 128 + col] = f2bf(vv * sc);
                    } else {
                        Cf[(size_t)z * Cz + (size_t)row * 128 + col] = eluf(vv + bias[col]);
                    }
                }
            }
        }
    }
}

// ---------------------- attention ----------------------
__global__ __launch_bounds__(THREADS) void small_mm_nn_kernel(
    const float* __restrict__ W, const float* __restrict__ A, float* __restrict__ T) {
    int idx = blockIdx.x * THREADS + threadIdx.x;
    if (idx >= 3 * 128 * 128) return;
    int b = idx & 127;
    int vk = idx >> 7;
    const float* w = W + (size_t)vk * 128;
    float s = 0.f;
#pragma unroll 8
    for (int a = 0; a < 128; a++) s += w[a] * A[a * 128 + b];
    T[idx] = s;
}

__global__ __launch_bounds__(THREADS) void att_reduce_kernel(
    const float* __restrict__ T, const float* __restrict__ W,
    const float* __restrict__ bA, float* __restrict__ Mraw) {
    int v = blockIdx.x / 3, w = blockIdx.x % 3;
    const float* tp = T + (size_t)v * 16384;
    const float* wp = W + (size_t)w * 16384;
    float s = 0.f;
    for (int i = threadIdx.x; i < 16384; i += THREADS) s += tp[i] * wp[i];
    __shared__ float red[THREADS];
    red[threadIdx.x] = s;
    __syncthreads();
    for (int st = THREADS / 2; st; st >>= 1) {
        if (threadIdx.x < st) red[threadIdx.x] += red[threadIdx.x + st];
        __syncthreads();
    }
    if (threadIdx.x == 0) Mraw[blockIdx.x] = red[0] + 128.f * bA[0];
}

__global__ void att_softmax_kernel(const float* __restrict__ Mraw, float* __restrict__ att) {
    int v = threadIdx.x;
    if (v >= 3) return;
    float m0 = Mraw[v * 3 + 0], m1 = Mraw[v * 3 + 1], m2 = Mraw[v * 3 + 2];
    float mx = fmaxf(m0, fmaxf(m1, m2));
    float e0 = expf(m0 - mx), e1 = expf(m1 - mx), e2 = expf(m2 - mx);
    float s = e0 + e1 + e2;
    att[v * 3 + 0] = e0 / s;
    att[v * 3 + 1] = e1 / s;
    att[v * 3 + 2] = e2 / s;
}

// ---------------------- fused GCN gather + cross_rep ----------------------
// xs = bf16(dinv[row] * h[row]) prescaled. One wave per (v,n); 4 groups of 16
// lanes each own one edge (stride 4); lane owns 8 features (us8 = 16B load).
// agg = dc * (sum_edges xs[row] + xs[self]); cross recovers h via 1/dinv.
__global__ __launch_bounds__(THREADS) void gather_cross_kernel(
    const unsigned short* __restrict__ xs, const float* __restrict__ dinv,
    const int* __restrict__ ptr, const int* __restrict__ idx,
    const float* __restrict__ att, const float* __restrict__ bias,
    float* __restrict__ xr, int N, int elu_inner) {
    int wv = (blockIdx.x * THREADS + threadIdx.x) >> 6;
    int lane = threadIdx.x & 63;
    int VN = 3 * N;
    if (wv >= VN) return;
    int v = wv / N;
    int n = wv - v * N;
    int vN = v * N;
    int g = lane >> 4, f0 = (lane & 15) * 8;

    float acc[8] = {};
    int s = (wv == 0) ? 0 : ptr[wv - 1];
    int e = ptr[wv];
    for (int j = s + g; j < e; j += 4) {
        int r = idx[j];
        us8 u = *(const us8*)(xs + (((size_t)(vN + r)) << 7) + f0);
#pragma unroll
        for (int i = 0; i < 8; i++) acc[i] += bf2f(u[i]);
    }
#pragma unroll
    for (int i = 0; i < 8; i++) {
        acc[i] += __shfl_xor(acc[i], 16);
        acc[i] += __shfl_xor(acc[i], 32);
    }

    // self + cross sources
    us8 su = *(const us8*)(xs + (((size_t)wv) << 7) + f0);
    float dc = dinv[wv];
    size_t nb = (((size_t)n) << 7) + f0;
    size_t NH = ((size_t)N) << 7;
    us8 c0 = *(const us8*)(xs + nb);
    us8 c1 = *(const us8*)(xs + NH + nb);
    us8 c2 = *(const us8*)(xs + 2 * NH + nb);
    float wa = att[v * 3 + 0] / dinv[n];
    float wb = att[v * 3 + 1] / dinv[N + n];
    float wc = att[v * 3 + 2] / dinv[2 * N + n];
    float4 bb0 = *(const float4*)(bias + v * 128 + f0);
    float4 bb1 = *(const float4*)(bias + v * 128 + f0 + 4);
    float bv[8] = {bb0.x, bb0.y, bb0.z, bb0.w, bb1.x, bb1.y, bb1.z, bb1.w};

    float ov[8];
#pragma unroll
    for (int i = 0; i < 8; i++) {
        float a = dc * (acc[i] + bf2f(su[i])) + bv[i];
        if (elu_inner) a = eluf(a);
        float cr = wa * bf2f(c0[i]) + wb * bf2f(c1[i]) + wc * bf2f(c2[i]);
        ov[i] = 0.5f + a + eluf(0.5f * cr);
    }
    if (g == 0) {
        float4 o0 = {ov[0], ov[1], ov[2], ov[3]};
        float4 o1 = {ov[4], ov[5], ov[6], ov[7]};
        *(float4*)(xr + (((size_t)wv) << 7) + f0)     = o0;
        *(float4*)(xr + (((size_t)wv) << 7) + f0 + 4) = o1;
    }
}

// ---------------------- edge scoring: 2 edges per wave (32-lane halves) ----------------------
__global__ __launch_bounds__(THREADS) void edge_score_kernel(
    const float* __restrict__ xr2, const int* __restrict__ edges,
    const int* __restrict__ edges_neg, float* __restrict__ out, int N, int Eev, int V) {
    int half = (blockIdx.x * THREADS + threadIdx.x) >> 5;
    int l32 = threadIdx.x & 31;
    int total = V * 2 * Eev;
    if (half >= total) return;
    int v = half / (2 * Eev);
    int r = half - v * (2 * Eev);
    const int* ep;
    if (r < Eev)
        ep = edges + ((size_t)v * Eev + r) * 2;
    else
        ep = edges_neg + ((size_t)v * Eev + (r - Eev)) * 2;
    int a = ep[0], b = ep[1];
    const float4* pa = (const float4*)(xr2 + (((size_t)v * N + a)) * 128);
    const float4* pb = (const float4*)(xr2 + (((size_t)v * N + b)) * 128);
    float4 ua = pa[l32], ub = pb[l32];
    float s = ua.x * ub.x + ua.y * ub.y + ua.z * ub.z + ua.w * ub.w;
#pragma unroll
    for (int off = 16; off; off >>= 1) s += __shfl_xor(s, off, 32);
    if (l32 == 0) out[half] = s;
}

// ---------------------------------------------------------------------------
extern "C" void kernel_launch(void* const* d_in, const int* in_sizes, int n_in,
                              void* d_out, int out_size, void* d_ws, size_t ws_size,
                              hipStream_t stream) {
    const float* x   = (const float*)d_in[0];
    const float* W1  = (const float*)d_in[1];
    const float* b1  = (const float*)d_in[2];
    const float* W2  = (const float*)d_in[3];
    const float* b2  = (const float*)d_in[4];
    const float* A1  = (const float*)d_in[5];
    const float* bA1 = (const float*)d_in[6];
    const float* A2  = (const float*)d_in[7];
    const float* bA2 = (const float*)d_in[8];
    const float* Wc1 = (const float*)d_in[9];
    const float* bc1 = (const float*)d_in[10];
    const int* ei        = (const int*)d_in[13];
    const int* edges     = (const int*)d_in[14];
    const int* edges_neg = (const int*)d_in[15];
    float* out = (float*)d_out;

    const int H = 128, V = 3;
    const int N = in_sizes[0] / H;          // 50000
    const int E = in_sizes[13] / (V * 2);   // 800000
    const int Eev = in_sizes[14] / (V * 2); // 100000
    const int VNH = V * N * H;
    const int VN = V * N;
    const int VE = V * E;

    // workspace partition
    float* ws   = (float*)d_ws;
    float* agg  = ws;                  // VNH (xr1 then xr2)
    float* xc   = agg + VNH;           // N*H
    float* dinv = xc + (size_t)N * H;  // VN
    float* T    = dinv + VN;           // 3*128*128
    float* Mraw = T + 3 * 128 * 128;   // 16
    float* att  = Mraw + 16;           // 16
    int* cnt  = (int*)(att + 16);      // VN
    int* ptr  = cnt + VN;              // VN
    int* bsum = ptr + VN;              // 256
    int* idx  = bsum + 256;            // VE
    unsigned short* xs = (unsigned short*)(idx + VE);  // VNH bf16 (prescaled)
    (void)ws_size; (void)n_in; (void)out_size;

    dim3 blk(THREADS);
    int gVN = (VN + THREADS - 1) / THREADS;
    int gVE = (VE + THREADS - 1) / THREADS;
    int gGather = (int)(((size_t)VN * 64 + THREADS - 1) / THREADS);
    int nScanB = (VN + SC_CHUNK - 1) / SC_CHUNK;  // 147 <= 256
    dim3 gemmGrid((N + 127) / 128, 1, V);
    dim3 gemmGrid1((N + 127) / 128, 1, 1);
    int gScore = (int)(((size_t)V * 2 * Eev * 32 + THREADS - 1) / THREADS);

    // --- CSR build (shared by both layers) ---
    init_int_kernel<<<gVN, blk, 0, stream>>>(cnt, VN);
    hist_kernel<<<gVE, blk, 0, stream>>>(ei, cnt, N, E, V);
    dinv_kernel<<<gVN, blk, 0, stream>>>(cnt, dinv, VN);
    scan_sum_kernel<<<nScanB, SC_T, 0, stream>>>(cnt, bsum, VN);
    scan_top_kernel<<<1, SC_T, 0, stream>>>(bsum, nScanB);
    scan_apply_kernel<<<nScanB, SC_T, 0, stream>>>(cnt, bsum, ptr, VN);
    fill_kernel<<<gVE, blk, 0, stream>>>(ei, ptr, idx, N, E, V);

    // --- layer 1 ---
    gemm_bfx3_kernel<<<gemmGrid, blk, 0, stream>>>(
        x, W1, nullptr, nullptr, xs, dinv, N, 128, (size_t)0, (size_t)128 * 128, (size_t)N * 128);
    small_mm_nn_kernel<<<(3 * 128 * 128 + THREADS - 1) / THREADS, blk, 0, stream>>>(W1, A1, T);
    att_reduce_kernel<<<9, blk, 0, stream>>>(T, W1, bA1, Mraw);
    att_softmax_kernel<<<1, 64, 0, stream>>>(Mraw, att);
    gather_cross_kernel<<<gGather, blk, 0, stream>>>(xs, dinv, ptr, idx, att, b1, agg, N, 1);

    // --- combine: xc = elu(emb @ Wc1^T + bc1), emb gathered from agg ---
    gemm_bfx3_kernel<<<gemmGrid1, blk, 0, stream>>>(
        agg, Wc1, bc1, xc, nullptr, nullptr, N, 384, (size_t)N * 128, (size_t)0, (size_t)0);

    // --- layer 2 ---
    gemm_bfx3_kernel<<<gemmGrid, blk, 0, stream>>>(
        xc, W2, nullptr, nullptr, xs, dinv, N, 128, (size_t)0, (size_t)128 * 128, (size_t)N * 128);
    small_mm_nn_kernel<<<(3 * 128 * 128 + THREADS - 1) / THREADS, blk, 0, stream>>>(W2, A2, T);
    att_reduce_kernel<<<9, blk, 0, stream>>>(T, W2, bA2, Mraw);
    att_softmax_kernel<<<1, 64, 0, stream>>>(Mraw, att);
    gather_cross_kernel<<<gGather, blk, 0, stream>>>(xs, dinv, ptr, idx, att, b2, agg, N, 0);

    // --- scoring ---
    edge_score_kernel<<<gScore, blk, 0, stream>>>(agg, edges, edges_neg, out, N, Eev, V);
}

// Round 6
// 858.713 us; speedup vs baseline: 3.2822x; 1.0176x over previous
//
#include <hip/hip_runtime.h>
#include <hip/hip_bf16.h>

// ---------------------------------------------------------------------------
// mGCN: 3-view GCN + cross-view attention, 2 layers, edge scoring.
// R6: bucketed CSR build (LDS-local scatter, no hot global atomics),
//     single-MFMA bf16 layer GEMMs (bfx3 kept for combine), 8-deep gather MLP.
// Dims: N=50000, D=H=128, V=3, E=800000/view, Eev=100000.
// ---------------------------------------------------------------------------

#define THREADS 256
#define BCH 8192   // edges per bucket-chunk block

typedef __bf16 bf16x8 __attribute__((ext_vector_type(8)));
typedef float f32x4 __attribute__((ext_vector_type(4)));
typedef unsigned short us8 __attribute__((ext_vector_type(8)));

__device__ __forceinline__ float eluf(float x) {
    return x > 0.f ? x : expm1f(x);
}

__device__ __forceinline__ unsigned short f2bf(float f) {
    unsigned u = __builtin_bit_cast(unsigned, f);
    u += 0x7FFF + ((u >> 16) & 1);
    return (unsigned short)(u >> 16);
}
__device__ __forceinline__ float bf2f(unsigned short s) {
    unsigned u = ((unsigned)s) << 16;
    return __builtin_bit_cast(float, u);
}

// ---------------------- misc ----------------------
__global__ __launch_bounds__(THREADS) void init_int_kernel(int* p, int n) {
    int i = blockIdx.x * THREADS + threadIdx.x;
    if (i < n) p[i] = 0;
}

__global__ __launch_bounds__(THREADS) void dinv_kernel(
    const int* __restrict__ cnt, float* __restrict__ dinv, int VN) {
    int i = blockIdx.x * THREADS + threadIdx.x;
    if (i < VN) dinv[i] = rsqrtf((float)(cnt[i] + 1));  // +1 self loop
}

// ---------------------- bucketed CSR build ----------------------
// bucket(g) = g >> 10, g = v*N+col in [0, VN), NB = ceil(VN/1024) <= 160.

// P1: per-chunk LDS bucket histogram -> global bcnt
__global__ __launch_bounds__(THREADS) void bucket_count_kernel(
    const int* __restrict__ ei, int* __restrict__ bcnt, int N, int E, int VE) {
    __shared__ int h[160];
    for (int i = threadIdx.x; i < 160; i += THREADS) h[i] = 0;
    __syncthreads();
    int base = blockIdx.x * BCH;
    for (int k = 0; k < BCH; k += THREADS) {
        int t = base + k + threadIdx.x;
        if (t < VE) {
            int v = (t >= E) + (t >= 2 * E);
            int e = t - v * E;
            int col = ei[(size_t)v * 2 * E + E + e];
            atomicAdd(&h[(v * N + col) >> 10], 1);
        }
    }
    __syncthreads();
    for (int i = threadIdx.x; i < 160; i += THREADS)
        if (h[i]) atomicAdd(&bcnt[i], h[i]);
}

// P2: single-block scan of bucket counts -> bstart[0..nb], bofs cursors
__global__ __launch_bounds__(THREADS) void bucket_scan_kernel(
    const int* __restrict__ bcnt, int* __restrict__ bstart, int* __restrict__ bofs, int nb) {
    __shared__ int sh[THREADS];
    int t = threadIdx.x;
    int v = (t < nb) ? bcnt[t] : 0;
    sh[t] = v;
    __syncthreads();
    for (int off = 1; off < THREADS; off <<= 1) {
        int u = (t >= off) ? sh[t - off] : 0;
        __syncthreads();
        sh[t] += u;
        __syncthreads();
    }
    int excl = sh[t] - v;
    if (t < nb) { bstart[t] = excl; bofs[t] = excl; }
    if (t == nb - 1) bstart[nb] = sh[t];
}

// P3: scatter edges into bucket-sorted COO (block claims ranges per bucket)
__global__ __launch_bounds__(THREADS) void bucket_scatter_kernel(
    const int* __restrict__ ei, int* __restrict__ bofs,
    int* __restrict__ coo_g, int* __restrict__ coo_r, int N, int E, int VE) {
    __shared__ int h[160];
    __shared__ int cur[160];
    for (int i = threadIdx.x; i < 160; i += THREADS) h[i] = 0;
    __syncthreads();
    int base = blockIdx.x * BCH;
    for (int k = 0; k < BCH; k += THREADS) {
        int t = base + k + threadIdx.x;
        if (t < VE) {
            int v = (t >= E) + (t >= 2 * E);
            int e = t - v * E;
            int col = ei[(size_t)v * 2 * E + E + e];
            atomicAdd(&h[(v * N + col) >> 10], 1);
        }
    }
    __syncthreads();
    if (threadIdx.x < 160 && h[threadIdx.x])
        cur[threadIdx.x] = atomicAdd(&bofs[threadIdx.x], h[threadIdx.x]);
    __syncthreads();
    for (int k = 0; k < BCH; k += THREADS) {
        int t = base + k + threadIdx.x;
        if (t < VE) {
            int v = (t >= E) + (t >= 2 * E);
            int e = t - v * E;
            const int* eiv = ei + (size_t)v * 2 * E;
            int row = eiv[e], col = eiv[E + e];
            int g = v * N + col;
            int pos = atomicAdd(&cur[g >> 10], 1);
            coo_g[pos] = g;
            coo_r[pos] = row;
        }
    }
}

// P4a: per-bucket node histogram -> cnt (replaces global-atomic hist)
__global__ __launch_bounds__(THREADS) void bucket_hist_kernel(
    const int* __restrict__ coo_g, const int* __restrict__ bstart,
    int* __restrict__ cnt, int VN) {
    __shared__ int h[1024];
    for (int i = threadIdx.x; i < 1024; i += THREADS) h[i] = 0;
    __syncthreads();
    int b = blockIdx.x;
    int s = bstart[b], e = bstart[b + 1];
    for (int i = s + threadIdx.x; i < e; i += THREADS)
        atomicAdd(&h[coo_g[i] & 1023], 1);
    __syncthreads();
    int g0 = b << 10;
    for (int i = threadIdx.x; i < 1024; i += THREADS)
        if (g0 + i < VN) cnt[g0 + i] = h[i];
}

// P4b: per-bucket CSR fill with LDS cursors; ptr: starts -> ends
__global__ __launch_bounds__(THREADS) void bucket_fill_kernel(
    const int* __restrict__ coo_g, const int* __restrict__ coo_r,
    const int* __restrict__ bstart, int* __restrict__ ptr,
    int* __restrict__ idx, int VN) {
    __shared__ int p[1024];
    int b = blockIdx.x, g0 = b << 10;
    for (int i = threadIdx.x; i < 1024; i += THREADS)
        p[i] = (g0 + i < VN) ? ptr[g0 + i] : 0;
    __syncthreads();
    int s = bstart[b], e = bstart[b + 1];
    for (int i = s + threadIdx.x; i < e; i += THREADS) {
        int pos = atomicAdd(&p[coo_g[i] & 1023], 1);
        idx[pos] = coo_r[i];
    }
    __syncthreads();
    for (int i = threadIdx.x; i < 1024; i += THREADS)
        if (g0 + i < VN) ptr[g0 + i] = p[i];
}

// ---- hierarchical exclusive scan over node counts ----
#define SC_T 256
#define SC_CHUNK 1024

__global__ __launch_bounds__(SC_T) void scan_sum_kernel(
    const int* __restrict__ cnt, int* __restrict__ bsum, int n) {
    __shared__ int red[SC_T];
    int base = blockIdx.x * SC_CHUNK + threadIdx.x * 4;
    int s = 0;
#pragma unroll
    for (int k = 0; k < 4; k++) {
        int i = base + k;
        if (i < n) s += cnt[i];
    }
    red[threadIdx.x] = s;
    __syncthreads();
    for (int st = SC_T / 2; st; st >>= 1) {
        if (threadIdx.x < st) red[threadIdx.x] += red[threadIdx.x + st];
        __syncthreads();
    }
    if (threadIdx.x == 0) bsum[blockIdx.x] = red[0];
}

__global__ __launch_bounds__(SC_T) void scan_top_kernel(int* bsum, int nb) {
    __shared__ int sh[SC_T];
    int t = threadIdx.x;
    int v = (t < nb) ? bsum[t] : 0;
    sh[t] = v;
    __syncthreads();
    for (int off = 1; off < SC_T; off <<= 1) {
        int u = (t >= off) ? sh[t - off] : 0;
        __syncthreads();
        sh[t] += u;
        __syncthreads();
    }
    if (t < nb) bsum[t] = sh[t] - v;  // exclusive
}

__global__ __launch_bounds__(SC_T) void scan_apply_kernel(
    const int* __restrict__ cnt, const int* __restrict__ bsum,
    int* __restrict__ ptr, int n) {
    __shared__ int sh[SC_T];
    int base = blockIdx.x * SC_CHUNK + threadIdx.x * 4;
    int v[4];
    int s = 0;
#pragma unroll
    for (int k = 0; k < 4; k++) {
        int i = base + k;
        v[k] = (i < n) ? cnt[i] : 0;
        s += v[k];
    }
    int tin = s;
    sh[threadIdx.x] = s;
    __syncthreads();
    for (int off = 1; off < SC_T; off <<= 1) {
        int u = (threadIdx.x >= off) ? sh[threadIdx.x - off] : 0;
        __syncthreads();
        sh[threadIdx.x] += u;
        __syncthreads();
    }
    int run = bsum[blockIdx.x] + sh[threadIdx.x] - tin;
#pragma unroll
    for (int k = 0; k < 4; k++) {
        int i = base + k;
        if (i < n) {
            ptr[i] = run;
            run += v[k];
        }
    }
}

// ---------------------- MFMA GEMM (template: split-bf16 or plain bf16) ----------------------
// C[M,128] = A[M,K] @ B[128,K]^T, fp32 acc.
// SPLIT3=1: hi+lo split (fp32-grade), LDS 64KB. SPLIT3=0: plain bf16, LDS 32KB.
// A elem (m, k0+c) at A[(k0>>7)*AV + (k0&127) + m*128 + c].
// Output: Cbf!=null -> bf16 store of acc*dscale[z*M+row]; else fp32 elu(acc+bias).
template <int SPLIT3>
__global__ __launch_bounds__(256) void gemm_mfma_kernel(
    const float* __restrict__ A, const float* __restrict__ B,
    const float* __restrict__ bias, float* __restrict__ Cf,
    unsigned short* __restrict__ Cbf, const float* __restrict__ dscale,
    int M, int Kb, size_t AV, size_t Bz, size_t Cz) {
    extern __shared__ unsigned short sm[];
    unsigned short* Ahi = sm;            // 128*64
    unsigned short* Bhi = sm + 8192;
    unsigned short* Alo = SPLIT3 ? sm + 16384 : nullptr;
    unsigned short* Blo = SPLIT3 ? sm + 24576 : nullptr;
    int tid = threadIdx.x;
    int z = blockIdx.z;
    int m0 = blockIdx.x * 128;
    const float* Bp = B + (size_t)z * Bz;
    int lane = tid & 63, wid = tid >> 6;
    int wr = wid >> 1, wc = wid & 1;
    int lr = lane & 15, lg = lane >> 4;
    f32x4 acc[4][4] = {};

    for (int k0 = 0; k0 < Kb; k0 += 64) {
        size_t Abase = (size_t)(k0 >> 7) * AV + (k0 & 127);
        for (int i = 0; i < 4; ++i) {
            int ch = tid + i * 256;  // 0..1023
            int row = ch >> 3, c8 = (ch & 7) << 3;
            int e = (row * 64 + c8) ^ ((row & 7) << 3);
            float va[8];
            int gm = m0 + row;
            if (gm < M) {
                const float* p = A + Abase + (size_t)gm * 128 + c8;
                *(float4*)(va)     = *(const float4*)(p);
                *(float4*)(va + 4) = *(const float4*)(p + 4);
            } else {
#pragma unroll
                for (int j = 0; j < 8; j++) va[j] = 0.f;
            }
            us8 h8, l8;
#pragma unroll
            for (int j = 0; j < 8; j++) {
                unsigned short h = f2bf(va[j]);
                h8[j] = h;
                if (SPLIT3) l8[j] = f2bf(va[j] - bf2f(h));
            }
            *(us8*)&Ahi[e] = h8;
            if (SPLIT3) *(us8*)&Alo[e] = l8;
            float vb[8];
            const float* q = Bp + (size_t)row * Kb + k0 + c8;
            *(float4*)(vb)     = *(const float4*)(q);
            *(float4*)(vb + 4) = *(const float4*)(q + 4);
#pragma unroll
            for (int j = 0; j < 8; j++) {
                unsigned short h = f2bf(vb[j]);
                h8[j] = h;
                if (SPLIT3) l8[j] = f2bf(vb[j] - bf2f(h));
            }
            *(us8*)&Bhi[e] = h8;
            if (SPLIT3) *(us8*)&Blo[e] = l8;
        }
        __syncthreads();
#pragma unroll
        for (int ks = 0; ks < 2; ++ks) {
            bf16x8 ah[4], al[4], bh[4], bl[4];
#pragma unroll
            for (int m = 0; m < 4; m++) {
                int row = wr * 64 + m * 16 + lr;
                int e = (row * 64 + ks * 32 + lg * 8) ^ ((row & 7) << 3);
                ah[m] = *(const bf16x8*)&Ahi[e];
                if (SPLIT3) al[m] = *(const bf16x8*)&Alo[e];
            }
#pragma unroll
            for (int n = 0; n < 4; n++) {
                int col = wc * 64 + n * 16 + lr;
                int e = (col * 64 + ks * 32 + lg * 8) ^ ((col & 7) << 3);
                bh[n] = *(const bf16x8*)&Bhi[e];
                if (SPLIT3) bl[n] = *(const bf16x8*)&Blo[e];
            }
#pragma unroll
            for (int m = 0; m < 4; m++)
#pragma unroll
                for (int n = 0; n < 4; n++) {
                    acc[m][n] = __builtin_amdgcn_mfma_f32_16x16x32_bf16(ah[m], bh[n], acc[m][n], 0, 0, 0);
                    if (SPLIT3) {
                        acc[m][n] = __builtin_amdgcn_mfma_f32_16x16x32_bf16(ah[m], bl[n], acc[m][n], 0, 0, 0);
                        acc[m][n] = __builtin_amdgcn_mfma_f32_16x16x32_bf16(al[m], bh[n], acc[m][n], 0, 0, 0);
                    }
                }
        }
        __syncthreads();
    }

#pragma unroll
    for (int m = 0; m < 4; m++) {
        int rbase = m0 + wr * 64 + m * 16 + lg * 4;
#pragma unroll
        for (int n = 0; n < 4; n++) {
            int col = wc * 64 + n * 16 + lr;
#pragma unroll
            for (int j = 0; j < 4; j++) {
                int row = rbase + j;
                if (row < M) {
                    float vv = acc[m][n][j];
                    if (Cbf) {
                        float sc = dscale[(size_t)z * M + row];
                        Cbf[(size_t)z * Cz + (size_t)row * 128 + col] = f2bf(vv * sc);
                    } else {
                        Cf[(size_t)z * Cz + (size_t)row * 128 + col] = eluf(vv + bias[col]);
                    }
                }
            }
        }
    }
}

// ---------------------- attention ----------------------
__global__ __launch_bounds__(THREADS) void small_mm_nn_kernel(
    const float* __restrict__ W, const float* __restrict__ A, float* __restrict__ T) {
    int idx = blockIdx.x * THREADS + threadIdx.x;
    if (idx >= 3 * 128 * 128) return;
    int b = idx & 127;
    int vk = idx >> 7;
    const float* w = W + (size_t)vk * 128;
    float s = 0.f;
#pragma unroll 8
    for (int a = 0; a < 128; a++) s += w[a] * A[a * 128 + b];
    T[idx] = s;
}

__global__ __launch_bounds__(THREADS) void att_reduce_kernel(
    const float* __restrict__ T, const float* __restrict__ W,
    const float* __restrict__ bA, float* __restrict__ Mraw) {
    int v = blockIdx.x / 3, w = blockIdx.x % 3;
    const float* tp = T + (size_t)v * 16384;
    const float* wp = W + (size_t)w * 16384;
    float s = 0.f;
    for (int i = threadIdx.x; i < 16384; i += THREADS) s += tp[i] * wp[i];
    __shared__ float red[THREADS];
    red[threadIdx.x] = s;
    __syncthreads();
    for (int st = THREADS / 2; st; st >>= 1) {
        if (threadIdx.x < st) red[threadIdx.x] += red[threadIdx.x + st];
        __syncthreads();
    }
    if (threadIdx.x == 0) Mraw[blockIdx.x] = red[0] + 128.f * bA[0];
}

__global__ void att_softmax_kernel(const float* __restrict__ Mraw, float* __restrict__ att) {
    int v = threadIdx.x;
    if (v >= 3) return;
    float m0 = Mraw[v * 3 + 0], m1 = Mraw[v * 3 + 1], m2 = Mraw[v * 3 + 2];
    float mx = fmaxf(m0, fmaxf(m1, m2));
    float e0 = expf(m0 - mx), e1 = expf(m1 - mx), e2 = expf(m2 - mx);
    float s = e0 + e1 + e2;
    att[v * 3 + 0] = e0 / s;
    att[v * 3 + 1] = e1 / s;
    att[v * 3 + 2] = e2 / s;
}

// ---------------------- fused GCN gather + cross_rep ----------------------
// xs = bf16(dinv[row]*h[row]). One wave per (v,n); 8 groups of 8 lanes each
// own one edge (stride 8); each edge row read as 2x us8 per lane (16 feats).
__global__ __launch_bounds__(THREADS) void gather_cross_kernel(
    const unsigned short* __restrict__ xs, const float* __restrict__ dinv,
    const int* __restrict__ ptr, const int* __restrict__ idx,
    const float* __restrict__ att, const float* __restrict__ bias,
    float* __restrict__ xr, int N, int elu_inner) {
    int wv = (blockIdx.x * THREADS + threadIdx.x) >> 6;
    int lane = threadIdx.x & 63;
    int VN = 3 * N;
    if (wv >= VN) return;
    int v = wv / N;
    int n = wv - v * N;
    int vN = v * N;
    int g = lane >> 3, f0 = (lane & 7) * 8;

    float acc[16] = {};
    int s = (wv == 0) ? 0 : ptr[wv - 1];
    int e = ptr[wv];
    for (int j = s + g; j < e; j += 8) {
        int r = idx[j];
        const unsigned short* rp = xs + (((size_t)(vN + r)) << 7);
        us8 u0 = *(const us8*)(rp + f0);
        us8 u1 = *(const us8*)(rp + 64 + f0);
#pragma unroll
        for (int i = 0; i < 8; i++) {
            acc[i]     += bf2f(u0[i]);
            acc[8 + i] += bf2f(u1[i]);
        }
    }
#pragma unroll
    for (int i = 0; i < 16; i++) {
        acc[i] += __shfl_xor(acc[i], 8);
        acc[i] += __shfl_xor(acc[i], 16);
        acc[i] += __shfl_xor(acc[i], 32);
    }

    // self + cross sources (features f0..f0+7 and 64+f0..64+f0+7)
    const unsigned short* sp = xs + (((size_t)wv) << 7);
    us8 su0 = *(const us8*)(sp + f0);
    us8 su1 = *(const us8*)(sp + 64 + f0);
    float dc = dinv[wv];
    size_t nb = (((size_t)n) << 7) + f0;
    size_t NH = ((size_t)N) << 7;
    us8 c00 = *(const us8*)(xs + nb),           c01 = *(const us8*)(xs + nb + 64);
    us8 c10 = *(const us8*)(xs + NH + nb),      c11 = *(const us8*)(xs + NH + nb + 64);
    us8 c20 = *(const us8*)(xs + 2 * NH + nb),  c21 = *(const us8*)(xs + 2 * NH + nb + 64);
    float wa = att[v * 3 + 0] / dinv[n];
    float wb = att[v * 3 + 1] / dinv[N + n];
    float wc = att[v * 3 + 2] / dinv[2 * N + n];
    float4 bb0 = *(const float4*)(bias + v * 128 + f0);
    float4 bb1 = *(const float4*)(bias + v * 128 + f0 + 4);
    float4 bb2 = *(const float4*)(bias + v * 128 + 64 + f0);
    float4 bb3 = *(const float4*)(bias + v * 128 + 64 + f0 + 4);
    float bv[16] = {bb0.x, bb0.y, bb0.z, bb0.w, bb1.x, bb1.y, bb1.z, bb1.w,
                    bb2.x, bb2.y, bb2.z, bb2.w, bb3.x, bb3.y, bb3.z, bb3.w};

    float ov[16];
#pragma unroll
    for (int i = 0; i < 8; i++) {
        float a = dc * (acc[i] + bf2f(su0[i])) + bv[i];
        if (elu_inner) a = eluf(a);
        float cr = wa * bf2f(c00[i]) + wb * bf2f(c10[i]) + wc * bf2f(c20[i]);
        ov[i] = 0.5f + a + eluf(0.5f * cr);
        float a2 = dc * (acc[8 + i] + bf2f(su1[i])) + bv[8 + i];
        if (elu_inner) a2 = eluf(a2);
        float cr2 = wa * bf2f(c01[i]) + wb * bf2f(c11[i]) + wc * bf2f(c21[i]);
        ov[8 + i] = 0.5f + a2 + eluf(0.5f * cr2);
    }
    float* op = xr + (((size_t)wv) << 7);
    if (lane < 8) {  // group 0: features f0..f0+7
        float4 o0 = {ov[0], ov[1], ov[2], ov[3]};
        float4 o1 = {ov[4], ov[5], ov[6], ov[7]};
        *(float4*)(op + f0)     = o0;
        *(float4*)(op + f0 + 4) = o1;
    } else if (lane < 16) {  // group 1: features 64+f0..
        float4 o0 = {ov[8], ov[9], ov[10], ov[11]};
        float4 o1 = {ov[12], ov[13], ov[14], ov[15]};
        *(float4*)(op + 64 + f0)     = o0;
        *(float4*)(op + 64 + f0 + 4) = o1;
    }
}

// ---------------------- edge scoring: 2 edges per wave (32-lane halves) ----------------------
__global__ __launch_bounds__(THREADS) void edge_score_kernel(
    const float* __restrict__ xr2, const int* __restrict__ edges,
    const int* __restrict__ edges_neg, float* __restrict__ out, int N, int Eev, int V) {
    int half = (blockIdx.x * THREADS + threadIdx.x) >> 5;
    int l32 = threadIdx.x & 31;
    int total = V * 2 * Eev;
    if (half >= total) return;
    int v = half / (2 * Eev);
    int r = half - v * (2 * Eev);
    const int* ep;
    if (r < Eev)
        ep = edges + ((size_t)v * Eev + r) * 2;
    else
        ep = edges_neg + ((size_t)v * Eev + (r - Eev)) * 2;
    int a = ep[0], b = ep[1];
    const float4* pa = (const float4*)(xr2 + (((size_t)v * N + a)) * 128);
    const float4* pb = (const float4*)(xr2 + (((size_t)v * N + b)) * 128);
    float4 ua = pa[l32], ub = pb[l32];
    float s = ua.x * ub.x + ua.y * ub.y + ua.z * ub.z + ua.w * ub.w;
#pragma unroll
    for (int off = 16; off; off >>= 1) s += __shfl_xor(s, off, 32);
    if (l32 == 0) out[half] = s;
}

// ---------------------------------------------------------------------------
extern "C" void kernel_launch(void* const* d_in, const int* in_sizes, int n_in,
                              void* d_out, int out_size, void* d_ws, size_t ws_size,
                              hipStream_t stream) {
    const float* x   = (const float*)d_in[0];
    const float* W1  = (const float*)d_in[1];
    const float* b1  = (const float*)d_in[2];
    const float* W2  = (const float*)d_in[3];
    const float* b2  = (const float*)d_in[4];
    const float* A1  = (const float*)d_in[5];
    const float* bA1 = (const float*)d_in[6];
    const float* A2  = (const float*)d_in[7];
    const float* bA2 = (const float*)d_in[8];
    const float* Wc1 = (const float*)d_in[9];
    const float* bc1 = (const float*)d_in[10];
    const int* ei        = (const int*)d_in[13];
    const int* edges     = (const int*)d_in[14];
    const int* edges_neg = (const int*)d_in[15];
    float* out = (float*)d_out;

    const int H = 128, V = 3;
    const int N = in_sizes[0] / H;          // 50000
    const int E = in_sizes[13] / (V * 2);   // 800000
    const int Eev = in_sizes[14] / (V * 2); // 100000
    const int VNH = V * N * H;
    const int VN = V * N;
    const int VE = V * E;
    const int NB = (VN + 1023) >> 10;       // 147 buckets

    // workspace partition
    float* ws   = (float*)d_ws;
    float* agg  = ws;                  // VNH (xr1 then xr2)
    float* xc   = agg + VNH;           // N*H
    float* dinv = xc + (size_t)N * H;  // VN
    float* T    = dinv + VN;           // 3*128*128
    float* Mraw = T + 3 * 128 * 128;   // 16
    float* att  = Mraw + 16;           // 16
    int* cnt    = (int*)(att + 16);    // VN
    int* ptr    = cnt + VN;            // VN
    int* bsum   = ptr + VN;            // 256 (node-scan partials)
    int* bcnt   = bsum + 256;          // 256
    int* bstart = bcnt + 256;          // 256 (NB+1 used)
    int* bofs   = bstart + 256;        // 256
    int* idx    = bofs + 256;          // VE
    int* coo_g  = idx + VE;            // VE
    int* coo_r  = coo_g + VE;          // VE
    unsigned short* xs = (unsigned short*)(coo_r + VE);  // VNH bf16 (prescaled)
    (void)ws_size; (void)n_in; (void)out_size;

    dim3 blk(THREADS);
    int gVN = (VN + THREADS - 1) / THREADS;
    int gBC = (VE + BCH - 1) / BCH;
    int gGather = (int)(((size_t)VN * 64 + THREADS - 1) / THREADS);
    int nScanB = (VN + SC_CHUNK - 1) / SC_CHUNK;  // 147 <= 256
    dim3 gemmGrid((N + 127) / 128, 1, V);
    dim3 gemmGrid1((N + 127) / 128, 1, 1);
    int gScore = (int)(((size_t)V * 2 * Eev * 32 + THREADS - 1) / THREADS);

    // --- bucketed CSR build (shared by both layers) ---
    init_int_kernel<<<1, blk, 0, stream>>>(bcnt, 256);
    bucket_count_kernel<<<gBC, blk, 0, stream>>>(ei, bcnt, N, E, VE);
    bucket_scan_kernel<<<1, blk, 0, stream>>>(bcnt, bstart, bofs, NB);
    bucket_scatter_kernel<<<gBC, blk, 0, stream>>>(ei, bofs, coo_g, coo_r, N, E, VE);
    bucket_hist_kernel<<<NB, blk, 0, stream>>>(coo_g, bstart, cnt, VN);
    dinv_kernel<<<gVN, blk, 0, stream>>>(cnt, dinv, VN);
    scan_sum_kernel<<<nScanB, SC_T, 0, stream>>>(cnt, bsum, VN);
    scan_top_kernel<<<1, SC_T, 0, stream>>>(bsum, nScanB);
    scan_apply_kernel<<<nScanB, SC_T, 0, stream>>>(cnt, bsum, ptr, VN);
    bucket_fill_kernel<<<NB, blk, 0, stream>>>(coo_g, coo_r, bstart, ptr, idx, VN);

    // --- layer 1: xs = bf16(dinv * (x @ W1^T)) ---
    gemm_mfma_kernel<0><<<gemmGrid, blk, 32768, stream>>>(
        x, W1, nullptr, nullptr, xs, dinv, N, 128, (size_t)0, (size_t)128 * 128, (size_t)N * 128);
    small_mm_nn_kernel<<<(3 * 128 * 128 + THREADS - 1) / THREADS, blk, 0, stream>>>(W1, A1, T);
    att_reduce_kernel<<<9, blk, 0, stream>>>(T, W1, bA1, Mraw);
    att_softmax_kernel<<<1, 64, 0, stream>>>(Mraw, att);
    gather_cross_kernel<<<gGather, blk, 0, stream>>>(xs, dinv, ptr, idx, att, b1, agg, N, 1);

    // --- combine: xc = elu(emb @ Wc1^T + bc1), emb gathered from agg (fp32, bfx3) ---
    gemm_mfma_kernel<1><<<gemmGrid1, blk, 65536, stream>>>(
        agg, Wc1, bc1, xc, nullptr, nullptr, N, 384, (size_t)N * 128, (size_t)0, (size_t)0);

    // --- layer 2 ---
    gemm_mfma_kernel<0><<<gemmGrid, blk, 32768, stream>>>(
        xc, W2, nullptr, nullptr, xs, dinv, N, 128, (size_t)0, (size_t)128 * 128, (size_t)N * 128);
    small_mm_nn_kernel<<<(3 * 128 * 128 + THREADS - 1) / THREADS, blk, 0, stream>>>(W2, A2, T);
    att_reduce_kernel<<<9, blk, 0, stream>>>(T, W2, bA2, Mraw);
    att_softmax_kernel<<<1, 64, 0, stream>>>(Mraw, att);
    gather_cross_kernel<<<gGather, blk, 0, stream>>>(xs, dinv, ptr, idx, att, b2, agg, N, 0);

    // --- scoring ---
    edge_score_kernel<<<gScore, blk, 0, stream>>>(agg, edges, edges_neg, out, N, Eev, V);
}

// Round 7
// 627.186 us; speedup vs baseline: 4.4939x; 1.3692x over previous
//
#include <hip/hip_runtime.h>
#include <hip/hip_bf16.h>

// ---------------------------------------------------------------------------
// mGCN: 3-view GCN + cross-view attention, 2 layers, edge scoring.
// R7: revert gather to 4x16 groups + 2x unroll (8 rows in flight, low VGPR);
//     bf16 xr2 + bf16 edge scoring; bucketed CSR; bf16/bfx3 MFMA GEMMs.
// Dims: N=50000, D=H=128, V=3, E=800000/view, Eev=100000.
// ---------------------------------------------------------------------------

#define THREADS 256
#define BCH 8192   // edges per bucket-chunk block

typedef __bf16 bf16x8 __attribute__((ext_vector_type(8)));
typedef float f32x4 __attribute__((ext_vector_type(4)));
typedef unsigned short us8 __attribute__((ext_vector_type(8)));
typedef unsigned short us4 __attribute__((ext_vector_type(4)));

__device__ __forceinline__ float eluf(float x) {
    return x > 0.f ? x : expm1f(x);
}

__device__ __forceinline__ unsigned short f2bf(float f) {
    unsigned u = __builtin_bit_cast(unsigned, f);
    u += 0x7FFF + ((u >> 16) & 1);
    return (unsigned short)(u >> 16);
}
__device__ __forceinline__ float bf2f(unsigned short s) {
    unsigned u = ((unsigned)s) << 16;
    return __builtin_bit_cast(float, u);
}

// ---------------------- misc ----------------------
__global__ __launch_bounds__(THREADS) void init_int_kernel(int* p, int n) {
    int i = blockIdx.x * THREADS + threadIdx.x;
    if (i < n) p[i] = 0;
}

__global__ __launch_bounds__(THREADS) void dinv_kernel(
    const int* __restrict__ cnt, float* __restrict__ dinv, int VN) {
    int i = blockIdx.x * THREADS + threadIdx.x;
    if (i < VN) dinv[i] = rsqrtf((float)(cnt[i] + 1));  // +1 self loop
}

// ---------------------- bucketed CSR build ----------------------
// bucket(g) = g >> 10, g = v*N+col in [0, VN), NB = ceil(VN/1024) <= 160.

__global__ __launch_bounds__(THREADS) void bucket_count_kernel(
    const int* __restrict__ ei, int* __restrict__ bcnt, int N, int E, int VE) {
    __shared__ int h[160];
    for (int i = threadIdx.x; i < 160; i += THREADS) h[i] = 0;
    __syncthreads();
    int base = blockIdx.x * BCH;
    for (int k = 0; k < BCH; k += THREADS) {
        int t = base + k + threadIdx.x;
        if (t < VE) {
            int v = (t >= E) + (t >= 2 * E);
            int e = t - v * E;
            int col = ei[(size_t)v * 2 * E + E + e];
            atomicAdd(&h[(v * N + col) >> 10], 1);
        }
    }
    __syncthreads();
    for (int i = threadIdx.x; i < 160; i += THREADS)
        if (h[i]) atomicAdd(&bcnt[i], h[i]);
}

__global__ __launch_bounds__(THREADS) void bucket_scan_kernel(
    const int* __restrict__ bcnt, int* __restrict__ bstart, int* __restrict__ bofs, int nb) {
    __shared__ int sh[THREADS];
    int t = threadIdx.x;
    int v = (t < nb) ? bcnt[t] : 0;
    sh[t] = v;
    __syncthreads();
    for (int off = 1; off < THREADS; off <<= 1) {
        int u = (t >= off) ? sh[t - off] : 0;
        __syncthreads();
        sh[t] += u;
        __syncthreads();
    }
    int excl = sh[t] - v;
    if (t < nb) { bstart[t] = excl; bofs[t] = excl; }
    if (t == nb - 1) bstart[nb] = sh[t];
}

__global__ __launch_bounds__(THREADS) void bucket_scatter_kernel(
    const int* __restrict__ ei, int* __restrict__ bofs,
    int* __restrict__ coo_g, int* __restrict__ coo_r, int N, int E, int VE) {
    __shared__ int h[160];
    __shared__ int cur[160];
    for (int i = threadIdx.x; i < 160; i += THREADS) h[i] = 0;
    __syncthreads();
    int base = blockIdx.x * BCH;
    for (int k = 0; k < BCH; k += THREADS) {
        int t = base + k + threadIdx.x;
        if (t < VE) {
            int v = (t >= E) + (t >= 2 * E);
            int e = t - v * E;
            int col = ei[(size_t)v * 2 * E + E + e];
            atomicAdd(&h[(v * N + col) >> 10], 1);
        }
    }
    __syncthreads();
    if (threadIdx.x < 160 && h[threadIdx.x])
        cur[threadIdx.x] = atomicAdd(&bofs[threadIdx.x], h[threadIdx.x]);
    __syncthreads();
    for (int k = 0; k < BCH; k += THREADS) {
        int t = base + k + threadIdx.x;
        if (t < VE) {
            int v = (t >= E) + (t >= 2 * E);
            int e = t - v * E;
            const int* eiv = ei + (size_t)v * 2 * E;
            int row = eiv[e], col = eiv[E + e];
            int g = v * N + col;
            int pos = atomicAdd(&cur[g >> 10], 1);
            coo_g[pos] = g;
            coo_r[pos] = row;
        }
    }
}

__global__ __launch_bounds__(THREADS) void bucket_hist_kernel(
    const int* __restrict__ coo_g, const int* __restrict__ bstart,
    int* __restrict__ cnt, int VN) {
    __shared__ int h[1024];
    for (int i = threadIdx.x; i < 1024; i += THREADS) h[i] = 0;
    __syncthreads();
    int b = blockIdx.x;
    int s = bstart[b], e = bstart[b + 1];
    for (int i = s + threadIdx.x; i < e; i += THREADS)
        atomicAdd(&h[coo_g[i] & 1023], 1);
    __syncthreads();
    int g0 = b << 10;
    for (int i = threadIdx.x; i < 1024; i += THREADS)
        if (g0 + i < VN) cnt[g0 + i] = h[i];
}

__global__ __launch_bounds__(THREADS) void bucket_fill_kernel(
    const int* __restrict__ coo_g, const int* __restrict__ coo_r,
    const int* __restrict__ bstart, int* __restrict__ ptr,
    int* __restrict__ idx, int VN) {
    __shared__ int p[1024];
    int b = blockIdx.x, g0 = b << 10;
    for (int i = threadIdx.x; i < 1024; i += THREADS)
        p[i] = (g0 + i < VN) ? ptr[g0 + i] : 0;
    __syncthreads();
    int s = bstart[b], e = bstart[b + 1];
    for (int i = s + threadIdx.x; i < e; i += THREADS) {
        int pos = atomicAdd(&p[coo_g[i] & 1023], 1);
        idx[pos] = coo_r[i];
    }
    __syncthreads();
    for (int i = threadIdx.x; i < 1024; i += THREADS)
        if (g0 + i < VN) ptr[g0 + i] = p[i];
}

// ---- hierarchical exclusive scan over node counts ----
#define SC_T 256
#define SC_CHUNK 1024

__global__ __launch_bounds__(SC_T) void scan_sum_kernel(
    const int* __restrict__ cnt, int* __restrict__ bsum, int n) {
    __shared__ int red[SC_T];
    int base = blockIdx.x * SC_CHUNK + threadIdx.x * 4;
    int s = 0;
#pragma unroll
    for (int k = 0; k < 4; k++) {
        int i = base + k;
        if (i < n) s += cnt[i];
    }
    red[threadIdx.x] = s;
    __syncthreads();
    for (int st = SC_T / 2; st; st >>= 1) {
        if (threadIdx.x < st) red[threadIdx.x] += red[threadIdx.x + st];
        __syncthreads();
    }
    if (threadIdx.x == 0) bsum[blockIdx.x] = red[0];
}

__global__ __launch_bounds__(SC_T) void scan_top_kernel(int* bsum, int nb) {
    __shared__ int sh[SC_T];
    int t = threadIdx.x;
    int v = (t < nb) ? bsum[t] : 0;
    sh[t] = v;
    __syncthreads();
    for (int off = 1; off < SC_T; off <<= 1) {
        int u = (t >= off) ? sh[t - off] : 0;
        __syncthreads();
        sh[t] += u;
        __syncthreads();
    }
    if (t < nb) bsum[t] = sh[t] - v;  // exclusive
}

__global__ __launch_bounds__(SC_T) void scan_apply_kernel(
    const int* __restrict__ cnt, const int* __restrict__ bsum,
    int* __restrict__ ptr, int n) {
    __shared__ int sh[SC_T];
    int base = blockIdx.x * SC_CHUNK + threadIdx.x * 4;
    int v[4];
    int s = 0;
#pragma unroll
    for (int k = 0; k < 4; k++) {
        int i = base + k;
        v[k] = (i < n) ? cnt[i] : 0;
        s += v[k];
    }
    int tin = s;
    sh[threadIdx.x] = s;
    __syncthreads();
    for (int off = 1; off < SC_T; off <<= 1) {
        int u = (threadIdx.x >= off) ? sh[threadIdx.x - off] : 0;
        __syncthreads();
        sh[threadIdx.x] += u;
        __syncthreads();
    }
    int run = bsum[blockIdx.x] + sh[threadIdx.x] - tin;
#pragma unroll
    for (int k = 0; k < 4; k++) {
        int i = base + k;
        if (i < n) {
            ptr[i] = run;
            run += v[k];
        }
    }
}

// ---------------------- MFMA GEMM (template: split-bf16 or plain bf16) ----------------------
template <int SPLIT3>
__global__ __launch_bounds__(256) void gemm_mfma_kernel(
    const float* __restrict__ A, const float* __restrict__ B,
    const float* __restrict__ bias, float* __restrict__ Cf,
    unsigned short* __restrict__ Cbf, const float* __restrict__ dscale,
    int M, int Kb, size_t AV, size_t Bz, size_t Cz) {
    extern __shared__ unsigned short sm[];
    unsigned short* Ahi = sm;            // 128*64
    unsigned short* Bhi = sm + 8192;
    unsigned short* Alo = SPLIT3 ? sm + 16384 : nullptr;
    unsigned short* Blo = SPLIT3 ? sm + 24576 : nullptr;
    int tid = threadIdx.x;
    int z = blockIdx.z;
    int m0 = blockIdx.x * 128;
    const float* Bp = B + (size_t)z * Bz;
    int lane = tid & 63, wid = tid >> 6;
    int wr = wid >> 1, wc = wid & 1;
    int lr = lane & 15, lg = lane >> 4;
    f32x4 acc[4][4] = {};

    for (int k0 = 0; k0 < Kb; k0 += 64) {
        size_t Abase = (size_t)(k0 >> 7) * AV + (k0 & 127);
        for (int i = 0; i < 4; ++i) {
            int ch = tid + i * 256;  // 0..1023
            int row = ch >> 3, c8 = (ch & 7) << 3;
            int e = (row * 64 + c8) ^ ((row & 7) << 3);
            float va[8];
            int gm = m0 + row;
            if (gm < M) {
                const float* p = A + Abase + (size_t)gm * 128 + c8;
                *(float4*)(va)     = *(const float4*)(p);
                *(float4*)(va + 4) = *(const float4*)(p + 4);
            } else {
#pragma unroll
                for (int j = 0; j < 8; j++) va[j] = 0.f;
            }
            us8 h8, l8;
#pragma unroll
            for (int j = 0; j < 8; j++) {
                unsigned short h = f2bf(va[j]);
                h8[j] = h;
                if (SPLIT3) l8[j] = f2bf(va[j] - bf2f(h));
            }
            *(us8*)&Ahi[e] = h8;
            if (SPLIT3) *(us8*)&Alo[e] = l8;
            float vb[8];
            const float* q = Bp + (size_t)row * Kb + k0 + c8;
            *(float4*)(vb)     = *(const float4*)(q);
            *(float4*)(vb + 4) = *(const float4*)(q + 4);
#pragma unroll
            for (int j = 0; j < 8; j++) {
                unsigned short h = f2bf(vb[j]);
                h8[j] = h;
                if (SPLIT3) l8[j] = f2bf(vb[j] - bf2f(h));
            }
            *(us8*)&Bhi[e] = h8;
            if (SPLIT3) *(us8*)&Blo[e] = l8;
        }
        __syncthreads();
#pragma unroll
        for (int ks = 0; ks < 2; ++ks) {
            bf16x8 ah[4], al[4], bh[4], bl[4];
#pragma unroll
            for (int m = 0; m < 4; m++) {
                int row = wr * 64 + m * 16 + lr;
                int e = (row * 64 + ks * 32 + lg * 8) ^ ((row & 7) << 3);
                ah[m] = *(const bf16x8*)&Ahi[e];
                if (SPLIT3) al[m] = *(const bf16x8*)&Alo[e];
            }
#pragma unroll
            for (int n = 0; n < 4; n++) {
                int col = wc * 64 + n * 16 + lr;
                int e = (col * 64 + ks * 32 + lg * 8) ^ ((col & 7) << 3);
                bh[n] = *(const bf16x8*)&Bhi[e];
                if (SPLIT3) bl[n] = *(const bf16x8*)&Blo[e];
            }
#pragma unroll
            for (int m = 0; m < 4; m++)
#pragma unroll
                for (int n = 0; n < 4; n++) {
                    acc[m][n] = __builtin_amdgcn_mfma_f32_16x16x32_bf16(ah[m], bh[n], acc[m][n], 0, 0, 0);
                    if (SPLIT3) {
                        acc[m][n] = __builtin_amdgcn_mfma_f32_16x16x32_bf16(ah[m], bl[n], acc[m][n], 0, 0, 0);
                        acc[m][n] = __builtin_amdgcn_mfma_f32_16x16x32_bf16(al[m], bh[n], acc[m][n], 0, 0, 0);
                    }
                }
        }
        __syncthreads();
    }

#pragma unroll
    for (int m = 0; m < 4; m++) {
        int rbase = m0 + wr * 64 + m * 16 + lg * 4;
#pragma unroll
        for (int n = 0; n < 4; n++) {
            int col = wc * 64 + n * 16 + lr;
#pragma unroll
            for (int j = 0; j < 4; j++) {
                int row = rbase + j;
                if (row < M) {
                    float vv = acc[m][n][j];
                    if (Cbf) {
                        float sc = dscale[(size_t)z * M + row];
                        Cbf[(size_t)z * Cz + (size_t)row * 128 + col] = f2bf(vv * sc);
                    } else {
                        Cf[(size_t)z * Cz + (size_t)row * 128 + col] = eluf(vv + bias[col]);
                    }
                }
            }
        }
    }
}

// ---------------------- attention ----------------------
__global__ __launch_bounds__(THREADS) void small_mm_nn_kernel(
    const float* __restrict__ W, const float* __restrict__ A, float* __restrict__ T) {
    int idx = blockIdx.x * THREADS + threadIdx.x;
    if (idx >= 3 * 128 * 128) return;
    int b = idx & 127;
    int vk = idx >> 7;
    const float* w = W + (size_t)vk * 128;
    float s = 0.f;
#pragma unroll 8
    for (int a = 0; a < 128; a++) s += w[a] * A[a * 128 + b];
    T[idx] = s;
}

__global__ __launch_bounds__(THREADS) void att_reduce_kernel(
    const float* __restrict__ T, const float* __restrict__ W,
    const float* __restrict__ bA, float* __restrict__ Mraw) {
    int v = blockIdx.x / 3, w = blockIdx.x % 3;
    const float* tp = T + (size_t)v * 16384;
    const float* wp = W + (size_t)w * 16384;
    float s = 0.f;
    for (int i = threadIdx.x; i < 16384; i += THREADS) s += tp[i] * wp[i];
    __shared__ float red[THREADS];
    red[threadIdx.x] = s;
    __syncthreads();
    for (int st = THREADS / 2; st; st >>= 1) {
        if (threadIdx.x < st) red[threadIdx.x] += red[threadIdx.x + st];
        __syncthreads();
    }
    if (threadIdx.x == 0) Mraw[blockIdx.x] = red[0] + 128.f * bA[0];
}

__global__ void att_softmax_kernel(const float* __restrict__ Mraw, float* __restrict__ att) {
    int v = threadIdx.x;
    if (v >= 3) return;
    float m0 = Mraw[v * 3 + 0], m1 = Mraw[v * 3 + 1], m2 = Mraw[v * 3 + 2];
    float mx = fmaxf(m0, fmaxf(m1, m2));
    float e0 = expf(m0 - mx), e1 = expf(m1 - mx), e2 = expf(m2 - mx);
    float s = e0 + e1 + e2;
    att[v * 3 + 0] = e0 / s;
    att[v * 3 + 1] = e1 / s;
    att[v * 3 + 2] = e2 / s;
}

// ---------------------- fused GCN gather + cross_rep ----------------------
// xs = bf16(dinv[row]*h[row]). One wave per (v,n); 4 groups of 16 lanes each
// own edges stride-4, unrolled x2 (8 rows in flight/wave); lane owns 8 feats.
// OUTBF=0: fp32 out (xrf); OUTBF=1: bf16 out (xrb).
template <int OUTBF>
__global__ __launch_bounds__(THREADS) void gather_cross_kernel(
    const unsigned short* __restrict__ xs, const float* __restrict__ dinv,
    const int* __restrict__ ptr, const int* __restrict__ idx,
    const float* __restrict__ att, const float* __restrict__ bias,
    float* __restrict__ xrf, unsigned short* __restrict__ xrb,
    int N, int elu_inner) {
    int wv = (blockIdx.x * THREADS + threadIdx.x) >> 6;
    int lane = threadIdx.x & 63;
    int VN = 3 * N;
    if (wv >= VN) return;
    int v = wv / N;
    int n = wv - v * N;
    int vN = v * N;
    int g = lane >> 4, f0 = (lane & 15) * 8;

    float acc[8] = {};
    int s = (wv == 0) ? 0 : ptr[wv - 1];
    int e = ptr[wv];
    int j = s + g;
    for (; j + 4 < e; j += 8) {
        int r0 = idx[j], r1 = idx[j + 4];
        us8 u0 = *(const us8*)(xs + (((size_t)(vN + r0)) << 7) + f0);
        us8 u1 = *(const us8*)(xs + (((size_t)(vN + r1)) << 7) + f0);
#pragma unroll
        for (int i = 0; i < 8; i++) acc[i] += bf2f(u0[i]) + bf2f(u1[i]);
    }
    if (j < e) {
        int r0 = idx[j];
        us8 u0 = *(const us8*)(xs + (((size_t)(vN + r0)) << 7) + f0);
#pragma unroll
        for (int i = 0; i < 8; i++) acc[i] += bf2f(u0[i]);
    }
#pragma unroll
    for (int i = 0; i < 8; i++) {
        acc[i] += __shfl_xor(acc[i], 16);
        acc[i] += __shfl_xor(acc[i], 32);
    }

    if (g == 0) {  // 16 lanes cover all 128 features
        us8 su = *(const us8*)(xs + (((size_t)wv) << 7) + f0);
        float dc = dinv[wv];
        size_t nb = (((size_t)n) << 7) + f0;
        size_t NH = ((size_t)N) << 7;
        us8 c0 = *(const us8*)(xs + nb);
        us8 c1 = *(const us8*)(xs + NH + nb);
        us8 c2 = *(const us8*)(xs + 2 * NH + nb);
        float wa = att[v * 3 + 0] / dinv[n];
        float wb = att[v * 3 + 1] / dinv[N + n];
        float wc = att[v * 3 + 2] / dinv[2 * N + n];
        float4 bb0 = *(const float4*)(bias + v * 128 + f0);
        float4 bb1 = *(const float4*)(bias + v * 128 + f0 + 4);
        float bv[8] = {bb0.x, bb0.y, bb0.z, bb0.w, bb1.x, bb1.y, bb1.z, bb1.w};
        float ov[8];
#pragma unroll
        for (int i = 0; i < 8; i++) {
            float a = dc * (acc[i] + bf2f(su[i])) + bv[i];
            if (elu_inner) a = eluf(a);
            float cr = wa * bf2f(c0[i]) + wb * bf2f(c1[i]) + wc * bf2f(c2[i]);
            ov[i] = 0.5f + a + eluf(0.5f * cr);
        }
        if (OUTBF) {
            us8 o;
#pragma unroll
            for (int i = 0; i < 8; i++) o[i] = f2bf(ov[i]);
            *(us8*)(xrb + (((size_t)wv) << 7) + f0) = o;
        } else {
            float4 o0 = {ov[0], ov[1], ov[2], ov[3]};
            float4 o1 = {ov[4], ov[5], ov[6], ov[7]};
            *(float4*)(xrf + (((size_t)wv) << 7) + f0)     = o0;
            *(float4*)(xrf + (((size_t)wv) << 7) + f0 + 4) = o1;
        }
    }
}

// ---------------------- edge scoring: bf16 xr2, 2 edges per wave ----------------------
__global__ __launch_bounds__(THREADS) void edge_score_kernel(
    const unsigned short* __restrict__ xr2, const int* __restrict__ edges,
    const int* __restrict__ edges_neg, float* __restrict__ out, int N, int Eev, int V) {
    int half = (blockIdx.x * THREADS + threadIdx.x) >> 5;
    int l32 = threadIdx.x & 31;
    int total = V * 2 * Eev;
    if (half >= total) return;
    int v = half / (2 * Eev);
    int r = half - v * (2 * Eev);
    const int* ep = (r < Eev) ? edges + ((size_t)v * Eev + r) * 2
                              : edges_neg + ((size_t)v * Eev + (r - Eev)) * 2;
    int a = ep[0], b = ep[1];
    const unsigned short* pa = xr2 + (((size_t)v * N + a) << 7) + l32 * 4;
    const unsigned short* pb = xr2 + (((size_t)v * N + b) << 7) + l32 * 4;
    us4 ua = *(const us4*)pa, ub = *(const us4*)pb;
    float s = bf2f(ua[0]) * bf2f(ub[0]) + bf2f(ua[1]) * bf2f(ub[1]) +
              bf2f(ua[2]) * bf2f(ub[2]) + bf2f(ua[3]) * bf2f(ub[3]);
#pragma unroll
    for (int off = 16; off; off >>= 1) s += __shfl_xor(s, off, 32);
    if (l32 == 0) out[half] = s;
}

// ---------------------------------------------------------------------------
extern "C" void kernel_launch(void* const* d_in, const int* in_sizes, int n_in,
                              void* d_out, int out_size, void* d_ws, size_t ws_size,
                              hipStream_t stream) {
    const float* x   = (const float*)d_in[0];
    const float* W1  = (const float*)d_in[1];
    const float* b1  = (const float*)d_in[2];
    const float* W2  = (const float*)d_in[3];
    const float* b2  = (const float*)d_in[4];
    const float* A1  = (const float*)d_in[5];
    const float* bA1 = (const float*)d_in[6];
    const float* A2  = (const float*)d_in[7];
    const float* bA2 = (const float*)d_in[8];
    const float* Wc1 = (const float*)d_in[9];
    const float* bc1 = (const float*)d_in[10];
    const int* ei        = (const int*)d_in[13];
    const int* edges     = (const int*)d_in[14];
    const int* edges_neg = (const int*)d_in[15];
    float* out = (float*)d_out;

    const int H = 128, V = 3;
    const int N = in_sizes[0] / H;          // 50000
    const int E = in_sizes[13] / (V * 2);   // 800000
    const int Eev = in_sizes[14] / (V * 2); // 100000
    const int VNH = V * N * H;
    const int VN = V * N;
    const int VE = V * E;
    const int NB = (VN + 1023) >> 10;       // 147 buckets

    // workspace partition
    float* ws   = (float*)d_ws;
    float* agg  = ws;                  // VNH (xr1 fp32; later xr2 bf16 alias)
    float* xc   = agg + VNH;           // N*H
    float* dinv = xc + (size_t)N * H;  // VN
    float* T    = dinv + VN;           // 3*128*128
    float* Mraw = T + 3 * 128 * 128;   // 16
    float* att  = Mraw + 16;           // 16
    int* cnt    = (int*)(att + 16);    // VN
    int* ptr    = cnt + VN;            // VN
    int* bsum   = ptr + VN;            // 256
    int* bcnt   = bsum + 256;          // 256
    int* bstart = bcnt + 256;          // 256 (NB+1 used)
    int* bofs   = bstart + 256;        // 256
    int* idx    = bofs + 256;          // VE
    int* coo_g  = idx + VE;            // VE
    int* coo_r  = coo_g + VE;          // VE
    unsigned short* xs = (unsigned short*)(coo_r + VE);  // VNH bf16 (prescaled)
    unsigned short* xr2b = (unsigned short*)agg;         // VNH bf16 (layer-2 out)
    (void)ws_size; (void)n_in; (void)out_size;

    dim3 blk(THREADS);
    int gVN = (VN + THREADS - 1) / THREADS;
    int gBC = (VE + BCH - 1) / BCH;
    int gGather = (int)(((size_t)VN * 64 + THREADS - 1) / THREADS);
    int nScanB = (VN + SC_CHUNK - 1) / SC_CHUNK;  // 147 <= 256
    dim3 gemmGrid((N + 127) / 128, 1, V);
    dim3 gemmGrid1((N + 127) / 128, 1, 1);
    int gScore = (int)(((size_t)V * 2 * Eev * 32 + THREADS - 1) / THREADS);

    // --- bucketed CSR build (shared by both layers) ---
    init_int_kernel<<<1, blk, 0, stream>>>(bcnt, 256);
    bucket_count_kernel<<<gBC, blk, 0, stream>>>(ei, bcnt, N, E, VE);
    bucket_scan_kernel<<<1, blk, 0, stream>>>(bcnt, bstart, bofs, NB);
    bucket_scatter_kernel<<<gBC, blk, 0, stream>>>(ei, bofs, coo_g, coo_r, N, E, VE);
    bucket_hist_kernel<<<NB, blk, 0, stream>>>(coo_g, bstart, cnt, VN);
    dinv_kernel<<<gVN, blk, 0, stream>>>(cnt, dinv, VN);
    scan_sum_kernel<<<nScanB, SC_T, 0, stream>>>(cnt, bsum, VN);
    scan_top_kernel<<<1, SC_T, 0, stream>>>(bsum, nScanB);
    scan_apply_kernel<<<nScanB, SC_T, 0, stream>>>(cnt, bsum, ptr, VN);
    bucket_fill_kernel<<<NB, blk, 0, stream>>>(coo_g, coo_r, bstart, ptr, idx, VN);

    // --- layer 1: xs = bf16(dinv * (x @ W1^T)) ---
    gemm_mfma_kernel<0><<<gemmGrid, blk, 32768, stream>>>(
        x, W1, nullptr, nullptr, xs, dinv, N, 128, (size_t)0, (size_t)128 * 128, (size_t)N * 128);
    small_mm_nn_kernel<<<(3 * 128 * 128 + THREADS - 1) / THREADS, blk, 0, stream>>>(W1, A1, T);
    att_reduce_kernel<<<9, blk, 0, stream>>>(T, W1, bA1, Mraw);
    att_softmax_kernel<<<1, 64, 0, stream>>>(Mraw, att);
    gather_cross_kernel<0><<<gGather, blk, 0, stream>>>(xs, dinv, ptr, idx, att, b1, agg, nullptr, N, 1);

    // --- combine: xc = elu(emb @ Wc1^T + bc1), emb gathered from agg (fp32, bfx3) ---
    gemm_mfma_kernel<1><<<gemmGrid1, blk, 65536, stream>>>(
        agg, Wc1, bc1, xc, nullptr, nullptr, N, 384, (size_t)N * 128, (size_t)0, (size_t)0);

    // --- layer 2 ---
    gemm_mfma_kernel<0><<<gemmGrid, blk, 32768, stream>>>(
        xc, W2, nullptr, nullptr, xs, dinv, N, 128, (size_t)0, (size_t)128 * 128, (size_t)N * 128);
    small_mm_nn_kernel<<<(3 * 128 * 128 + THREADS - 1) / THREADS, blk, 0, stream>>>(W2, A2, T);
    att_reduce_kernel<<<9, blk, 0, stream>>>(T, W2, bA2, Mraw);
    att_softmax_kernel<<<1, 64, 0, stream>>>(Mraw, att);
    gather_cross_kernel<1><<<gGather, blk, 0, stream>>>(xs, dinv, ptr, idx, att, b2, nullptr, xr2b, N, 0);

    // --- scoring (bf16 xr2) ---
    edge_score_kernel<<<gScore, blk, 0, stream>>>(xr2b, edges, edges_neg, out, N, Eev, V);
}

// Round 8
// 584.719 us; speedup vs baseline: 4.8203x; 1.0726x over previous
//
#include <hip/hip_runtime.h>
#include <hip/hip_bf16.h>

// ---------------------------------------------------------------------------
// mGCN: 3-view GCN + cross-view attention, 2 layers, edge scoring.
// R8: all-bf16 inter-kernel tensors (xr1/xc bf16, single-MFMA combine),
//     gather unroll x4 (16 rows in flight), batched attention (both layers
//     up front), 4-edge scoring, dinv folded into scan. absmax floor is the
//     comparator's bf16 ULP (0.5 since the all-fp32 R1), so bf16 is free.
// Dims: N=50000, D=H=128, V=3, E=800000/view, Eev=100000.
// ---------------------------------------------------------------------------

#define THREADS 256
#define BCH 8192   // edges per bucket-chunk block

typedef __bf16 bf16x8 __attribute__((ext_vector_type(8)));
typedef float f32x4 __attribute__((ext_vector_type(4)));
typedef unsigned short us8 __attribute__((ext_vector_type(8)));

__device__ __forceinline__ float eluf(float x) {
    return x > 0.f ? x : expm1f(x);
}

__device__ __forceinline__ unsigned short f2bf(float f) {
    unsigned u = __builtin_bit_cast(unsigned, f);
    u += 0x7FFF + ((u >> 16) & 1);
    return (unsigned short)(u >> 16);
}
__device__ __forceinline__ float bf2f(unsigned short s) {
    unsigned u = ((unsigned)s) << 16;
    return __builtin_bit_cast(float, u);
}

// ---------------------- misc ----------------------
__global__ __launch_bounds__(THREADS) void init_int_kernel(int* p, int n) {
    int i = blockIdx.x * THREADS + threadIdx.x;
    if (i < n) p[i] = 0;
}

// ---------------------- bucketed CSR build ----------------------
// bucket(g) = g >> 10, g = v*N+col in [0, VN), NB = ceil(VN/1024) <= 160.

__global__ __launch_bounds__(THREADS) void bucket_count_kernel(
    const int* __restrict__ ei, int* __restrict__ bcnt, int N, int E, int VE) {
    __shared__ int h[160];
    for (int i = threadIdx.x; i < 160; i += THREADS) h[i] = 0;
    __syncthreads();
    int base = blockIdx.x * BCH;
    for (int k = 0; k < BCH; k += THREADS) {
        int t = base + k + threadIdx.x;
        if (t < VE) {
            int v = (t >= E) + (t >= 2 * E);
            int e = t - v * E;
            int col = ei[(size_t)v * 2 * E + E + e];
            atomicAdd(&h[(v * N + col) >> 10], 1);
        }
    }
    __syncthreads();
    for (int i = threadIdx.x; i < 160; i += THREADS)
        if (h[i]) atomicAdd(&bcnt[i], h[i]);
}

__global__ __launch_bounds__(THREADS) void bucket_scan_kernel(
    const int* __restrict__ bcnt, int* __restrict__ bstart, int* __restrict__ bofs, int nb) {
    __shared__ int sh[THREADS];
    int t = threadIdx.x;
    int v = (t < nb) ? bcnt[t] : 0;
    sh[t] = v;
    __syncthreads();
    for (int off = 1; off < THREADS; off <<= 1) {
        int u = (t >= off) ? sh[t - off] : 0;
        __syncthreads();
        sh[t] += u;
        __syncthreads();
    }
    int excl = sh[t] - v;
    if (t < nb) { bstart[t] = excl; bofs[t] = excl; }
    if (t == nb - 1) bstart[nb] = sh[t];
}

__global__ __launch_bounds__(THREADS) void bucket_scatter_kernel(
    const int* __restrict__ ei, int* __restrict__ bofs,
    int* __restrict__ coo_g, int* __restrict__ coo_r, int N, int E, int VE) {
    __shared__ int h[160];
    __shared__ int cur[160];
    for (int i = threadIdx.x; i < 160; i += THREADS) h[i] = 0;
    __syncthreads();
    int base = blockIdx.x * BCH;
    for (int k = 0; k < BCH; k += THREADS) {
        int t = base + k + threadIdx.x;
        if (t < VE) {
            int v = (t >= E) + (t >= 2 * E);
            int e = t - v * E;
            int col = ei[(size_t)v * 2 * E + E + e];
            atomicAdd(&h[(v * N + col) >> 10], 1);
        }
    }
    __syncthreads();
    if (threadIdx.x < 160 && h[threadIdx.x])
        cur[threadIdx.x] = atomicAdd(&bofs[threadIdx.x], h[threadIdx.x]);
    __syncthreads();
    for (int k = 0; k < BCH; k += THREADS) {
        int t = base + k + threadIdx.x;
        if (t < VE) {
            int v = (t >= E) + (t >= 2 * E);
            int e = t - v * E;
            const int* eiv = ei + (size_t)v * 2 * E;
            int row = eiv[e], col = eiv[E + e];
            int g = v * N + col;
            int pos = atomicAdd(&cur[g >> 10], 1);
            coo_g[pos] = g;
            coo_r[pos] = row;
        }
    }
}

__global__ __launch_bounds__(THREADS) void bucket_hist_kernel(
    const int* __restrict__ coo_g, const int* __restrict__ bstart,
    int* __restrict__ cnt, int VN) {
    __shared__ int h[1024];
    for (int i = threadIdx.x; i < 1024; i += THREADS) h[i] = 0;
    __syncthreads();
    int b = blockIdx.x;
    int s = bstart[b], e = bstart[b + 1];
    for (int i = s + threadIdx.x; i < e; i += THREADS)
        atomicAdd(&h[coo_g[i] & 1023], 1);
    __syncthreads();
    int g0 = b << 10;
    for (int i = threadIdx.x; i < 1024; i += THREADS)
        if (g0 + i < VN) cnt[g0 + i] = h[i];
}

__global__ __launch_bounds__(THREADS) void bucket_fill_kernel(
    const int* __restrict__ coo_g, const int* __restrict__ coo_r,
    const int* __restrict__ bstart, int* __restrict__ ptr,
    int* __restrict__ idx, int VN) {
    __shared__ int p[1024];
    int b = blockIdx.x, g0 = b << 10;
    for (int i = threadIdx.x; i < 1024; i += THREADS)
        p[i] = (g0 + i < VN) ? ptr[g0 + i] : 0;
    __syncthreads();
    int s = bstart[b], e = bstart[b + 1];
    for (int i = s + threadIdx.x; i < e; i += THREADS) {
        int pos = atomicAdd(&p[coo_g[i] & 1023], 1);
        idx[pos] = coo_r[i];
    }
    __syncthreads();
    for (int i = threadIdx.x; i < 1024; i += THREADS)
        if (g0 + i < VN) ptr[g0 + i] = p[i];
}

// ---- hierarchical exclusive scan over node counts (+ dinv fused) ----
#define SC_T 256
#define SC_CHUNK 1024

__global__ __launch_bounds__(SC_T) void scan_sum_kernel(
    const int* __restrict__ cnt, int* __restrict__ bsum, int n) {
    __shared__ int red[SC_T];
    int base = blockIdx.x * SC_CHUNK + threadIdx.x * 4;
    int s = 0;
#pragma unroll
    for (int k = 0; k < 4; k++) {
        int i = base + k;
        if (i < n) s += cnt[i];
    }
    red[threadIdx.x] = s;
    __syncthreads();
    for (int st = SC_T / 2; st; st >>= 1) {
        if (threadIdx.x < st) red[threadIdx.x] += red[threadIdx.x + st];
        __syncthreads();
    }
    if (threadIdx.x == 0) bsum[blockIdx.x] = red[0];
}

__global__ __launch_bounds__(SC_T) void scan_top_kernel(int* bsum, int nb) {
    __shared__ int sh[SC_T];
    int t = threadIdx.x;
    int v = (t < nb) ? bsum[t] : 0;
    sh[t] = v;
    __syncthreads();
    for (int off = 1; off < SC_T; off <<= 1) {
        int u = (t >= off) ? sh[t - off] : 0;
        __syncthreads();
        sh[t] += u;
        __syncthreads();
    }
    if (t < nb) bsum[t] = sh[t] - v;  // exclusive
}

__global__ __launch_bounds__(SC_T) void scan_apply_kernel(
    const int* __restrict__ cnt, const int* __restrict__ bsum,
    int* __restrict__ ptr, float* __restrict__ dinv, int n) {
    __shared__ int sh[SC_T];
    int base = blockIdx.x * SC_CHUNK + threadIdx.x * 4;
    int v[4];
    int s = 0;
#pragma unroll
    for (int k = 0; k < 4; k++) {
        int i = base + k;
        v[k] = (i < n) ? cnt[i] : 0;
        s += v[k];
    }
    int tin = s;
    sh[threadIdx.x] = s;
    __syncthreads();
    for (int off = 1; off < SC_T; off <<= 1) {
        int u = (threadIdx.x >= off) ? sh[threadIdx.x - off] : 0;
        __syncthreads();
        sh[threadIdx.x] += u;
        __syncthreads();
    }
    int run = bsum[blockIdx.x] + sh[threadIdx.x] - tin;
#pragma unroll
    for (int k = 0; k < 4; k++) {
        int i = base + k;
        if (i < n) {
            ptr[i] = run;
            run += v[k];
            dinv[i] = rsqrtf((float)(v[k] + 1));  // +1 self loop
        }
    }
}

// ---------------------- bf16 MFMA GEMM ----------------------
// C[M,128] = A[M,K] @ B[128,K]^T, fp32 acc, bf16 output.
// ABF=0: A fp32; ABF=1: A bf16 plane (same element addressing).
// A elem (m, k0+c) at A[(k0>>7)*AV + (k0&127) + m*128 + c].
// Epilogue: if bias: vv=elu(vv+bias[col]); if dscale: vv*=dscale[z*M+row]; bf16.
template <int ABF>
__global__ __launch_bounds__(256) void gemm_bf16_kernel(
    const float* __restrict__ Af, const unsigned short* __restrict__ Ab,
    const float* __restrict__ B, const float* __restrict__ bias,
    unsigned short* __restrict__ C, const float* __restrict__ dscale,
    int M, int Kb, size_t AV, size_t Bz, size_t Cz) {
    __shared__ unsigned short Ah[128 * 64];
    __shared__ unsigned short Bh[128 * 64];
    int tid = threadIdx.x;
    int z = blockIdx.z;
    int m0 = blockIdx.x * 128;
    const float* Bp = B + (size_t)z * Bz;
    int lane = tid & 63, wid = tid >> 6;
    int wr = wid >> 1, wc = wid & 1;
    int lr = lane & 15, lg = lane >> 4;
    f32x4 acc[4][4] = {};

    for (int k0 = 0; k0 < Kb; k0 += 64) {
        size_t Abase = (size_t)(k0 >> 7) * AV + (k0 & 127);
        for (int i = 0; i < 4; ++i) {
            int ch = tid + i * 256;  // 0..1023
            int row = ch >> 3, c8 = (ch & 7) << 3;
            int e = (row * 64 + c8) ^ ((row & 7) << 3);
            int gm = m0 + row;
            us8 h8;
            if (ABF) {
                if (gm < M) {
                    h8 = *(const us8*)(Ab + Abase + (size_t)gm * 128 + c8);
                } else {
#pragma unroll
                    for (int j = 0; j < 8; j++) h8[j] = 0;
                }
            } else {
                float va[8];
                if (gm < M) {
                    const float* p = Af + Abase + (size_t)gm * 128 + c8;
                    *(float4*)(va)     = *(const float4*)(p);
                    *(float4*)(va + 4) = *(const float4*)(p + 4);
                } else {
#pragma unroll
                    for (int j = 0; j < 8; j++) va[j] = 0.f;
                }
#pragma unroll
                for (int j = 0; j < 8; j++) h8[j] = f2bf(va[j]);
            }
            *(us8*)&Ah[e] = h8;
            float vb[8];
            const float* q = Bp + (size_t)row * Kb + k0 + c8;
            *(float4*)(vb)     = *(const float4*)(q);
            *(float4*)(vb + 4) = *(const float4*)(q + 4);
            us8 b8;
#pragma unroll
            for (int j = 0; j < 8; j++) b8[j] = f2bf(vb[j]);
            *(us8*)&Bh[e] = b8;
        }
        __syncthreads();
#pragma unroll
        for (int ks = 0; ks < 2; ++ks) {
            bf16x8 ah[4], bh[4];
#pragma unroll
            for (int m = 0; m < 4; m++) {
                int row = wr * 64 + m * 16 + lr;
                int e = (row * 64 + ks * 32 + lg * 8) ^ ((row & 7) << 3);
                ah[m] = *(const bf16x8*)&Ah[e];
            }
#pragma unroll
            for (int n = 0; n < 4; n++) {
                int col = wc * 64 + n * 16 + lr;
                int e = (col * 64 + ks * 32 + lg * 8) ^ ((col & 7) << 3);
                bh[n] = *(const bf16x8*)&Bh[e];
            }
#pragma unroll
            for (int m = 0; m < 4; m++)
#pragma unroll
                for (int n = 0; n < 4; n++)
                    acc[m][n] = __builtin_amdgcn_mfma_f32_16x16x32_bf16(ah[m], bh[n], acc[m][n], 0, 0, 0);
        }
        __syncthreads();
    }

#pragma unroll
    for (int m = 0; m < 4; m++) {
        int rbase = m0 + wr * 64 + m * 16 + lg * 4;
#pragma unroll
        for (int n = 0; n < 4; n++) {
            int col = wc * 64 + n * 16 + lr;
#pragma unroll
            for (int j = 0; j < 4; j++) {
                int row = rbase + j;
                if (row < M) {
                    float vv = acc[m][n][j];
                    if (bias) vv = eluf(vv + bias[col]);
                    if (dscale) vv *= dscale[(size_t)z * M + row];
                    C[(size_t)z * Cz + (size_t)row * 128 + col] = f2bf(vv);
                }
            }
        }
    }
}

// ---------------------- attention (both layers batched, weights-only dep) ----------------------
// T[l,v,k,b] = sum_a W_l[v,k,a] * A_l[a,b]
__global__ __launch_bounds__(THREADS) void small_mm_nn_kernel(
    const float* __restrict__ W1, const float* __restrict__ W2,
    const float* __restrict__ A1, const float* __restrict__ A2,
    float* __restrict__ T) {
    int lin = blockIdx.x * THREADS + threadIdx.x;
    if (lin >= 2 * 3 * 128 * 128) return;
    int l = lin / 49152;
    int rem = lin - l * 49152;
    int b = rem & 127;
    int vk = rem >> 7;
    const float* w = (l ? W2 : W1) + (size_t)vk * 128;
    const float* A = l ? A2 : A1;
    float s = 0.f;
#pragma unroll 8
    for (int a = 0; a < 128; a++) s += w[a] * A[a * 128 + b];
    T[lin] = s;
}

// Mraw[l*9 + v*3+w] = sum_i T[l,v,i]*W_l[w,i] + 128*bA_l
__global__ __launch_bounds__(THREADS) void att_reduce_kernel(
    const float* __restrict__ T, const float* __restrict__ W1,
    const float* __restrict__ W2, const float* __restrict__ bA1,
    const float* __restrict__ bA2, float* __restrict__ Mraw) {
    int l = blockIdx.x / 9;
    int vw = blockIdx.x - l * 9;
    int v = vw / 3, w = vw - v * 3;
    const float* tp = T + (size_t)l * 49152 + (size_t)v * 16384;
    const float* wp = (l ? W2 : W1) + (size_t)w * 16384;
    float s = 0.f;
    for (int i = threadIdx.x; i < 16384; i += THREADS) s += tp[i] * wp[i];
    __shared__ float red[THREADS];
    red[threadIdx.x] = s;
    __syncthreads();
    for (int st = THREADS / 2; st; st >>= 1) {
        if (threadIdx.x < st) red[threadIdx.x] += red[threadIdx.x + st];
        __syncthreads();
    }
    if (threadIdx.x == 0) Mraw[blockIdx.x] = red[0] + 128.f * (l ? bA2[0] : bA1[0]);
}

__global__ void att_softmax_kernel(const float* __restrict__ Mraw, float* __restrict__ att) {
    int v = threadIdx.x;
    if (v >= 6) return;
    float m0 = Mraw[v * 3 + 0], m1 = Mraw[v * 3 + 1], m2 = Mraw[v * 3 + 2];
    float mx = fmaxf(m0, fmaxf(m1, m2));
    float e0 = expf(m0 - mx), e1 = expf(m1 - mx), e2 = expf(m2 - mx);
    float s = e0 + e1 + e2;
    att[v * 3 + 0] = e0 / s;
    att[v * 3 + 1] = e1 / s;
    att[v * 3 + 2] = e2 / s;
}

// ---------------------- fused GCN gather + cross_rep (bf16 out) ----------------------
// xs = bf16(dinv[row]*h[row]). One wave per (v,n); 4 groups of 16 lanes each
// own edges stride-4, unrolled x4 (16 rows in flight/wave); lane owns 8 feats.
__global__ __launch_bounds__(THREADS) void gather_cross_kernel(
    const unsigned short* __restrict__ xs, const float* __restrict__ dinv,
    const int* __restrict__ ptr, const int* __restrict__ idx,
    const float* __restrict__ att, const float* __restrict__ bias,
    unsigned short* __restrict__ xr, int N, int elu_inner) {
    int wv = (blockIdx.x * THREADS + threadIdx.x) >> 6;
    int lane = threadIdx.x & 63;
    int VN = 3 * N;
    if (wv >= VN) return;
    int v = wv / N;
    int n = wv - v * N;
    int vN = v * N;
    int g = lane >> 4, f0 = (lane & 15) * 8;

    float acc[8] = {};
    int s = (wv == 0) ? 0 : ptr[wv - 1];
    int e = ptr[wv];
    int j = s + g;
    for (; j + 12 < e; j += 16) {
        int r0 = idx[j], r1 = idx[j + 4], r2 = idx[j + 8], r3 = idx[j + 12];
        us8 u0 = *(const us8*)(xs + (((size_t)(vN + r0)) << 7) + f0);
        us8 u1 = *(const us8*)(xs + (((size_t)(vN + r1)) << 7) + f0);
        us8 u2 = *(const us8*)(xs + (((size_t)(vN + r2)) << 7) + f0);
        us8 u3 = *(const us8*)(xs + (((size_t)(vN + r3)) << 7) + f0);
#pragma unroll
        for (int i = 0; i < 8; i++)
            acc[i] += (bf2f(u0[i]) + bf2f(u1[i])) + (bf2f(u2[i]) + bf2f(u3[i]));
    }
    for (; j < e; j += 4) {
        int r0 = idx[j];
        us8 u0 = *(const us8*)(xs + (((size_t)(vN + r0)) << 7) + f0);
#pragma unroll
        for (int i = 0; i < 8; i++) acc[i] += bf2f(u0[i]);
    }
#pragma unroll
    for (int i = 0; i < 8; i++) {
        acc[i] += __shfl_xor(acc[i], 16);
        acc[i] += __shfl_xor(acc[i], 32);
    }

    if (g == 0) {  // 16 lanes cover all 128 features
        us8 su = *(const us8*)(xs + (((size_t)wv) << 7) + f0);
        float dc = dinv[wv];
        size_t nb = (((size_t)n) << 7) + f0;
        size_t NH = ((size_t)N) << 7;
        us8 c0 = *(const us8*)(xs + nb);
        us8 c1 = *(const us8*)(xs + NH + nb);
        us8 c2 = *(const us8*)(xs + 2 * NH + nb);
        float wa = att[v * 3 + 0] / dinv[n];
        float wb = att[v * 3 + 1] / dinv[N + n];
        float wc = att[v * 3 + 2] / dinv[2 * N + n];
        float4 bb0 = *(const float4*)(bias + v * 128 + f0);
        float4 bb1 = *(const float4*)(bias + v * 128 + f0 + 4);
        float bv[8] = {bb0.x, bb0.y, bb0.z, bb0.w, bb1.x, bb1.y, bb1.z, bb1.w};
        us8 o;
#pragma unroll
        for (int i = 0; i < 8; i++) {
            float a = dc * (acc[i] + bf2f(su[i])) + bv[i];
            if (elu_inner) a = eluf(a);
            float cr = wa * bf2f(c0[i]) + wb * bf2f(c1[i]) + wc * bf2f(c2[i]);
            o[i] = f2bf(0.5f + a + eluf(0.5f * cr));
        }
        *(us8*)(xr + (((size_t)wv) << 7) + f0) = o;
    }
}

// ---------------------- edge scoring: bf16 xr2, 4 edges per wave ----------------------
__global__ __launch_bounds__(THREADS) void edge_score_kernel(
    const unsigned short* __restrict__ xr2, const int* __restrict__ edges,
    const int* __restrict__ edges_neg, float* __restrict__ out, int N, int Eev, int V) {
    int q = (blockIdx.x * THREADS + threadIdx.x) >> 4;
    int l16 = threadIdx.x & 15;
    int total = V * 2 * Eev;
    if (q >= total) return;
    int v = q / (2 * Eev);
    int r = q - v * (2 * Eev);
    const int* ep = (r < Eev) ? edges + ((size_t)v * Eev + r) * 2
                              : edges_neg + ((size_t)v * Eev + (r - Eev)) * 2;
    int a = ep[0], b = ep[1];
    const unsigned short* pa = xr2 + (((size_t)v * N + a) << 7) + l16 * 8;
    const unsigned short* pb = xr2 + (((size_t)v * N + b) << 7) + l16 * 8;
    us8 ua = *(const us8*)pa, ub = *(const us8*)pb;
    float s = 0.f;
#pragma unroll
    for (int i = 0; i < 8; i++) s += bf2f(ua[i]) * bf2f(ub[i]);
    s += __shfl_xor(s, 8);
    s += __shfl_xor(s, 4);
    s += __shfl_xor(s, 2);
    s += __shfl_xor(s, 1);
    if (l16 == 0) out[q] = s;
}

// ---------------------------------------------------------------------------
extern "C" void kernel_launch(void* const* d_in, const int* in_sizes, int n_in,
                              void* d_out, int out_size, void* d_ws, size_t ws_size,
                              hipStream_t stream) {
    const float* x   = (const float*)d_in[0];
    const float* W1  = (const float*)d_in[1];
    const float* b1  = (const float*)d_in[2];
    const float* W2  = (const float*)d_in[3];
    const float* b2  = (const float*)d_in[4];
    const float* A1  = (const float*)d_in[5];
    const float* bA1 = (const float*)d_in[6];
    const float* A2  = (const float*)d_in[7];
    const float* bA2 = (const float*)d_in[8];
    const float* Wc1 = (const float*)d_in[9];
    const float* bc1 = (const float*)d_in[10];
    const int* ei        = (const int*)d_in[13];
    const int* edges     = (const int*)d_in[14];
    const int* edges_neg = (const int*)d_in[15];
    float* out = (float*)d_out;

    const int H = 128, V = 3;
    const int N = in_sizes[0] / H;          // 50000
    const int E = in_sizes[13] / (V * 2);   // 800000
    const int Eev = in_sizes[14] / (V * 2); // 100000
    const int VNH = V * N * H;
    const int VN = V * N;
    const int VE = V * E;
    const int NB = (VN + 1023) >> 10;       // 147 buckets

    // workspace partition (all offsets 16B-aligned)
    float* ws   = (float*)d_ws;
    float* dinv = ws;                  // VN
    float* T    = dinv + VN;           // 2*3*128*128 = 98304
    float* Mraw = T + 98304;           // 32
    float* att  = Mraw + 32;           // 32 (att1 = att, att2 = att+9)
    int* cnt    = (int*)(att + 32);    // VN
    int* ptr    = cnt + VN;            // VN
    int* bsum   = ptr + VN;            // 256
    int* bcnt   = bsum + 256;          // 256
    int* bstart = bcnt + 256;          // 256 (NB+1 used)
    int* bofs   = bstart + 256;        // 256
    int* idx    = bofs + 256;          // VE
    int* coo_g  = idx + VE;            // VE
    int* coo_r  = coo_g + VE;          // VE
    unsigned short* xs = (unsigned short*)(coo_r + VE);  // VNH bf16 (prescaled h)
    unsigned short* xr = xs + VNH;                       // VNH bf16 (xr1 then xr2)
    unsigned short* xc = xr + VNH;                       // N*H bf16
    (void)ws_size; (void)n_in; (void)out_size;

    dim3 blk(THREADS);
    int gBC = (VE + BCH - 1) / BCH;
    int gGather = (int)(((size_t)VN * 64 + THREADS - 1) / THREADS);
    int nScanB = (VN + SC_CHUNK - 1) / SC_CHUNK;  // 147 <= 256
    dim3 gemmGrid((N + 127) / 128, 1, V);
    dim3 gemmGrid1((N + 127) / 128, 1, 1);
    int gScore = (int)(((size_t)V * 2 * Eev * 16 + THREADS - 1) / THREADS);

    // --- bucketed CSR build (shared by both layers) ---
    init_int_kernel<<<1, blk, 0, stream>>>(bcnt, 256);
    bucket_count_kernel<<<gBC, blk, 0, stream>>>(ei, bcnt, N, E, VE);
    bucket_scan_kernel<<<1, blk, 0, stream>>>(bcnt, bstart, bofs, NB);
    bucket_scatter_kernel<<<gBC, blk, 0, stream>>>(ei, bofs, coo_g, coo_r, N, E, VE);
    bucket_hist_kernel<<<NB, blk, 0, stream>>>(coo_g, bstart, cnt, VN);
    scan_sum_kernel<<<nScanB, SC_T, 0, stream>>>(cnt, bsum, VN);
    scan_top_kernel<<<1, SC_T, 0, stream>>>(bsum, nScanB);
    scan_apply_kernel<<<nScanB, SC_T, 0, stream>>>(cnt, bsum, ptr, dinv, VN);
    bucket_fill_kernel<<<NB, blk, 0, stream>>>(coo_g, coo_r, bstart, ptr, idx, VN);

    // --- attention (both layers, weights-only) ---
    small_mm_nn_kernel<<<(2 * 49152 + THREADS - 1) / THREADS, blk, 0, stream>>>(W1, W2, A1, A2, T);
    att_reduce_kernel<<<18, blk, 0, stream>>>(T, W1, W2, bA1, bA2, Mraw);
    att_softmax_kernel<<<1, 64, 0, stream>>>(Mraw, att);

    // --- layer 1: xs = bf16(dinv * (x @ W1^T)); xr1 = cross_rep (bf16) ---
    gemm_bf16_kernel<0><<<gemmGrid, blk, 0, stream>>>(
        x, nullptr, W1, nullptr, xs, dinv, N, 128, (size_t)0, (size_t)128 * 128, (size_t)N * 128);
    gather_cross_kernel<<<gGather, blk, 0, stream>>>(xs, dinv, ptr, idx, att, b1, xr, N, 1);

    // --- combine: xc = bf16(elu(emb @ Wc1^T + bc1)), emb = bf16 xr1 gathered ---
    gemm_bf16_kernel<1><<<gemmGrid1, blk, 0, stream>>>(
        nullptr, xr, Wc1, bc1, xc, nullptr, N, 384, (size_t)N * 128, (size_t)0, (size_t)0);

    // --- layer 2: xs = bf16(dinv * (xc @ W2^T)); xr2 = cross_rep (bf16) ---
    gemm_bf16_kernel<1><<<gemmGrid, blk, 0, stream>>>(
        nullptr, xc, W2, nullptr, xs, dinv, N, 128, (size_t)0, (size_t)128 * 128, (size_t)N * 128);
    gather_cross_kernel<<<gGather, blk, 0, stream>>>(xs, dinv, ptr, idx, att + 9, b2, xr, N, 0);

    // --- scoring (bf16 xr2) ---
    edge_score_kernel<<<gScore, blk, 0, stream>>>(xr, edges, edges_neg, out, N, Eev, V);
}

// Round 9
// 544.681 us; speedup vs baseline: 5.1746x; 1.0735x over previous
//
#include <hip/hip_runtime.h>
#include <hip/hip_bf16.h>

// ---------------------------------------------------------------------------
// mGCN: 3-view GCN + cross-view attention, 2 layers, edge scoring.
// R9: single fused per-bucket CSR kernel (hist+scan+dinv+ptr+fill in LDS,
//     no global VN scan, no cnt array); x pre-converted to bf16 for the
//     3-view layer-1 GEMM. Gather/score unchanged (random-read bound).
// Dims: N=50000, D=H=128, V=3, E=800000/view, Eev=100000.
// ---------------------------------------------------------------------------

#define THREADS 256
#define BCH 8192   // edges per bucket-chunk block

typedef __bf16 bf16x8 __attribute__((ext_vector_type(8)));
typedef float f32x4 __attribute__((ext_vector_type(4)));
typedef unsigned short us8 __attribute__((ext_vector_type(8)));

__device__ __forceinline__ float eluf(float x) {
    return x > 0.f ? x : expm1f(x);
}

__device__ __forceinline__ unsigned short f2bf(float f) {
    unsigned u = __builtin_bit_cast(unsigned, f);
    u += 0x7FFF + ((u >> 16) & 1);
    return (unsigned short)(u >> 16);
}
__device__ __forceinline__ float bf2f(unsigned short s) {
    unsigned u = ((unsigned)s) << 16;
    return __builtin_bit_cast(float, u);
}

// ---------------------- misc ----------------------
__global__ __launch_bounds__(THREADS) void init_int_kernel(int* p, int n) {
    int i = blockIdx.x * THREADS + threadIdx.x;
    if (i < n) p[i] = 0;
}

__global__ __launch_bounds__(THREADS) void f32_to_bf16_kernel(
    const float* __restrict__ in, unsigned short* __restrict__ out, int n8) {
    int i = blockIdx.x * THREADS + threadIdx.x;
    if (i >= n8) return;
    const float* p = in + (size_t)i * 8;
    float va[8];
    *(float4*)(va)     = *(const float4*)(p);
    *(float4*)(va + 4) = *(const float4*)(p + 4);
    us8 o;
#pragma unroll
    for (int j = 0; j < 8; j++) o[j] = f2bf(va[j]);
    *(us8*)(out + (size_t)i * 8) = o;
}

// ---------------------- bucketed CSR build ----------------------
// bucket(g) = g >> 10, g = v*N+col in [0, VN), NB = ceil(VN/1024) <= 160.

__global__ __launch_bounds__(THREADS) void bucket_count_kernel(
    const int* __restrict__ ei, int* __restrict__ bcnt, int N, int E, int VE) {
    __shared__ int h[160];
    for (int i = threadIdx.x; i < 160; i += THREADS) h[i] = 0;
    __syncthreads();
    int base = blockIdx.x * BCH;
    for (int k = 0; k < BCH; k += THREADS) {
        int t = base + k + threadIdx.x;
        if (t < VE) {
            int v = (t >= E) + (t >= 2 * E);
            int e = t - v * E;
            int col = ei[(size_t)v * 2 * E + E + e];
            atomicAdd(&h[(v * N + col) >> 10], 1);
        }
    }
    __syncthreads();
    for (int i = threadIdx.x; i < 160; i += THREADS)
        if (h[i]) atomicAdd(&bcnt[i], h[i]);
}

__global__ __launch_bounds__(THREADS) void bucket_scan_kernel(
    const int* __restrict__ bcnt, int* __restrict__ bstart, int* __restrict__ bofs, int nb) {
    __shared__ int sh[THREADS];
    int t = threadIdx.x;
    int v = (t < nb) ? bcnt[t] : 0;
    sh[t] = v;
    __syncthreads();
    for (int off = 1; off < THREADS; off <<= 1) {
        int u = (t >= off) ? sh[t - off] : 0;
        __syncthreads();
        sh[t] += u;
        __syncthreads();
    }
    int excl = sh[t] - v;
    if (t < nb) { bstart[t] = excl; bofs[t] = excl; }
    if (t == nb - 1) bstart[nb] = sh[t];
}

__global__ __launch_bounds__(THREADS) void bucket_scatter_kernel(
    const int* __restrict__ ei, int* __restrict__ bofs,
    int* __restrict__ coo_g, int* __restrict__ coo_r, int N, int E, int VE) {
    __shared__ int h[160];
    __shared__ int cur[160];
    for (int i = threadIdx.x; i < 160; i += THREADS) h[i] = 0;
    __syncthreads();
    int base = blockIdx.x * BCH;
    for (int k = 0; k < BCH; k += THREADS) {
        int t = base + k + threadIdx.x;
        if (t < VE) {
            int v = (t >= E) + (t >= 2 * E);
            int e = t - v * E;
            int col = ei[(size_t)v * 2 * E + E + e];
            atomicAdd(&h[(v * N + col) >> 10], 1);
        }
    }
    __syncthreads();
    if (threadIdx.x < 160 && h[threadIdx.x])
        cur[threadIdx.x] = atomicAdd(&bofs[threadIdx.x], h[threadIdx.x]);
    __syncthreads();
    for (int k = 0; k < BCH; k += THREADS) {
        int t = base + k + threadIdx.x;
        if (t < VE) {
            int v = (t >= E) + (t >= 2 * E);
            int e = t - v * E;
            const int* eiv = ei + (size_t)v * 2 * E;
            int row = eiv[e], col = eiv[E + e];
            int g = v * N + col;
            int pos = atomicAdd(&cur[g >> 10], 1);
            coo_g[pos] = g;
            coo_r[pos] = row;
        }
    }
}

// fused per-bucket: node hist -> local scan -> ptr (ends) + dinv -> CSR fill.
// Global CSR offset of node (g0+li) = bstart[b] + local_exclusive_scan[li].
__global__ __launch_bounds__(THREADS) void bucket_csr_kernel(
    const int* __restrict__ coo_g, const int* __restrict__ coo_r,
    const int* __restrict__ bstart, int* __restrict__ ptr,
    float* __restrict__ dinv, int* __restrict__ idx, int VN) {
    __shared__ int h[1024];
    __shared__ int cur[1024];
    __shared__ int sh[THREADS];
    int b = blockIdx.x, g0 = b << 10;
    int t = threadIdx.x;
    for (int i = t; i < 1024; i += THREADS) h[i] = 0;
    __syncthreads();
    int s = bstart[b], e = bstart[b + 1];
    for (int i = s + t; i < e; i += THREADS)
        atomicAdd(&h[coo_g[i] & 1023], 1);
    __syncthreads();
    // block scan: thread t owns h[4t..4t+3]
    int v0 = h[4 * t], v1 = h[4 * t + 1], v2 = h[4 * t + 2], v3 = h[4 * t + 3];
    int tsum = v0 + v1 + v2 + v3;
    sh[t] = tsum;
    __syncthreads();
    for (int off = 1; off < THREADS; off <<= 1) {
        int u = (t >= off) ? sh[t - off] : 0;
        __syncthreads();
        sh[t] += u;
        __syncthreads();
    }
    int run = s + sh[t] - tsum;  // global start of element 4t
    int starts[4] = {run, run + v0, run + v0 + v1, run + v0 + v1 + v2};
    int vals[4] = {v0, v1, v2, v3};
#pragma unroll
    for (int k = 0; k < 4; k++) {
        int li = 4 * t + k;
        cur[li] = starts[k];
        int g = g0 + li;
        if (g < VN) {
            ptr[g] = starts[k] + vals[k];           // ends
            dinv[g] = rsqrtf((float)(vals[k] + 1)); // +1 self loop
        }
    }
    __syncthreads();
    for (int i = s + t; i < e; i += THREADS) {
        int pos = atomicAdd(&cur[coo_g[i] & 1023], 1);
        idx[pos] = coo_r[i];
    }
}

// ---------------------- bf16 MFMA GEMM ----------------------
// C[M,128] = A[M,K] @ B[128,K]^T, fp32 acc, bf16 output.
// ABF=0: A fp32; ABF=1: A bf16 plane (same element addressing).
// A elem (m, k0+c) at A[(k0>>7)*AV + (k0&127) + m*128 + c].
// Epilogue: if bias: vv=elu(vv+bias[col]); if dscale: vv*=dscale[z*M+row]; bf16.
template <int ABF>
__global__ __launch_bounds__(256) void gemm_bf16_kernel(
    const float* __restrict__ Af, const unsigned short* __restrict__ Ab,
    const float* __restrict__ B, const float* __restrict__ bias,
    unsigned short* __restrict__ C, const float* __restrict__ dscale,
    int M, int Kb, size_t AV, size_t Bz, size_t Cz) {
    __shared__ unsigned short Ah[128 * 64];
    __shared__ unsigned short Bh[128 * 64];
    int tid = threadIdx.x;
    int z = blockIdx.z;
    int m0 = blockIdx.x * 128;
    const float* Bp = B + (size_t)z * Bz;
    int lane = tid & 63, wid = tid >> 6;
    int wr = wid >> 1, wc = wid & 1;
    int lr = lane & 15, lg = lane >> 4;
    f32x4 acc[4][4] = {};

    for (int k0 = 0; k0 < Kb; k0 += 64) {
        size_t Abase = (size_t)(k0 >> 7) * AV + (k0 & 127);
        for (int i = 0; i < 4; ++i) {
            int ch = tid + i * 256;  // 0..1023
            int row = ch >> 3, c8 = (ch & 7) << 3;
            int e = (row * 64 + c8) ^ ((row & 7) << 3);
            int gm = m0 + row;
            us8 h8;
            if (ABF) {
                if (gm < M) {
                    h8 = *(const us8*)(Ab + Abase + (size_t)gm * 128 + c8);
                } else {
#pragma unroll
                    for (int j = 0; j < 8; j++) h8[j] = 0;
                }
            } else {
                float va[8];
                if (gm < M) {
                    const float* p = Af + Abase + (size_t)gm * 128 + c8;
                    *(float4*)(va)     = *(const float4*)(p);
                    *(float4*)(va + 4) = *(const float4*)(p + 4);
                } else {
#pragma unroll
                    for (int j = 0; j < 8; j++) va[j] = 0.f;
                }
#pragma unroll
                for (int j = 0; j < 8; j++) h8[j] = f2bf(va[j]);
            }
            *(us8*)&Ah[e] = h8;
            float vb[8];
            const float* q = Bp + (size_t)row * Kb + k0 + c8;
            *(float4*)(vb)     = *(const float4*)(q);
            *(float4*)(vb + 4) = *(const float4*)(q + 4);
            us8 b8;
#pragma unroll
            for (int j = 0; j < 8; j++) b8[j] = f2bf(vb[j]);
            *(us8*)&Bh[e] = b8;
        }
        __syncthreads();
#pragma unroll
        for (int ks = 0; ks < 2; ++ks) {
            bf16x8 ah[4], bh[4];
#pragma unroll
            for (int m = 0; m < 4; m++) {
                int row = wr * 64 + m * 16 + lr;
                int e = (row * 64 + ks * 32 + lg * 8) ^ ((row & 7) << 3);
                ah[m] = *(const bf16x8*)&Ah[e];
            }
#pragma unroll
            for (int n = 0; n < 4; n++) {
                int col = wc * 64 + n * 16 + lr;
                int e = (col * 64 + ks * 32 + lg * 8) ^ ((col & 7) << 3);
                bh[n] = *(const bf16x8*)&Bh[e];
            }
#pragma unroll
            for (int m = 0; m < 4; m++)
#pragma unroll
                for (int n = 0; n < 4; n++)
                    acc[m][n] = __builtin_amdgcn_mfma_f32_16x16x32_bf16(ah[m], bh[n], acc[m][n], 0, 0, 0);
        }
        __syncthreads();
    }

#pragma unroll
    for (int m = 0; m < 4; m++) {
        int rbase = m0 + wr * 64 + m * 16 + lg * 4;
#pragma unroll
        for (int n = 0; n < 4; n++) {
            int col = wc * 64 + n * 16 + lr;
#pragma unroll
            for (int j = 0; j < 4; j++) {
                int row = rbase + j;
                if (row < M) {
                    float vv = acc[m][n][j];
                    if (bias) vv = eluf(vv + bias[col]);
                    if (dscale) vv *= dscale[(size_t)z * M + row];
                    C[(size_t)z * Cz + (size_t)row * 128 + col] = f2bf(vv);
                }
            }
        }
    }
}

// ---------------------- attention (both layers batched) ----------------------
__global__ __launch_bounds__(THREADS) void small_mm_nn_kernel(
    const float* __restrict__ W1, const float* __restrict__ W2,
    const float* __restrict__ A1, const float* __restrict__ A2,
    float* __restrict__ T) {
    int lin = blockIdx.x * THREADS + threadIdx.x;
    if (lin >= 2 * 3 * 128 * 128) return;
    int l = lin / 49152;
    int rem = lin - l * 49152;
    int b = rem & 127;
    int vk = rem >> 7;
    const float* w = (l ? W2 : W1) + (size_t)vk * 128;
    const float* A = l ? A2 : A1;
    float s = 0.f;
#pragma unroll 8
    for (int a = 0; a < 128; a++) s += w[a] * A[a * 128 + b];
    T[lin] = s;
}

__global__ __launch_bounds__(THREADS) void att_reduce_kernel(
    const float* __restrict__ T, const float* __restrict__ W1,
    const float* __restrict__ W2, const float* __restrict__ bA1,
    const float* __restrict__ bA2, float* __restrict__ Mraw) {
    int l = blockIdx.x / 9;
    int vw = blockIdx.x - l * 9;
    int v = vw / 3, w = vw - v * 3;
    const float* tp = T + (size_t)l * 49152 + (size_t)v * 16384;
    const float* wp = (l ? W2 : W1) + (size_t)w * 16384;
    float s = 0.f;
    for (int i = threadIdx.x; i < 16384; i += THREADS) s += tp[i] * wp[i];
    __shared__ float red[THREADS];
    red[threadIdx.x] = s;
    __syncthreads();
    for (int st = THREADS / 2; st; st >>= 1) {
        if (threadIdx.x < st) red[threadIdx.x] += red[threadIdx.x + st];
        __syncthreads();
    }
    if (threadIdx.x == 0) Mraw[blockIdx.x] = red[0] + 128.f * (l ? bA2[0] : bA1[0]);
}

__global__ void att_softmax_kernel(const float* __restrict__ Mraw, float* __restrict__ att) {
    int v = threadIdx.x;
    if (v >= 6) return;
    float m0 = Mraw[v * 3 + 0], m1 = Mraw[v * 3 + 1], m2 = Mraw[v * 3 + 2];
    float mx = fmaxf(m0, fmaxf(m1, m2));
    float e0 = expf(m0 - mx), e1 = expf(m1 - mx), e2 = expf(m2 - mx);
    float s = e0 + e1 + e2;
    att[v * 3 + 0] = e0 / s;
    att[v * 3 + 1] = e1 / s;
    att[v * 3 + 2] = e2 / s;
}

// ---------------------- fused GCN gather + cross_rep (bf16 out) ----------------------
// xs = bf16(dinv[row]*h[row]). One wave per (v,n); 4 groups of 16 lanes each
// own edges stride-4, unrolled x4 (16 rows in flight/wave); lane owns 8 feats.
__global__ __launch_bounds__(THREADS) void gather_cross_kernel(
    const unsigned short* __restrict__ xs, const float* __restrict__ dinv,
    const int* __restrict__ ptr, const int* __restrict__ idx,
    const float* __restrict__ att, const float* __restrict__ bias,
    unsigned short* __restrict__ xr, int N, int elu_inner) {
    int wv = (blockIdx.x * THREADS + threadIdx.x) >> 6;
    int lane = threadIdx.x & 63;
    int VN = 3 * N;
    if (wv >= VN) return;
    int v = wv / N;
    int n = wv - v * N;
    int vN = v * N;
    int g = lane >> 4, f0 = (lane & 15) * 8;

    float acc[8] = {};
    int s = (wv == 0) ? 0 : ptr[wv - 1];
    int e = ptr[wv];
    int j = s + g;
    for (; j + 12 < e; j += 16) {
        int r0 = idx[j], r1 = idx[j + 4], r2 = idx[j + 8], r3 = idx[j + 12];
        us8 u0 = *(const us8*)(xs + (((size_t)(vN + r0)) << 7) + f0);
        us8 u1 = *(const us8*)(xs + (((size_t)(vN + r1)) << 7) + f0);
        us8 u2 = *(const us8*)(xs + (((size_t)(vN + r2)) << 7) + f0);
        us8 u3 = *(const us8*)(xs + (((size_t)(vN + r3)) << 7) + f0);
#pragma unroll
        for (int i = 0; i < 8; i++)
            acc[i] += (bf2f(u0[i]) + bf2f(u1[i])) + (bf2f(u2[i]) + bf2f(u3[i]));
    }
    for (; j < e; j += 4) {
        int r0 = idx[j];
        us8 u0 = *(const us8*)(xs + (((size_t)(vN + r0)) << 7) + f0);
#pragma unroll
        for (int i = 0; i < 8; i++) acc[i] += bf2f(u0[i]);
    }
#pragma unroll
    for (int i = 0; i < 8; i++) {
        acc[i] += __shfl_xor(acc[i], 16);
        acc[i] += __shfl_xor(acc[i], 32);
    }

    if (g == 0) {  // 16 lanes cover all 128 features
        us8 su = *(const us8*)(xs + (((size_t)wv) << 7) + f0);
        float dc = dinv[wv];
        size_t nb = (((size_t)n) << 7) + f0;
        size_t NH = ((size_t)N) << 7;
        us8 c0 = *(const us8*)(xs + nb);
        us8 c1 = *(const us8*)(xs + NH + nb);
        us8 c2 = *(const us8*)(xs + 2 * NH + nb);
        float wa = att[v * 3 + 0] / dinv[n];
        float wb = att[v * 3 + 1] / dinv[N + n];
        float wc = att[v * 3 + 2] / dinv[2 * N + n];
        float4 bb0 = *(const float4*)(bias + v * 128 + f0);
        float4 bb1 = *(const float4*)(bias + v * 128 + f0 + 4);
        float bv[8] = {bb0.x, bb0.y, bb0.z, bb0.w, bb1.x, bb1.y, bb1.z, bb1.w};
        us8 o;
#pragma unroll
        for (int i = 0; i < 8; i++) {
            float a = dc * (acc[i] + bf2f(su[i])) + bv[i];
            if (elu_inner) a = eluf(a);
            float cr = wa * bf2f(c0[i]) + wb * bf2f(c1[i]) + wc * bf2f(c2[i]);
            o[i] = f2bf(0.5f + a + eluf(0.5f * cr));
        }
        *(us8*)(xr + (((size_t)wv) << 7) + f0) = o;
    }
}

// ---------------------- edge scoring: bf16 xr2, 4 edges per wave ----------------------
__global__ __launch_bounds__(THREADS) void edge_score_kernel(
    const unsigned short* __restrict__ xr2, const int* __restrict__ edges,
    const int* __restrict__ edges_neg, float* __restrict__ out, int N, int Eev, int V) {
    int q = (blockIdx.x * THREADS + threadIdx.x) >> 4;
    int l16 = threadIdx.x & 15;
    int total = V * 2 * Eev;
    if (q >= total) return;
    int v = q / (2 * Eev);
    int r = q - v * (2 * Eev);
    const int* ep = (r < Eev) ? edges + ((size_t)v * Eev + r) * 2
                              : edges_neg + ((size_t)v * Eev + (r - Eev)) * 2;
    int a = ep[0], b = ep[1];
    const unsigned short* pa = xr2 + (((size_t)v * N + a) << 7) + l16 * 8;
    const unsigned short* pb = xr2 + (((size_t)v * N + b) << 7) + l16 * 8;
    us8 ua = *(const us8*)pa, ub = *(const us8*)pb;
    float s = 0.f;
#pragma unroll
    for (int i = 0; i < 8; i++) s += bf2f(ua[i]) * bf2f(ub[i]);
    s += __shfl_xor(s, 8);
    s += __shfl_xor(s, 4);
    s += __shfl_xor(s, 2);
    s += __shfl_xor(s, 1);
    if (l16 == 0) out[q] = s;
}

// ---------------------------------------------------------------------------
extern "C" void kernel_launch(void* const* d_in, const int* in_sizes, int n_in,
                              void* d_out, int out_size, void* d_ws, size_t ws_size,
                              hipStream_t stream) {
    const float* x   = (const float*)d_in[0];
    const float* W1  = (const float*)d_in[1];
    const float* b1  = (const float*)d_in[2];
    const float* W2  = (const float*)d_in[3];
    const float* b2  = (const float*)d_in[4];
    const float* A1  = (const float*)d_in[5];
    const float* bA1 = (const float*)d_in[6];
    const float* A2  = (const float*)d_in[7];
    const float* bA2 = (const float*)d_in[8];
    const float* Wc1 = (const float*)d_in[9];
    const float* bc1 = (const float*)d_in[10];
    const int* ei        = (const int*)d_in[13];
    const int* edges     = (const int*)d_in[14];
    const int* edges_neg = (const int*)d_in[15];
    float* out = (float*)d_out;

    const int H = 128, V = 3;
    const int N = in_sizes[0] / H;          // 50000
    const int E = in_sizes[13] / (V * 2);   // 800000
    const int Eev = in_sizes[14] / (V * 2); // 100000
    const int VNH = V * N * H;
    const int VN = V * N;
    const int VE = V * E;
    const int NB = (VN + 1023) >> 10;       // 147 buckets

    // workspace partition (all offsets 16B-aligned)
    float* ws   = (float*)d_ws;
    float* dinv = ws;                  // VN
    float* T    = dinv + VN;           // 2*3*128*128 = 98304
    float* Mraw = T + 98304;           // 32
    float* att  = Mraw + 32;           // 32 (att1 = att, att2 = att+9)
    int* ptr    = (int*)(att + 32);    // VN
    int* bcnt   = ptr + VN;            // 256
    int* bstart = bcnt + 256;          // 256 (NB+1 used)
    int* bofs   = bstart + 256;        // 256
    int* idx    = bofs + 256;          // VE
    int* coo_g  = idx + VE;            // VE
    int* coo_r  = coo_g + VE;          // VE
    unsigned short* xs = (unsigned short*)(coo_r + VE);  // VNH bf16 (prescaled h)
    unsigned short* xr = xs + VNH;                       // VNH bf16 (xr1 then xr2)
    unsigned short* xc = xr + VNH;                       // N*H bf16
    unsigned short* xb = xc + (size_t)N * H;             // N*H bf16 (x pre-converted)
    (void)ws_size; (void)n_in; (void)out_size;

    dim3 blk(THREADS);
    int gBC = (VE + BCH - 1) / BCH;
    int gGather = (int)(((size_t)VN * 64 + THREADS - 1) / THREADS);
    dim3 gemmGrid((N + 127) / 128, 1, V);
    dim3 gemmGrid1((N + 127) / 128, 1, 1);
    int gScore = (int)(((size_t)V * 2 * Eev * 16 + THREADS - 1) / THREADS);
    int n8 = N * H / 8;

    // --- bucketed CSR build (shared by both layers): 5 kernels ---
    init_int_kernel<<<1, blk, 0, stream>>>(bcnt, 256);
    bucket_count_kernel<<<gBC, blk, 0, stream>>>(ei, bcnt, N, E, VE);
    bucket_scan_kernel<<<1, blk, 0, stream>>>(bcnt, bstart, bofs, NB);
    bucket_scatter_kernel<<<gBC, blk, 0, stream>>>(ei, bofs, coo_g, coo_r, N, E, VE);
    bucket_csr_kernel<<<NB, blk, 0, stream>>>(coo_g, coo_r, bstart, ptr, dinv, idx, VN);

    // --- x -> bf16 (read once instead of fp32 x3 in the view GEMM) ---
    f32_to_bf16_kernel<<<(n8 + THREADS - 1) / THREADS, blk, 0, stream>>>(x, xb, n8);

    // --- attention (both layers, weights-only) ---
    small_mm_nn_kernel<<<(2 * 49152 + THREADS - 1) / THREADS, blk, 0, stream>>>(W1, W2, A1, A2, T);
    att_reduce_kernel<<<18, blk, 0, stream>>>(T, W1, W2, bA1, bA2, Mraw);
    att_softmax_kernel<<<1, 64, 0, stream>>>(Mraw, att);

    // --- layer 1: xs = bf16(dinv * (x @ W1^T)); xr1 = cross_rep (bf16) ---
    gemm_bf16_kernel<1><<<gemmGrid, blk, 0, stream>>>(
        nullptr, xb, W1, nullptr, xs, dinv, N, 128, (size_t)0, (size_t)128 * 128, (size_t)N * 128);
    gather_cross_kernel<<<gGather, blk, 0, stream>>>(xs, dinv, ptr, idx, att, b1, xr, N, 1);

    // --- combine: xc = bf16(elu(emb @ Wc1^T + bc1)), emb = bf16 xr1 gathered ---
    gemm_bf16_kernel<1><<<gemmGrid1, blk, 0, stream>>>(
        nullptr, xr, Wc1, bc1, xc, nullptr, N, 384, (size_t)N * 128, (size_t)0, (size_t)0);

    // --- layer 2: xs = bf16(dinv * (xc @ W2^T)); xr2 = cross_rep (bf16) ---
    gemm_bf16_kernel<1><<<gemmGrid, blk, 0, stream>>>(
        nullptr, xc, W2, nullptr, xs, dinv, N, 128, (size_t)0, (size_t)128 * 128, (size_t)N * 128);
    gather_cross_kernel<<<gGather, blk, 0, stream>>>(xs, dinv, ptr, idx, att + 9, b2, xr, N, 0);

    // --- scoring (bf16 xr2) ---
    edge_score_kernel<<<gScore, blk, 0, stream>>>(xr, edges, edges_neg, out, N, Eev, V);
}

// Round 10
// 540.697 us; speedup vs baseline: 5.2127x; 1.0074x over previous
//
#include <hip/hip_runtime.h>
#include <hip/hip_bf16.h>

// ---------------------------------------------------------------------------
// mGCN: 3-view GCN + cross-view attention, 2 layers, edge scoring.
// R10: software-pipelined gather inner loop (2-deep prefetch per 16-lane
//      group -> 8 rows in flight/wave at low VGPR; avg deg 16 means the old
//      unrolled path never ran), memset for bcnt init. Rest as R9.
// Dims: N=50000, D=H=128, V=3, E=800000/view, Eev=100000.
// ---------------------------------------------------------------------------

#define THREADS 256
#define BCH 8192   // edges per bucket-chunk block

typedef __bf16 bf16x8 __attribute__((ext_vector_type(8)));
typedef float f32x4 __attribute__((ext_vector_type(4)));
typedef unsigned short us8 __attribute__((ext_vector_type(8)));

__device__ __forceinline__ float eluf(float x) {
    return x > 0.f ? x : expm1f(x);
}

__device__ __forceinline__ unsigned short f2bf(float f) {
    unsigned u = __builtin_bit_cast(unsigned, f);
    u += 0x7FFF + ((u >> 16) & 1);
    return (unsigned short)(u >> 16);
}
__device__ __forceinline__ float bf2f(unsigned short s) {
    unsigned u = ((unsigned)s) << 16;
    return __builtin_bit_cast(float, u);
}

// ---------------------- misc ----------------------
__global__ __launch_bounds__(THREADS) void f32_to_bf16_kernel(
    const float* __restrict__ in, unsigned short* __restrict__ out, int n8) {
    int i = blockIdx.x * THREADS + threadIdx.x;
    if (i >= n8) return;
    const float* p = in + (size_t)i * 8;
    float va[8];
    *(float4*)(va)     = *(const float4*)(p);
    *(float4*)(va + 4) = *(const float4*)(p + 4);
    us8 o;
#pragma unroll
    for (int j = 0; j < 8; j++) o[j] = f2bf(va[j]);
    *(us8*)(out + (size_t)i * 8) = o;
}

// ---------------------- bucketed CSR build ----------------------
// bucket(g) = g >> 10, g = v*N+col in [0, VN), NB = ceil(VN/1024) <= 160.

__global__ __launch_bounds__(THREADS) void bucket_count_kernel(
    const int* __restrict__ ei, int* __restrict__ bcnt, int N, int E, int VE) {
    __shared__ int h[160];
    for (int i = threadIdx.x; i < 160; i += THREADS) h[i] = 0;
    __syncthreads();
    int base = blockIdx.x * BCH;
    for (int k = 0; k < BCH; k += THREADS) {
        int t = base + k + threadIdx.x;
        if (t < VE) {
            int v = (t >= E) + (t >= 2 * E);
            int e = t - v * E;
            int col = ei[(size_t)v * 2 * E + E + e];
            atomicAdd(&h[(v * N + col) >> 10], 1);
        }
    }
    __syncthreads();
    for (int i = threadIdx.x; i < 160; i += THREADS)
        if (h[i]) atomicAdd(&bcnt[i], h[i]);
}

__global__ __launch_bounds__(THREADS) void bucket_scan_kernel(
    const int* __restrict__ bcnt, int* __restrict__ bstart, int* __restrict__ bofs, int nb) {
    __shared__ int sh[THREADS];
    int t = threadIdx.x;
    int v = (t < nb) ? bcnt[t] : 0;
    sh[t] = v;
    __syncthreads();
    for (int off = 1; off < THREADS; off <<= 1) {
        int u = (t >= off) ? sh[t - off] : 0;
        __syncthreads();
        sh[t] += u;
        __syncthreads();
    }
    int excl = sh[t] - v;
    if (t < nb) { bstart[t] = excl; bofs[t] = excl; }
    if (t == nb - 1) bstart[nb] = sh[t];
}

__global__ __launch_bounds__(THREADS) void bucket_scatter_kernel(
    const int* __restrict__ ei, int* __restrict__ bofs,
    int* __restrict__ coo_g, int* __restrict__ coo_r, int N, int E, int VE) {
    __shared__ int h[160];
    __shared__ int cur[160];
    for (int i = threadIdx.x; i < 160; i += THREADS) h[i] = 0;
    __syncthreads();
    int base = blockIdx.x * BCH;
    for (int k = 0; k < BCH; k += THREADS) {
        int t = base + k + threadIdx.x;
        if (t < VE) {
            int v = (t >= E) + (t >= 2 * E);
            int e = t - v * E;
            int col = ei[(size_t)v * 2 * E + E + e];
            atomicAdd(&h[(v * N + col) >> 10], 1);
        }
    }
    __syncthreads();
    if (threadIdx.x < 160 && h[threadIdx.x])
        cur[threadIdx.x] = atomicAdd(&bofs[threadIdx.x], h[threadIdx.x]);
    __syncthreads();
    for (int k = 0; k < BCH; k += THREADS) {
        int t = base + k + threadIdx.x;
        if (t < VE) {
            int v = (t >= E) + (t >= 2 * E);
            int e = t - v * E;
            const int* eiv = ei + (size_t)v * 2 * E;
            int row = eiv[e], col = eiv[E + e];
            int g = v * N + col;
            int pos = atomicAdd(&cur[g >> 10], 1);
            coo_g[pos] = g;
            coo_r[pos] = row;
        }
    }
}

// fused per-bucket: node hist -> local scan -> ptr (ends) + dinv -> CSR fill.
__global__ __launch_bounds__(THREADS) void bucket_csr_kernel(
    const int* __restrict__ coo_g, const int* __restrict__ coo_r,
    const int* __restrict__ bstart, int* __restrict__ ptr,
    float* __restrict__ dinv, int* __restrict__ idx, int VN) {
    __shared__ int h[1024];
    __shared__ int cur[1024];
    __shared__ int sh[THREADS];
    int b = blockIdx.x, g0 = b << 10;
    int t = threadIdx.x;
    for (int i = t; i < 1024; i += THREADS) h[i] = 0;
    __syncthreads();
    int s = bstart[b], e = bstart[b + 1];
    for (int i = s + t; i < e; i += THREADS)
        atomicAdd(&h[coo_g[i] & 1023], 1);
    __syncthreads();
    int v0 = h[4 * t], v1 = h[4 * t + 1], v2 = h[4 * t + 2], v3 = h[4 * t + 3];
    int tsum = v0 + v1 + v2 + v3;
    sh[t] = tsum;
    __syncthreads();
    for (int off = 1; off < THREADS; off <<= 1) {
        int u = (t >= off) ? sh[t - off] : 0;
        __syncthreads();
        sh[t] += u;
        __syncthreads();
    }
    int run = s + sh[t] - tsum;
    int starts[4] = {run, run + v0, run + v0 + v1, run + v0 + v1 + v2};
    int vals[4] = {v0, v1, v2, v3};
#pragma unroll
    for (int k = 0; k < 4; k++) {
        int li = 4 * t + k;
        cur[li] = starts[k];
        int g = g0 + li;
        if (g < VN) {
            ptr[g] = starts[k] + vals[k];           // ends
            dinv[g] = rsqrtf((float)(vals[k] + 1)); // +1 self loop
        }
    }
    __syncthreads();
    for (int i = s + t; i < e; i += THREADS) {
        int pos = atomicAdd(&cur[coo_g[i] & 1023], 1);
        idx[pos] = coo_r[i];
    }
}

// ---------------------- bf16 MFMA GEMM ----------------------
template <int ABF>
__global__ __launch_bounds__(256) void gemm_bf16_kernel(
    const float* __restrict__ Af, const unsigned short* __restrict__ Ab,
    const float* __restrict__ B, const float* __restrict__ bias,
    unsigned short* __restrict__ C, const float* __restrict__ dscale,
    int M, int Kb, size_t AV, size_t Bz, size_t Cz) {
    __shared__ unsigned short Ah[128 * 64];
    __shared__ unsigned short Bh[128 * 64];
    int tid = threadIdx.x;
    int z = blockIdx.z;
    int m0 = blockIdx.x * 128;
    const float* Bp = B + (size_t)z * Bz;
    int lane = tid & 63, wid = tid >> 6;
    int wr = wid >> 1, wc = wid & 1;
    int lr = lane & 15, lg = lane >> 4;
    f32x4 acc[4][4] = {};

    for (int k0 = 0; k0 < Kb; k0 += 64) {
        size_t Abase = (size_t)(k0 >> 7) * AV + (k0 & 127);
        for (int i = 0; i < 4; ++i) {
            int ch = tid + i * 256;  // 0..1023
            int row = ch >> 3, c8 = (ch & 7) << 3;
            int e = (row * 64 + c8) ^ ((row & 7) << 3);
            int gm = m0 + row;
            us8 h8;
            if (ABF) {
                if (gm < M) {
                    h8 = *(const us8*)(Ab + Abase + (size_t)gm * 128 + c8);
                } else {
#pragma unroll
                    for (int j = 0; j < 8; j++) h8[j] = 0;
                }
            } else {
                float va[8];
                if (gm < M) {
                    const float* p = Af + Abase + (size_t)gm * 128 + c8;
                    *(float4*)(va)     = *(const float4*)(p);
                    *(float4*)(va + 4) = *(const float4*)(p + 4);
                } else {
#pragma unroll
                    for (int j = 0; j < 8; j++) va[j] = 0.f;
                }
#pragma unroll
                for (int j = 0; j < 8; j++) h8[j] = f2bf(va[j]);
            }
            *(us8*)&Ah[e] = h8;
            float vb[8];
            const float* q = Bp + (size_t)row * Kb + k0 + c8;
            *(float4*)(vb)     = *(const float4*)(q);
            *(float4*)(vb + 4) = *(const float4*)(q + 4);
            us8 b8;
#pragma unroll
            for (int j = 0; j < 8; j++) b8[j] = f2bf(vb[j]);
            *(us8*)&Bh[e] = b8;
        }
        __syncthreads();
#pragma unroll
        for (int ks = 0; ks < 2; ++ks) {
            bf16x8 ah[4], bh[4];
#pragma unroll
            for (int m = 0; m < 4; m++) {
                int row = wr * 64 + m * 16 + lr;
                int e = (row * 64 + ks * 32 + lg * 8) ^ ((row & 7) << 3);
                ah[m] = *(const bf16x8*)&Ah[e];
            }
#pragma unroll
            for (int n = 0; n < 4; n++) {
                int col = wc * 64 + n * 16 + lr;
                int e = (col * 64 + ks * 32 + lg * 8) ^ ((col & 7) << 3);
                bh[n] = *(const bf16x8*)&Bh[e];
            }
#pragma unroll
            for (int m = 0; m < 4; m++)
#pragma unroll
                for (int n = 0; n < 4; n++)
                    acc[m][n] = __builtin_amdgcn_mfma_f32_16x16x32_bf16(ah[m], bh[n], acc[m][n], 0, 0, 0);
        }
        __syncthreads();
    }

#pragma unroll
    for (int m = 0; m < 4; m++) {
        int rbase = m0 + wr * 64 + m * 16 + lg * 4;
#pragma unroll
        for (int n = 0; n < 4; n++) {
            int col = wc * 64 + n * 16 + lr;
#pragma unroll
            for (int j = 0; j < 4; j++) {
                int row = rbase + j;
                if (row < M) {
                    float vv = acc[m][n][j];
                    if (bias) vv = eluf(vv + bias[col]);
                    if (dscale) vv *= dscale[(size_t)z * M + row];
                    C[(size_t)z * Cz + (size_t)row * 128 + col] = f2bf(vv);
                }
            }
        }
    }
}

// ---------------------- attention (both layers batched) ----------------------
__global__ __launch_bounds__(THREADS) void small_mm_nn_kernel(
    const float* __restrict__ W1, const float* __restrict__ W2,
    const float* __restrict__ A1, const float* __restrict__ A2,
    float* __restrict__ T) {
    int lin = blockIdx.x * THREADS + threadIdx.x;
    if (lin >= 2 * 3 * 128 * 128) return;
    int l = lin / 49152;
    int rem = lin - l * 49152;
    int b = rem & 127;
    int vk = rem >> 7;
    const float* w = (l ? W2 : W1) + (size_t)vk * 128;
    const float* A = l ? A2 : A1;
    float s = 0.f;
#pragma unroll 8
    for (int a = 0; a < 128; a++) s += w[a] * A[a * 128 + b];
    T[lin] = s;
}

__global__ __launch_bounds__(THREADS) void att_reduce_kernel(
    const float* __restrict__ T, const float* __restrict__ W1,
    const float* __restrict__ W2, const float* __restrict__ bA1,
    const float* __restrict__ bA2, float* __restrict__ Mraw) {
    int l = blockIdx.x / 9;
    int vw = blockIdx.x - l * 9;
    int v = vw / 3, w = vw - v * 3;
    const float* tp = T + (size_t)l * 49152 + (size_t)v * 16384;
    const float* wp = (l ? W2 : W1) + (size_t)w * 16384;
    float s = 0.f;
    for (int i = threadIdx.x; i < 16384; i += THREADS) s += tp[i] * wp[i];
    __shared__ float red[THREADS];
    red[threadIdx.x] = s;
    __syncthreads();
    for (int st = THREADS / 2; st; st >>= 1) {
        if (threadIdx.x < st) red[threadIdx.x] += red[threadIdx.x + st];
        __syncthreads();
    }
    if (threadIdx.x == 0) Mraw[blockIdx.x] = red[0] + 128.f * (l ? bA2[0] : bA1[0]);
}

__global__ void att_softmax_kernel(const float* __restrict__ Mraw, float* __restrict__ att) {
    int v = threadIdx.x;
    if (v >= 6) return;
    float m0 = Mraw[v * 3 + 0], m1 = Mraw[v * 3 + 1], m2 = Mraw[v * 3 + 2];
    float mx = fmaxf(m0, fmaxf(m1, m2));
    float e0 = expf(m0 - mx), e1 = expf(m1 - mx), e2 = expf(m2 - mx);
    float s = e0 + e1 + e2;
    att[v * 3 + 0] = e0 / s;
    att[v * 3 + 1] = e1 / s;
    att[v * 3 + 2] = e2 / s;
}

// ---------------------- fused GCN gather + cross_rep (bf16 out) ----------------------
// xs = bf16(dinv[row]*h[row]). One wave per (v,n); 4 groups of 16 lanes own
// edges stride-4 with a 2-deep software pipeline (next row load issued before
// current row is accumulated -> 8 rows in flight/wave); lane owns 8 feats.
__global__ __launch_bounds__(THREADS) void gather_cross_kernel(
    const unsigned short* __restrict__ xs, const float* __restrict__ dinv,
    const int* __restrict__ ptr, const int* __restrict__ idx,
    const float* __restrict__ att, const float* __restrict__ bias,
    unsigned short* __restrict__ xr, int N, int elu_inner) {
    int wv = (blockIdx.x * THREADS + threadIdx.x) >> 6;
    int lane = threadIdx.x & 63;
    int VN = 3 * N;
    if (wv >= VN) return;
    int v = wv / N;
    int n = wv - v * N;
    int vN = v * N;
    int g = lane >> 4, f0 = (lane & 15) * 8;

    float acc[8] = {};
    int s = (wv == 0) ? 0 : ptr[wv - 1];
    int e = ptr[wv];
    int j = s + g;
    if (j < e) {
        us8 ucur = *(const us8*)(xs + (((size_t)(vN + idx[j])) << 7) + f0);
        for (j += 4; j < e; j += 4) {
            us8 unext = *(const us8*)(xs + (((size_t)(vN + idx[j])) << 7) + f0);
#pragma unroll
            for (int i = 0; i < 8; i++) acc[i] += bf2f(ucur[i]);
            ucur = unext;
        }
#pragma unroll
        for (int i = 0; i < 8; i++) acc[i] += bf2f(ucur[i]);
    }
#pragma unroll
    for (int i = 0; i < 8; i++) {
        acc[i] += __shfl_xor(acc[i], 16);
        acc[i] += __shfl_xor(acc[i], 32);
    }

    if (g == 0) {  // 16 lanes cover all 128 features
        us8 su = *(const us8*)(xs + (((size_t)wv) << 7) + f0);
        float dc = dinv[wv];
        size_t nb = (((size_t)n) << 7) + f0;
        size_t NH = ((size_t)N) << 7;
        us8 c0 = *(const us8*)(xs + nb);
        us8 c1 = *(const us8*)(xs + NH + nb);
        us8 c2 = *(const us8*)(xs + 2 * NH + nb);
        float wa = att[v * 3 + 0] / dinv[n];
        float wb = att[v * 3 + 1] / dinv[N + n];
        float wc = att[v * 3 + 2] / dinv[2 * N + n];
        float4 bb0 = *(const float4*)(bias + v * 128 + f0);
        float4 bb1 = *(const float4*)(bias + v * 128 + f0 + 4);
        float bv[8] = {bb0.x, bb0.y, bb0.z, bb0.w, bb1.x, bb1.y, bb1.z, bb1.w};
        us8 o;
#pragma unroll
        for (int i = 0; i < 8; i++) {
            float a = dc * (acc[i] + bf2f(su[i])) + bv[i];
            if (elu_inner) a = eluf(a);
            float cr = wa * bf2f(c0[i]) + wb * bf2f(c1[i]) + wc * bf2f(c2[i]);
            o[i] = f2bf(0.5f + a + eluf(0.5f * cr));
        }
        *(us8*)(xr + (((size_t)wv) << 7) + f0) = o;
    }
}

// ---------------------- edge scoring: bf16 xr2, 4 edges per wave ----------------------
__global__ __launch_bounds__(THREADS) void edge_score_kernel(
    const unsigned short* __restrict__ xr2, const int* __restrict__ edges,
    const int* __restrict__ edges_neg, float* __restrict__ out, int N, int Eev, int V) {
    int q = (blockIdx.x * THREADS + threadIdx.x) >> 4;
    int l16 = threadIdx.x & 15;
    int total = V * 2 * Eev;
    if (q >= total) return;
    int v = q / (2 * Eev);
    int r = q - v * (2 * Eev);
    const int* ep = (r < Eev) ? edges + ((size_t)v * Eev + r) * 2
                              : edges_neg + ((size_t)v * Eev + (r - Eev)) * 2;
    int a = ep[0], b = ep[1];
    const unsigned short* pa = xr2 + (((size_t)v * N + a) << 7) + l16 * 8;
    const unsigned short* pb = xr2 + (((size_t)v * N + b) << 7) + l16 * 8;
    us8 ua = *(const us8*)pa, ub = *(const us8*)pb;
    float s = 0.f;
#pragma unroll
    for (int i = 0; i < 8; i++) s += bf2f(ua[i]) * bf2f(ub[i]);
    s += __shfl_xor(s, 8);
    s += __shfl_xor(s, 4);
    s += __shfl_xor(s, 2);
    s += __shfl_xor(s, 1);
    if (l16 == 0) out[q] = s;
}

// ---------------------------------------------------------------------------
extern "C" void kernel_launch(void* const* d_in, const int* in_sizes, int n_in,
                              void* d_out, int out_size, void* d_ws, size_t ws_size,
                              hipStream_t stream) {
    const float* x   = (const float*)d_in[0];
    const float* W1  = (const float*)d_in[1];
    const float* b1  = (const float*)d_in[2];
    const float* W2  = (const float*)d_in[3];
    const float* b2  = (const float*)d_in[4];
    const float* A1  = (const float*)d_in[5];
    const float* bA1 = (const float*)d_in[6];
    const float* A2  = (const float*)d_in[7];
    const float* bA2 = (const float*)d_in[8];
    const float* Wc1 = (const float*)d_in[9];
    const float* bc1 = (const float*)d_in[10];
    const int* ei        = (const int*)d_in[13];
    const int* edges     = (const int*)d_in[14];
    const int* edges_neg = (const int*)d_in[15];
    float* out = (float*)d_out;

    const int H = 128, V = 3;
    const int N = in_sizes[0] / H;          // 50000
    const int E = in_sizes[13] / (V * 2);   // 800000
    const int Eev = in_sizes[14] / (V * 2); // 100000
    const int VNH = V * N * H;
    const int VN = V * N;
    const int VE = V * E;
    const int NB = (VN + 1023) >> 10;       // 147 buckets

    // workspace partition (all offsets 16B-aligned)
    float* ws   = (float*)d_ws;
    float* dinv = ws;                  // VN
    float* T    = dinv + VN;           // 2*3*128*128 = 98304
    float* Mraw = T + 98304;           // 32
    float* att  = Mraw + 32;           // 32 (att1 = att, att2 = att+9)
    int* ptr    = (int*)(att + 32);    // VN
    int* bcnt   = ptr + VN;            // 256
    int* bstart = bcnt + 256;          // 256 (NB+1 used)
    int* bofs   = bstart + 256;        // 256
    int* idx    = bofs + 256;          // VE
    int* coo_g  = idx + VE;            // VE
    int* coo_r  = coo_g + VE;          // VE
    unsigned short* xs = (unsigned short*)(coo_r + VE);  // VNH bf16 (prescaled h)
    unsigned short* xr = xs + VNH;                       // VNH bf16 (xr1 then xr2)
    unsigned short* xc = xr + VNH;                       // N*H bf16
    unsigned short* xb = xc + (size_t)N * H;             // N*H bf16 (x pre-converted)
    (void)ws_size; (void)n_in; (void)out_size;

    dim3 blk(THREADS);
    int gBC = (VE + BCH - 1) / BCH;
    int gGather = (int)(((size_t)VN * 64 + THREADS - 1) / THREADS);
    dim3 gemmGrid((N + 127) / 128, 1, V);
    dim3 gemmGrid1((N + 127) / 128, 1, 1);
    int gScore = (int)(((size_t)V * 2 * Eev * 16 + THREADS - 1) / THREADS);
    int n8 = N * H / 8;

    // --- bucketed CSR build (shared by both layers) ---
    hipMemsetAsync(bcnt, 0, 256 * sizeof(int), stream);
    bucket_count_kernel<<<gBC, blk, 0, stream>>>(ei, bcnt, N, E, VE);
    bucket_scan_kernel<<<1, blk, 0, stream>>>(bcnt, bstart, bofs, NB);
    bucket_scatter_kernel<<<gBC, blk, 0, stream>>>(ei, bofs, coo_g, coo_r, N, E, VE);
    bucket_csr_kernel<<<NB, blk, 0, stream>>>(coo_g, coo_r, bstart, ptr, dinv, idx, VN);

    // --- x -> bf16 (read once instead of fp32 x3 in the view GEMM) ---
    f32_to_bf16_kernel<<<(n8 + THREADS - 1) / THREADS, blk, 0, stream>>>(x, xb, n8);

    // --- attention (both layers, weights-only) ---
    small_mm_nn_kernel<<<(2 * 49152 + THREADS - 1) / THREADS, blk, 0, stream>>>(W1, W2, A1, A2, T);
    att_reduce_kernel<<<18, blk, 0, stream>>>(T, W1, W2, bA1, bA2, Mraw);
    att_softmax_kernel<<<1, 64, 0, stream>>>(Mraw, att);

    // --- layer 1: xs = bf16(dinv * (x @ W1^T)); xr1 = cross_rep (bf16) ---
    gemm_bf16_kernel<1><<<gemmGrid, blk, 0, stream>>>(
        nullptr, xb, W1, nullptr, xs, dinv, N, 128, (size_t)0, (size_t)128 * 128, (size_t)N * 128);
    gather_cross_kernel<<<gGather, blk, 0, stream>>>(xs, dinv, ptr, idx, att, b1, xr, N, 1);

    // --- combine: xc = bf16(elu(emb @ Wc1^T + bc1)), emb = bf16 xr1 gathered ---
    gemm_bf16_kernel<1><<<gemmGrid1, blk, 0, stream>>>(
        nullptr, xr, Wc1, bc1, xc, nullptr, N, 384, (size_t)N * 128, (size_t)0, (size_t)0);

    // --- layer 2: xs = bf16(dinv * (xc @ W2^T)); xr2 = cross_rep (bf16) ---
    gemm_bf16_kernel<1><<<gemmGrid, blk, 0, stream>>>(
        nullptr, xc, W2, nullptr, xs, dinv, N, 128, (size_t)0, (size_t)128 * 128, (size_t)N * 128);
    gather_cross_kernel<<<gGather, blk, 0, stream>>>(xs, dinv, ptr, idx, att + 9, b2, xr, N, 0);

    // --- scoring (bf16 xr2) ---
    edge_score_kernel<<<gScore, blk, 0, stream>>>(xr, edges, edges_neg, out, N, Eev, V);
}